// Round 15
// baseline (222.850 us; speedup 1.0000x reference)
//
#include <hip/hip_runtime.h>
#include <hip/hip_bf16.h>

// FactoredHmmLm forward on MI355X.
//  1. prep_k: grid-stride streaming weight-cvt + embeddings (2048 blocks) + CSR/esum block
//  2. residual MLPs: batched mlp_k<1>/<2> (plain 2-barrier staging)
//  3. rlse_k x4 quarter-grids: 256x256 tiles, 2D-XCD regions, counted vmcnt
//  4. hr_k: rred + head_dot fused
//  5. emis_k: MFMA 64-word blocks + atomic exp-sum
//  6. leaf_k: standalone leaf GEMMs (emit inline, identity folded)
//  7. comb4 L1 (64/seq) + L2 (16/seq) + tail_k (16 -> 4 -> 1 + hlse + final)

using u16 = unsigned short;
typedef __attribute__((ext_vector_type(8))) short bh8;     // 8 bf16 (4 VGPRs)
typedef __attribute__((ext_vector_type(4))) float f32x4;
typedef __attribute__((ext_vector_type(8))) unsigned short u16x8;

#define HD 256
#define TT 256
#define NB 16
#define KCL 128
#define CS 8192
#define VV 10000
#define MAXB 320
#define LOG2E 1.44269504f
#define WTOT (6 * 65536)
#define WT2  (WTOT + VV * HD)
#define NELEM8 ((WT2 + 4 * CS * HD) / 8)     // 1,417,728 chunks of 8
#define PREPB 2048

__device__ __forceinline__ u16 f2bf(float v) {
  union { float f; unsigned int i; } u; u.f = v;
  unsigned int r = u.i + 0x7fffu + ((u.i >> 16) & 1u);   // RNE
  return (u16)(r >> 16);
}
__device__ __forceinline__ float bf2f(u16 u) {
  union { unsigned int i; float f; } x; x.i = ((unsigned int)u) << 16; return x.f;
}
__device__ __forceinline__ void gl2lds16(const u16* g, u16* l) {
  __builtin_amdgcn_global_load_lds(
      (const __attribute__((address_space(1))) unsigned int*)g,
      (__attribute__((address_space(3))) unsigned int*)l, 16, 0, 0);
}
__device__ __forceinline__ u16x8 cvt8(const float* __restrict__ s) {
  const float4 a = *reinterpret_cast<const float4*>(s);
  const float4 b = *reinterpret_cast<const float4*>(s + 4);
  u16x8 o;
  o[0] = f2bf(a.x); o[1] = f2bf(a.y); o[2] = f2bf(a.z); o[3] = f2bf(a.w);
  o[4] = f2bf(b.x); o[5] = f2bf(b.y); o[6] = f2bf(b.z); o[7] = f2bf(b.w);
  return o;
}
__device__ __forceinline__ u16x8 add_cvt8(const float* __restrict__ s0,
                                          const float* __restrict__ s1) {
  const float4 a0 = *reinterpret_cast<const float4*>(s0);
  const float4 b0 = *reinterpret_cast<const float4*>(s0 + 4);
  const float4 a1 = *reinterpret_cast<const float4*>(s1);
  const float4 b1 = *reinterpret_cast<const float4*>(s1 + 4);
  u16x8 o;
  o[0] = f2bf(a0.x + a1.x); o[1] = f2bf(a0.y + a1.y);
  o[2] = f2bf(a0.z + a1.z); o[3] = f2bf(a0.w + a1.w);
  o[4] = f2bf(b0.x + b1.x); o[5] = f2bf(b0.y + b1.y);
  o[6] = f2bf(b0.z + b1.z); o[7] = f2bf(b0.w + b1.w);
  return o;
}

// ---------------- prep: grid-stride streaming cvt+emb; CSR/esum in last block ------------

__global__ __launch_bounds__(256) void prep_k(
    const float* __restrict__ w0, const float* __restrict__ w1,
    const float* __restrict__ w2, const float* __restrict__ w3,
    const float* __restrict__ w4, const float* __restrict__ w5,
    const float* __restrict__ tpw, u16* __restrict__ dstW,
    const float* __restrict__ ec0, const float* __restrict__ es0, u16* __restrict__ d0,
    const float* __restrict__ ec1, const float* __restrict__ es1, u16* __restrict__ d1,
    const float* __restrict__ ec2, const float* __restrict__ es2, u16* __restrict__ d2,
    const float* __restrict__ ec3, const float* __restrict__ es3, u16* __restrict__ d3,
    const int* __restrict__ w2c, int* __restrict__ offs,
    int* __restrict__ wlist, int* __restrict__ bmap, float* __restrict__ esum) {
  const int b = blockIdx.x, tid = threadIdx.x;
  if (b < PREPB) {
    for (int i = b * 256 + tid; i < NELEM8; i += PREPB * 256) {
      const int idx = i * 8;
      if (idx < WTOT) {
        const int wi = idx >> 16;
        const float* s = wi == 0 ? w0 : wi == 1 ? w1 : wi == 2 ? w2
                       : wi == 3 ? w3 : wi == 4 ? w4 : w5;
        *reinterpret_cast<u16x8*>(dstW + idx) = cvt8(s + (idx & 65535));
      } else if (idx < WT2) {
        *reinterpret_cast<u16x8*>(dstW + idx) = cvt8(tpw + (idx - WTOT));
      } else {
        const int off = idx - WT2;
        const int seg = off >> 21;
        const int o = off & ((CS * HD) - 1);
        const int h = o & 255, row = o >> 8;
        const int k = row >> 6, si = row & 63;
        const float* ec = seg == 0 ? ec0 : seg == 1 ? ec1 : seg == 2 ? ec2 : ec3;
        const float* es = seg == 0 ? es0 : seg == 1 ? es1 : seg == 2 ? es2 : es3;
        u16* d = seg == 0 ? d0 : seg == 1 ? d1 : seg == 2 ? d2 : d3;
        *reinterpret_cast<u16x8*>(d + o) = add_cvt8(ec + k * HD + h, es + si * HD + h);
      }
    }
  } else {
    __shared__ int cnt[KCL], cur[KCL], off_s[KCL + 1];
    if (tid < KCL) cnt[tid] = 0;
    __syncthreads();
    for (int w = tid; w < VV; w += 256) atomicAdd(&cnt[w2c[w]], 1);
    __syncthreads();
    if (tid == 0) {
      int acc = 0;
      for (int c = 0; c < KCL; ++c) { off_s[c] = acc; acc += cnt[c]; }
      off_s[KCL] = acc;
      int idx = 0;
      for (int c = 0; c < KCL; ++c) {
        const int nb = (cnt[c] + 63) >> 6;
        for (int bb = 0; bb < nb; ++bb) bmap[idx++] = (c << 8) | bb;
      }
      for (; idx < MAXB; ++idx) bmap[idx] = -1;
    }
    __syncthreads();
    if (tid < KCL) cur[tid] = off_s[tid];
    if (tid <= KCL) offs[tid] = off_s[tid];
    __syncthreads();
    for (int w = tid; w < VV; w += 256) {
      const int p = atomicAdd(&cur[w2c[w]], 1);
      wlist[p] = w;
    }
    for (int i = tid; i < CS; i += 256) esum[i] = 0.f;
  }
}

// ---------------- batched residual-MLP GEMMs ----------

template<int LAYER>
__global__ __launch_bounds__(256) void mlp_k(
    const u16* __restrict__ E0, const u16* __restrict__ E1, const u16* __restrict__ E2,
    u16* __restrict__ H0, u16* __restrict__ H1, u16* __restrict__ H2,
    const u16* __restrict__ Wall,
    const float* __restrict__ bb0, const float* __restrict__ bb1, const float* __restrict__ bb2,
    float* __restrict__ SHf, u16* __restrict__ Xbf, u16* __restrict__ PHb) {
  __shared__ char lds[16384];
  const int tid = threadIdx.x, lane = tid & 63, wid = tid >> 6;
  const int z = blockIdx.z;
  const u16* Eb = z == 0 ? E0 : z == 1 ? E1 : E2;
  u16* Hb = z == 0 ? H0 : z == 1 ? H1 : H2;
  const u16* A = (LAYER == 1) ? Eb : (const u16*)Hb;
  const u16* B = Wall + (size_t)(2 * z + (LAYER - 1)) * 65536;
  const float* bias = z == 0 ? bb0 : z == 1 ? bb1 : bb2;

  const int rm = blockIdx.y * 64, cn = blockIdx.x * 64;
  const u16* Ag = A + (size_t)rm * HD;
  const u16* Bg = B + (size_t)cn * HD;

  f32x4 acc[4];
#pragma unroll
  for (int i = 0; i < 4; ++i) acc[i] = (f32x4){0.f, 0.f, 0.f, 0.f};
  const int ra = wid * 16 + (lane & 15);
  const int rb0 = lane & 15;
  const int ko = (lane >> 4) * 8;

  for (int kc = 0; kc < HD; kc += 64) {
    if (kc) __syncthreads();
#pragma unroll
    for (int i = 0; i < 2; ++i) {
      const int c = i * 256 + tid;
      const int r = c >> 3, cb = c & 7;
      const int gq = cb ^ (r & 7);
      gl2lds16(Ag + (size_t)r * HD + kc + gq * 8, (u16*)&lds[c * 16]);
      gl2lds16(Bg + (size_t)r * HD + kc + gq * 8, (u16*)&lds[8192 + c * 16]);
    }
    __syncthreads();
#pragma unroll
    for (int kk = 0; kk < 64; kk += 32) {
      const int kb = (kk + ko) * 2;
      const bh8 af = *reinterpret_cast<const bh8*>(&lds[ra * 128 + (kb ^ ((ra & 7) << 4))]);
#pragma unroll
      for (int nj = 0; nj < 4; ++nj) {
        const int rb = nj * 16 + rb0;
        const bh8 bf = *reinterpret_cast<const bh8*>(&lds[8192 + rb * 128 + (kb ^ ((rb & 7) << 4))]);
        acc[nj] = __builtin_amdgcn_mfma_f32_16x16x32_bf16(af, bf, acc[nj], 0, 0, 0);
      }
    }
  }

  const int g = lane >> 4, c0 = lane & 15;
#pragma unroll
  for (int nj = 0; nj < 4; ++nj) {
    const int nidx = cn + nj * 16 + c0;
    const float bv = bias[nidx];
#pragma unroll
    for (int reg = 0; reg < 4; ++reg) {
      const int midx = rm + wid * 16 + g * 4 + reg;
      float v = acc[nj][reg] + bv;
      if (LAYER == 2) v += bf2f(Eb[(size_t)midx * 256 + nidx]);
      v = fmaxf(v, 0.f);
      if (LAYER == 1) {
        Hb[(size_t)midx * 256 + nidx] = f2bf(v);
      } else {
        if (z == 0) SHf[(size_t)midx * 256 + nidx] = v;
        else if (z == 1) Xbf[(size_t)midx * 256 + nidx] = f2bf(v);
        else PHb[(size_t)midx * 256 + nidx] = f2bf(v);
      }
    }
  }
}

// ---------------- transition row-lse: quarter-grid, 2D-XCD regions, counted vmcnt ------

__global__ __launch_bounds__(512) void rlse_k(const u16* __restrict__ A,
                                              const u16* __restrict__ B,
                                              float* __restrict__ part,
                                              int quarter) {
  __shared__ char lds[131072];
  const int tid = threadIdx.x;
  const int lane = tid & 63, w = tid >> 6;
  const int wr = w >> 2, wc = w & 3;
  const int c0 = lane & 15, g = lane >> 4;

  const int bid = blockIdx.x;
  const int xcd = bid & 7, idx = bid >> 3;
  const int by = quarter * 8 + (xcd >> 2) * 4 + (idx >> 3);
  const int bx = (xcd & 3) * 8 + (idx & 7);
  const int rm = by * 256, cn = bx * 256;

  int offA[2][8], offB[2][4];
#pragma unroll
  for (int h = 0; h < 2; ++h) {
    const int kb = (h * 32 + g * 8) * 2;
#pragma unroll
    for (int mi = 0; mi < 8; ++mi) {
      const int ar = wr * 128 + mi * 16 + c0;
      offA[h][mi] = ar * 128 + (kb ^ ((ar & 7) << 4));
    }
#pragma unroll
    for (int nj = 0; nj < 4; ++nj) {
      const int br = wc * 64 + nj * 16 + c0;
      offB[h][nj] = 32768 + br * 128 + (kb ^ ((br & 7) << 4));
    }
  }

  f32x4 acc[8][4];
#pragma unroll
  for (int i = 0; i < 8; ++i)
#pragma unroll
    for (int j = 0; j < 4; ++j) acc[i][j] = (f32x4){0.f, 0.f, 0.f, 0.f};

  auto STAGE = [&](int kt, int hb) {
    const int kc = kt * 64;
    const int bo = hb * 65536;
#pragma unroll
    for (int q = 0; q < 4; ++q) {
      const int c = q * 512 + tid;
      const int r = c >> 3, cb = c & 7;
      const int gq = cb ^ (r & 7);
      gl2lds16(A + (size_t)(rm + r) * HD + kc + gq * 8, (u16*)&lds[bo + c * 16]);
    }
#pragma unroll
    for (int q = 0; q < 4; ++q) {
      const int c = q * 512 + tid;
      const int r = c >> 3, cb = c & 7;
      const int gq = cb ^ (r & 7);
      gl2lds16(B + (size_t)(cn + r) * HD + kc + gq * 8, (u16*)&lds[bo + 32768 + c * 16]);
    }
  };

  STAGE(0, 0);
  STAGE(1, 1);

  for (int kt = 0; kt < 4; ++kt) {
    if (kt < 3) asm volatile("s_waitcnt vmcnt(8)" ::: "memory");
    else        asm volatile("s_waitcnt vmcnt(0)" ::: "memory");
    __builtin_amdgcn_sched_barrier(0);
    __builtin_amdgcn_s_barrier();
    const int bo = (kt & 1) * 65536;
    __builtin_amdgcn_s_setprio(1);
#pragma unroll
    for (int h = 0; h < 2; ++h) {
      bh8 af[8], bf[4];
#pragma unroll
      for (int mi = 0; mi < 8; ++mi)
        af[mi] = *reinterpret_cast<const bh8*>(&lds[bo + offA[h][mi]]);
#pragma unroll
      for (int nj = 0; nj < 4; ++nj)
        bf[nj] = *reinterpret_cast<const bh8*>(&lds[bo + offB[h][nj]]);
#pragma unroll
      for (int mi = 0; mi < 8; ++mi)
#pragma unroll
        for (int nj = 0; nj < 4; ++nj)
          acc[mi][nj] = __builtin_amdgcn_mfma_f32_16x16x32_bf16(af[mi], bf[nj], acc[mi][nj], 0, 0, 0);
    }
    __builtin_amdgcn_s_setprio(0);
    __builtin_amdgcn_s_barrier();
    __builtin_amdgcn_sched_barrier(0);
    if (kt < 2) STAGE(kt + 2, kt & 1);
  }

  float rs[8][4];
#pragma unroll
  for (int mi = 0; mi < 8; ++mi)
#pragma unroll
    for (int reg = 0; reg < 4; ++reg) {
      float s = 0.f;
#pragma unroll
      for (int nj = 0; nj < 4; ++nj) s += exp2f(acc[mi][nj][reg] * LOG2E);
      rs[mi][reg] = s;
    }
#pragma unroll
  for (int off = 1; off < 16; off <<= 1)
#pragma unroll
    for (int mi = 0; mi < 8; ++mi)
#pragma unroll
      for (int reg = 0; reg < 4; ++reg)
        rs[mi][reg] += __shfl_xor(rs[mi][reg], off, 64);

  float* Lf = reinterpret_cast<float*>(lds);
  if (c0 == 0) {
#pragma unroll
    for (int mi = 0; mi < 8; ++mi)
#pragma unroll
      for (int reg = 0; reg < 4; ++reg)
        Lf[(wr * 128 + mi * 16 + g * 4 + reg) * 4 + wc] = rs[mi][reg];
  }
  __syncthreads();
  if (tid < 256)
    part[(size_t)bx * CS + rm + tid] = Lf[tid * 4] + Lf[tid * 4 + 1] + Lf[tid * 4 + 2] + Lf[tid * 4 + 3];
}

// ---------------- fused rred + head_dot ----------------

__global__ __launch_bounds__(256) void hr_k(const float* __restrict__ part,
                                            float* __restrict__ rlse,
                                            const float* __restrict__ sh,
                                            const float* __restrict__ wv,
                                            const float* __restrict__ bv,
                                            float* __restrict__ logits) {
  const int b = blockIdx.x, tid = threadIdx.x;
  if (b < 32) {
    const int i = b * 256 + tid;
    float s = 0.f;
#pragma unroll 8
    for (int bb = 0; bb < 32; ++bb) s += part[(size_t)bb * CS + i];
    rlse[i] = logf(s);
  } else {
    const int lane = tid & 63, wid = tid >> 6;
    const int row = (b - 32) * 4 + wid;
    float s = 0.f;
#pragma unroll
    for (int q = 0; q < 4; ++q)
      s += sh[(size_t)row * HD + q * 64 + lane] * wv[q * 64 + lane];
    for (int off = 32; off; off >>= 1) s += __shfl_xor(s, off, 64);
    if (lane == 0) logits[row] = s + bv[0];
  }
}

// ---------------- leaf-gen GEMM 64x64 (standalone, emit inline) ----------------

__global__ __launch_bounds__(256) void leaf_k(
    const u16* __restrict__ A, const u16* __restrict__ B,
    const float* __restrict__ row_lse,
    const float* __restrict__ lall, const float* __restrict__ esum,
    const int* __restrict__ text, const int* __restrict__ w2c,
    u16* __restrict__ leafb, float* __restrict__ leafsc) {
  __shared__ char lds[16384];
  __shared__ float wmax[4];
  const int tid = threadIdx.x;
  const int lane = tid & 63;
  const int wid = tid >> 6;

  const int bi = blockIdx.x;
  if (bi >= NB * (TT - 1)) {               // identity leaf
    const int n = bi - NB * (TT - 1);
    if (n < NB) {
      u16* node = leafb + ((size_t)n * 256 + 255) * 4096;
      for (int c = tid; c < 4096; c += 256) node[c] = ((c >> 6) == (c & 63)) ? (u16)0x3F80 : (u16)0;
      if (tid == 0) leafsc[n * 256 + 255] = 0.f;
    }
    return;
  }
  const int nn = bi / (TT - 1);
  const int ttv = bi % (TT - 1) + 1;
  const int wcur = text[nn * TT + ttv];
  const int rm = w2c[text[nn * TT + ttv - 1]] * 64;
  const int cn = w2c[wcur] * 64;
  const u16* Ag = A + (size_t)rm * HD;
  const u16* Bg = B + (size_t)cn * HD;

  f32x4 acc[4];
#pragma unroll
  for (int i = 0; i < 4; ++i) acc[i] = (f32x4){0.f, 0.f, 0.f, 0.f};
  const int ra = wid * 16 + (lane & 15);
  const int rb0 = lane & 15;
  const int ko = (lane >> 4) * 8;

  for (int kc = 0; kc < HD; kc += 64) {
    if (kc) __syncthreads();
#pragma unroll
    for (int i = 0; i < 2; ++i) {
      const int c = i * 256 + tid;
      const int r = c >> 3, cb = c & 7;
      const int gq = cb ^ (r & 7);
      gl2lds16(Ag + (size_t)r * HD + kc + gq * 8, (u16*)&lds[c * 16]);
      gl2lds16(Bg + (size_t)r * HD + kc + gq * 8, (u16*)&lds[8192 + c * 16]);
    }
    __syncthreads();
#pragma unroll
    for (int kk = 0; kk < 64; kk += 32) {
      const int kb = (kk + ko) * 2;
      const bh8 af = *reinterpret_cast<const bh8*>(&lds[ra * 128 + (kb ^ ((ra & 7) << 4))]);
#pragma unroll
      for (int nj = 0; nj < 4; ++nj) {
        const int rb = nj * 16 + rb0;
        const bh8 bf = *reinterpret_cast<const bh8*>(&lds[8192 + rb * 128 + (kb ^ ((rb & 7) << 4))]);
        acc[nj] = __builtin_amdgcn_mfma_f32_16x16x32_bf16(af, bf, acc[nj], 0, 0, 0);
      }
    }
  }

  const int g = lane >> 4, c0 = lane & 15;
  float L[4][4];
  float mx = -1e30f;
#pragma unroll
  for (int nj = 0; nj < 4; ++nj) {
    const int col = nj * 16 + c0;
    const float ev = lall[(size_t)wcur * 64 + col] - logf(esum[cn + col]);
#pragma unroll
    for (int reg = 0; reg < 4; ++reg) {
      const float l = acc[nj][reg] - row_lse[rm + wid * 16 + g * 4 + reg] + ev;
      L[nj][reg] = l;
      mx = fmaxf(mx, l);
    }
  }
#pragma unroll
  for (int off = 1; off < 64; off <<= 1) mx = fmaxf(mx, __shfl_xor(mx, off, 64));
  if (lane == 0) wmax[wid] = mx;
  __syncthreads();
  const float m = fmaxf(fmaxf(wmax[0], wmax[1]), fmaxf(wmax[2], wmax[3]));
  float* ftile = reinterpret_cast<float*>(lds);
#pragma unroll
  for (int nj = 0; nj < 4; ++nj)
#pragma unroll
    for (int reg = 0; reg < 4; ++reg)
      ftile[(wid * 16 + g * 4 + reg) * 64 + nj * 16 + c0] = exp2f((L[nj][reg] - m) * LOG2E);
  __syncthreads();
  const int leaf = ttv - 1;
  u16* node = leafb + ((size_t)nn * 256 + leaf) * 4096;
  const int rr = tid >> 2, cb = (tid & 3) * 16;
  u16x8 o0, o1;
  if ((leaf & 1) == 0) {
#pragma unroll
    for (int e = 0; e < 8; ++e) o0[e] = f2bf(ftile[rr * 64 + cb + e]);
#pragma unroll
    for (int e = 0; e < 8; ++e) o1[e] = f2bf(ftile[rr * 64 + cb + 8 + e]);
  } else {
#pragma unroll
    for (int e = 0; e < 8; ++e) o0[e] = f2bf(ftile[(cb + e) * 64 + rr]);
#pragma unroll
    for (int e = 0; e < 8; ++e) o1[e] = f2bf(ftile[(cb + 8 + e) * 64 + rr]);
  }
  *reinterpret_cast<u16x8*>(node + rr * 64 + cb) = o0;
  *reinterpret_cast<u16x8*>(node + rr * 64 + cb + 8) = o1;
  if (tid == 0) leafsc[nn * 256 + leaf] = m;
}

// ---------------- quad combine (stage + core) ----------------

__device__ __forceinline__ void comb4_stage(
    char* lds, const u16* s0, const u16* s1, const u16* s2, const u16* s3, int tid) {
  const u16* srcs[4] = {s0, s1, s2, s3};
  const int sr = tid >> 3, scb = (tid & 7) * 16;
#pragma unroll
  for (int nd = 0; nd < 4; ++nd)
#pragma unroll
    for (int rep = 0; rep < 2; ++rep) {
      const int r = rep * 32 + sr;
      const bh8 v = *reinterpret_cast<const bh8*>(srcs[nd] + r * 64 + (scb >> 1));
      *reinterpret_cast<bh8*>(&lds[nd * 8192 + r * 128 + (scb ^ ((r & 7) << 4))]) = v;
    }
  __syncthreads();
}

__device__ __forceinline__ void comb4_core(
    char* lds, float* wpm,
    float sc0, float sc1, float sc2, float sc3,
    u16* node, float* dsc, int parity, int tid) {
  const int lane = tid & 63, w = tid >> 6;
  const int p = w >> 1, h = w & 1;
  const int abase = p * 16384, bbase = abase + 8192;
  const int c0 = lane & 15, g = lane >> 4;
  f32x4 a2[2][4];
#pragma unroll
  for (int mi = 0; mi < 2; ++mi)
#pragma unroll
    for (int nj = 0; nj < 4; ++nj) a2[mi][nj] = (f32x4){0.f, 0.f, 0.f, 0.f};
#pragma unroll
  for (int kk = 0; kk < 64; kk += 32) {
    const int kb = (kk + g * 8) * 2;
    bh8 af[2], bf[4];
#pragma unroll
    for (int mi = 0; mi < 2; ++mi) {
      const int ar = h * 32 + mi * 16 + c0;
      af[mi] = *reinterpret_cast<const bh8*>(&lds[abase + ar * 128 + (kb ^ ((ar & 7) << 4))]);
    }
#pragma unroll
    for (int nj = 0; nj < 4; ++nj) {
      const int br = nj * 16 + c0;
      bf[nj] = *reinterpret_cast<const bh8*>(&lds[bbase + br * 128 + (kb ^ ((br & 7) << 4))]);
    }
#pragma unroll
    for (int mi = 0; mi < 2; ++mi)
#pragma unroll
      for (int nj = 0; nj < 4; ++nj)
        a2[mi][nj] = __builtin_amdgcn_mfma_f32_16x16x32_bf16(af[mi], bf[nj], a2[mi][nj], 0, 0, 0);
  }
  float mx = 0.f;
#pragma unroll
  for (int mi = 0; mi < 2; ++mi)
#pragma unroll
    for (int nj = 0; nj < 4; ++nj)
#pragma unroll
      for (int reg = 0; reg < 4; ++reg) mx = fmaxf(mx, a2[mi][nj][reg]);
#pragma unroll
  for (int off = 1; off < 64; off <<= 1) mx = fmaxf(mx, __shfl_xor(mx, off, 64));
  if (lane == 0) wpm[w] = mx;
  __syncthreads();
  const float mp = fmaxf(wpm[p * 2], wpm[p * 2 + 1]);
  const float invp = 1.0f / mp;
#pragma unroll
  for (int mi = 0; mi < 2; ++mi)
#pragma unroll
    for (int nj = 0; nj < 4; ++nj)
#pragma unroll
      for (int reg = 0; reg < 4; ++reg) {
        const int row = h * 32 + mi * 16 + g * 4 + reg;
        const int col = nj * 16 + c0;
        const u16 val = f2bf(a2[mi][nj][reg] * invp);
        if (p == 0)
          *reinterpret_cast<u16*>(&lds[32768 + row * 128 + ((col * 2) ^ ((row & 7) << 4))]) = val;
        else
          *reinterpret_cast<u16*>(&lds[40960 + col * 128 + ((row * 2) ^ ((col & 7) << 4))]) = val;
      }
  __syncthreads();

  f32x4 acc[4];
#pragma unroll
  for (int i = 0; i < 4; ++i) acc[i] = (f32x4){0.f, 0.f, 0.f, 0.f};
  const int ra = w * 16 + c0;
#pragma unroll
  for (int kk = 0; kk < 64; kk += 32) {
    const int kb = (kk + g * 8) * 2;
    const bh8 af = *reinterpret_cast<const bh8*>(&lds[32768 + ra * 128 + (kb ^ ((ra & 7) << 4))]);
#pragma unroll
    for (int nj = 0; nj < 4; ++nj) {
      const int rb = nj * 16 + c0;
      const bh8 bf = *reinterpret_cast<const bh8*>(&lds[40960 + rb * 128 + (kb ^ ((rb & 7) << 4))]);
      acc[nj] = __builtin_amdgcn_mfma_f32_16x16x32_bf16(af, bf, acc[nj], 0, 0, 0);
    }
  }
  float mx2 = 0.f;
#pragma unroll
  for (int nj = 0; nj < 4; ++nj)
#pragma unroll
    for (int reg = 0; reg < 4; ++reg) mx2 = fmaxf(mx2, acc[nj][reg]);
#pragma unroll
  for (int off = 1; off < 64; off <<= 1) mx2 = fmaxf(mx2, __shfl_xor(mx2, off, 64));
  if (lane == 0) wpm[4 + w] = mx2;
  __syncthreads();
  const float m = fmaxf(fmaxf(wpm[4], wpm[5]), fmaxf(wpm[6], wpm[7]));
  const float inv = 1.0f / m;
  float* ftile = reinterpret_cast<float*>(lds);
#pragma unroll
  for (int nj = 0; nj < 4; ++nj)
#pragma unroll
    for (int reg = 0; reg < 4; ++reg)
      ftile[(w * 16 + g * 4 + reg) * 64 + nj * 16 + c0] = acc[nj][reg] * inv;
  __syncthreads();
  const int rr = tid >> 2, cb = (tid & 3) * 16;
  u16x8 o0, o1;
  if (parity == 0) {
#pragma unroll
    for (int e = 0; e < 8; ++e) o0[e] = f2bf(ftile[rr * 64 + cb + e]);
#pragma unroll
    for (int e = 0; e < 8; ++e) o1[e] = f2bf(ftile[rr * 64 + cb + 8 + e]);
  } else {
#pragma unroll
    for (int e = 0; e < 8; ++e) o0[e] = f2bf(ftile[(cb + e) * 64 + rr]);
#pragma unroll
    for (int e = 0; e < 8; ++e) o1[e] = f2bf(ftile[(cb + 8 + e) * 64 + rr]);
  }
  *reinterpret_cast<u16x8*>(node + rr * 64 + cb) = o0;
  *reinterpret_cast<u16x8*>(node + rr * 64 + cb + 8) = o1;
  if (tid == 0)
    *dsc = sc0 + sc1 + sc2 + sc3
         + logf(fmaxf(wpm[0], wpm[1])) + logf(fmaxf(wpm[2], wpm[3])) + logf(m);
}

__global__ __launch_bounds__(256) void comb4_k(const u16* __restrict__ src,
                                               const float* __restrict__ scs,
                                               u16* __restrict__ dst,
                                               float* __restrict__ scd, int U) {
  const int n = blockIdx.x / U, u = blockIdx.x % U;
  __shared__ char lds[49152];
  __shared__ float wpm[8];
  const u16* base = src + ((size_t)(n * 4 * U + 4 * u)) * 4096;
  const float* sb = scs + n * 4 * U + 4 * u;
  comb4_stage(lds, base, base + 4096, base + 2 * 4096, base + 3 * 4096, threadIdx.x);
  comb4_core(lds, wpm, sb[0], sb[1], sb[2], sb[3],
             dst + ((size_t)(n * U + u)) * 4096, &scd[n * U + u], u & 1, threadIdx.x);
}

// ---------------- tail: 16 -> 4 -> 1 + hlse + final ----------------

__global__ __launch_bounds__(256) void tail_k(
    const u16* __restrict__ nodes, const float* __restrict__ nsc,
    u16* __restrict__ scratch, float* __restrict__ ssc,
    const float* __restrict__ hlog, const float* __restrict__ lall,
    const float* __restrict__ esum, const int* __restrict__ text,
    const int* __restrict__ w2c, float* __restrict__ out) {
  __shared__ char lds[49152];
  __shared__ float wpm[8];
  __shared__ float redm[4];
  __shared__ float hl_s;
  const int n = blockIdx.x, tid = threadIdx.x;
  const int lane = tid & 63, w = tid >> 6;

  float mm = -1e30f;
  for (int i = tid; i < CS; i += 256) mm = fmaxf(mm, hlog[i]);
  for (int off = 32; off; off >>= 1) mm = fmaxf(mm, __shfl_xor(mm, off, 64));
  if (lane == 0) redm[w] = mm;
  __syncthreads();
  const float M = fmaxf(fmaxf(redm[0], redm[1]), fmaxf(redm[2], redm[3]));
  float sx = 0.f;
  for (int i = tid; i < CS; i += 256) sx += expf(hlog[i] - M);
  for (int off = 32; off; off >>= 1) sx += __shfl_xor(sx, off, 64);
  __syncthreads();
  if (lane == 0) redm[w] = sx;
  __syncthreads();
  if (tid == 0) hl_s = M + logf(redm[0] + redm[1] + redm[2] + redm[3]);
  __syncthreads();
  const float hlse = hl_s;

  const u16* src = nodes + (size_t)n * 16 * 4096;
  const float* sc = nsc + n * 16;
  u16* scr = scratch + (size_t)n * 64 * 4096;
  float* scs = ssc + n * 64;
  for (int i = 0; i < 4; ++i) {
    comb4_stage(lds, src + (size_t)(4 * i) * 4096, src + (size_t)(4 * i + 1) * 4096,
                src + (size_t)(4 * i + 2) * 4096, src + (size_t)(4 * i + 3) * 4096, tid);
    comb4_core(lds, wpm, sc[4 * i], sc[4 * i + 1], sc[4 * i + 2], sc[4 * i + 3],
               scr + (size_t)i * 4096, &scs[i], i & 1, tid);
    __syncthreads();
  }
  comb4_stage(lds, scr, scr + 4096, scr + 2 * 4096, scr + 3 * 4096, tid);
  comb4_core(lds, wpm, scs[0], scs[1], scs[2], scs[3], scr + 4 * 4096, &scs[4], 0, tid);
  __syncthreads();

  if (tid < 64) {
    const int i = tid;
    const int w0 = text[n * TT];
    const int cc = w2c[w0];
    const float ev = lall[(size_t)w0 * 64 + i] - logf(esum[cc * 64 + i]);
    float a0 = hlog[cc * 64 + i] - hlse + ev;
    float m0 = a0;
    for (int off = 32; off; off >>= 1) m0 = fmaxf(m0, __shfl_xor(m0, off, 64));
    const float lin = expf(a0 - m0);
    const u16* row = scr + 4 * 4096 + i * 64;
    float rs = 0.f;
#pragma unroll
    for (int e8 = 0; e8 < 8; ++e8) {
      const u16x8 v = *reinterpret_cast<const u16x8*>(row + e8 * 8);
#pragma unroll
      for (int e = 0; e < 8; ++e) rs += bf2f(v[e]);
    }
    float v = lin * rs;
    for (int off = 32; off; off >>= 1) v += __shfl_xor(v, off, 64);
    if (i == 0) out[n] = m0 + scs[4] + logf(v);
  }
}

// ---------------- emission GEMM ----------------

__global__ __launch_bounds__(256) void emis_k(
    const u16* __restrict__ Wpb, const u16* __restrict__ PHb,
    const float* __restrict__ bp,
    const int* __restrict__ offs, const int* __restrict__ wlist,
    const int* __restrict__ map,
    float* __restrict__ esum, float* __restrict__ logits_all) {
  const int ent = map[blockIdx.x];
  if (ent < 0) return;
  const int c = ent >> 8, blk = ent & 255;
  __shared__ char lds[16384];
  __shared__ int wid_s[64];
  const int tid = threadIdx.x, lane = tid & 63, wid = tid >> 6;
  const int st = offs[c], cnt = offs[c + 1] - st;
  if (tid < 64) {
    const int idx = blk * 64 + tid;
    wid_s[tid] = (idx < cnt) ? wlist[st + idx] : -1;
  }
  __syncthreads();

  f32x4 acc[4];
#pragma unroll
  for (int i = 0; i < 4; ++i) acc[i] = (f32x4){0.f, 0.f, 0.f, 0.f};

  const int ra = wid * 16 + (lane & 15);
  const int rb0 = lane & 15;
  const int ko = (lane >> 4) * 8;
  const u16* Bg = PHb + (size_t)(c * 64) * HD;

  for (int kc = 0; kc < HD; kc += 64) {
    if (kc) __syncthreads();
#pragma unroll
    for (int i = 0; i < 2; ++i) {
      const int cc = i * 256 + tid;
      const int r = cc >> 3, cb = cc & 7;
      const int gq = cb ^ (r & 7);
      const int wv = max(wid_s[r], 0);
      gl2lds16(Wpb + (size_t)wv * HD + kc + gq * 8, (u16*)&lds[cc * 16]);
      gl2lds16(Bg + (size_t)r * HD + kc + gq * 8, (u16*)&lds[8192 + cc * 16]);
    }
    __syncthreads();
#pragma unroll
    for (int kk = 0; kk < 64; kk += 32) {
      const int kb = (kk + ko) * 2;
      const bh8 af = *reinterpret_cast<const bh8*>(&lds[ra * 128 + (kb ^ ((ra & 7) << 4))]);
#pragma unroll
      for (int nj = 0; nj < 4; ++nj) {
        const int rb = nj * 16 + rb0;
        const bh8 bf = *reinterpret_cast<const bh8*>(&lds[8192 + rb * 128 + (kb ^ ((rb & 7) << 4))]);
        acc[nj] = __builtin_amdgcn_mfma_f32_16x16x32_bf16(af, bf, acc[nj], 0, 0, 0);
      }
    }
  }

  const int g = lane >> 4, c0 = lane & 15;
#pragma unroll
  for (int nj = 0; nj < 4; ++nj) {
    float se = 0.f;
#pragma unroll
    for (int reg = 0; reg < 4; ++reg) {
      const int row = wid * 16 + g * 4 + reg;
      const int w = wid_s[row];
      if (w >= 0) {
        const float lg = acc[nj][reg] + bp[w];
        logits_all[(size_t)w * 64 + nj * 16 + c0] = lg;
        se += expf(lg);
      }
    }
    se += __shfl_xor(se, 16, 64);
    se += __shfl_xor(se, 32, 64);
    if (g == 0) atomicAdd(&esum[c * 64 + nj * 16 + c0], se);
  }
}

// ---------------- host orchestration ----------------

extern "C" void kernel_launch(void* const* d_in, const int* in_sizes, int n_in,
                              void* d_out, int out_size, void* d_ws, size_t ws_size,
                              hipStream_t stream) {
  (void)in_sizes; (void)n_in; (void)out_size; (void)ws_size;
  const int* text = (const int*)d_in[0];
  const int* w2c  = (const int*)d_in[1];
  const float* sec = (const float*)d_in[2];
  const float* ses = (const float*)d_in[3];
  const float* stc = (const float*)d_in[4];
  const float* sts = (const float*)d_in[5];
  const float* nec = (const float*)d_in[6];
  const float* nes = (const float*)d_in[7];
  const float* pec = (const float*)d_in[8];
  const float* pes = (const float*)d_in[9];
  const float* srw1 = (const float*)d_in[10];
  const float* srb1 = (const float*)d_in[11];
  const float* srw2 = (const float*)d_in[12];
  const float* srb2 = (const float*)d_in[13];
  const float* trw1 = (const float*)d_in[14];
  const float* trb1 = (const float*)d_in[15];
  const float* trw2 = (const float*)d_in[16];
  const float* trb2 = (const float*)d_in[17];
  const float* tew1 = (const float*)d_in[18];
  const float* teb1 = (const float*)d_in[19];
  const float* tew2 = (const float*)d_in[20];
  const float* teb2 = (const float*)d_in[21];
  const float* sow = (const float*)d_in[22];
  const float* sob = (const float*)d_in[23];
  const float* tpw = (const float*)d_in[24];
  const float* tpb = (const float*)d_in[25];
  float* out = (float*)d_out;

  char* p = (char*)d_ws;
  auto carve = [&](size_t bytes) -> char* {
    char* r = p; p += (bytes + 255) & ~(size_t)255; return r;
  };
  u16* Wall = (u16*)carve((size_t)WT2 * 2);
  u16* Wpb  = Wall + WTOT;
  u16* EbS  = (u16*)carve((size_t)CS * HD * 2);
  u16* EbT  = (u16*)carve((size_t)CS * HD * 2);
  u16* NSEb = (u16*)carve((size_t)CS * HD * 2);
  u16* EbP  = (u16*)carve((size_t)CS * HD * 2);
  u16* Hb0  = (u16*)carve((size_t)CS * HD * 2);
  u16* Hb1  = (u16*)carve((size_t)CS * HD * 2);
  u16* Hb2  = (u16*)carve((size_t)CS * HD * 2);
  float* SHf = (float*)carve((size_t)CS * HD * 4);
  u16* Xbf  = (u16*)carve((size_t)CS * HD * 2);
  u16* PHb  = (u16*)carve((size_t)CS * HD * 2);
  float* hlog  = (float*)carve(CS * 4);
  float* part  = (float*)carve((size_t)32 * CS * 4);
  float* rlse  = (float*)carve(CS * 4);
  int* offs    = (int*)carve((KCL + 1) * 4);
  int* wlist   = (int*)carve(VV * 4);
  int* bmap    = (int*)carve(MAXB * 4);
  float* esum  = (float*)carve(CS * 4);
  float* lall  = (float*)carve((size_t)VV * 64 * 4);
  u16*   bufA  = (u16*)carve((size_t)NB * 256 * 4096 * 2);
  u16*   bufB  = (u16*)carve((size_t)NB * 64 * 4096 * 2);
  float* scA   = (float*)carve((size_t)NB * 256 * 4);
  float* scB   = (float*)carve((size_t)NB * 256 * 4);

  prep_k<<<PREPB + 1, 256, 0, stream>>>(
      srw1, srw2, trw1, trw2, tew1, tew2, tpw, Wall,
      sec, ses, EbS, stc, sts, EbT, nec, nes, NSEb, pec, pes, EbP,
      w2c, offs, wlist, bmap, esum);

  mlp_k<1><<<dim3(4, 128, 3), 256, 0, stream>>>(
      EbS, EbT, EbP, Hb0, Hb1, Hb2, Wall, srb1, trb1, teb1, nullptr, nullptr, nullptr);
  mlp_k<2><<<dim3(4, 128, 3), 256, 0, stream>>>(
      EbS, EbT, EbP, Hb0, Hb1, Hb2, Wall, srb2, trb2, teb2, SHf, Xbf, PHb);

  // transition row-logsumexp: 4 quarter-grids (profiler visibility)
  for (int q = 0; q < 4; ++q)
    rlse_k<<<256, 512, 0, stream>>>(Xbf, NSEb, part, q);
  hr_k<<<32 + CS / 4, 256, 0, stream>>>(part, rlse, SHf, sow, sob, hlog);

  emis_k<<<MAXB, 256, 0, stream>>>(Wpb, PHb, tpb, offs, wlist, bmap, esum, lall);

  // leaves (standalone blocks, emit inline, identity folded)
  leaf_k<<<dim3(NB * (TT - 1) + NB), 256, 0, stream>>>(
      Xbf, NSEb, rlse, lall, esum, text, w2c, bufA, scA);

  // quad-tree: 256 -> 64 -> 16, then tail (16 -> 4 -> 1 + final)
  comb4_k<<<NB * 64, 256, 0, stream>>>(bufA, scA, bufB, scB, 64);
  comb4_k<<<NB * 16, 256, 0, stream>>>(bufB, scB, bufA, scA, 16);
  tail_k<<<NB, 256, 0, stream>>>(bufA, scA, bufB, scB, hlog, lall, esum, text, w2c, out);
}

// Round 16
// 209.941 us; speedup vs baseline: 1.0615x; 1.0615x over previous
//
#include <hip/hip_runtime.h>
#include <hip/hip_bf16.h>

// FactoredHmmLm forward on MI355X.
//  1. csr_k: fully parallel CSR build (shuffle scans) + esum zero  [launched FIRST: probe]
//  2. prep_stream: grid-stride streaming weight-cvt + embeddings (2048 blocks)
//  3. residual MLPs: batched mlp_k<1>/<2>
//  4. rlse_k x4 quarter-grids: 256x256 tiles, 2D-XCD regions, counted vmcnt
//  5. hr_k: rred + head_dot fused
//  6. emis_k: MFMA 64-word blocks + atomic exp-sum
//  7. leaf_k: standalone leaf GEMMs (emit inline, identity folded)
//  8. comb4 L1 + L2 + tail_k (16 -> 4 -> 1 + hlse + final)

using u16 = unsigned short;
typedef __attribute__((ext_vector_type(8))) short bh8;     // 8 bf16 (4 VGPRs)
typedef __attribute__((ext_vector_type(4))) float f32x4;
typedef __attribute__((ext_vector_type(8))) unsigned short u16x8;

#define HD 256
#define TT 256
#define NB 16
#define KCL 128
#define CS 8192
#define VV 10000
#define MAXB 320
#define LOG2E 1.44269504f
#define WTOT (6 * 65536)
#define WT2  (WTOT + VV * HD)
#define NELEM8 ((WT2 + 4 * CS * HD) / 8)     // 1,417,728 chunks of 8
#define PREPB 2048

__device__ __forceinline__ u16 f2bf(float v) {
  union { float f; unsigned int i; } u; u.f = v;
  unsigned int r = u.i + 0x7fffu + ((u.i >> 16) & 1u);   // RNE
  return (u16)(r >> 16);
}
__device__ __forceinline__ float bf2f(u16 u) {
  union { unsigned int i; float f; } x; x.i = ((unsigned int)u) << 16; return x.f;
}
__device__ __forceinline__ void gl2lds16(const u16* g, u16* l) {
  __builtin_amdgcn_global_load_lds(
      (const __attribute__((address_space(1))) unsigned int*)g,
      (__attribute__((address_space(3))) unsigned int*)l, 16, 0, 0);
}
__device__ __forceinline__ u16x8 cvt8(const float* __restrict__ s) {
  const float4 a = *reinterpret_cast<const float4*>(s);
  const float4 b = *reinterpret_cast<const float4*>(s + 4);
  u16x8 o;
  o[0] = f2bf(a.x); o[1] = f2bf(a.y); o[2] = f2bf(a.z); o[3] = f2bf(a.w);
  o[4] = f2bf(b.x); o[5] = f2bf(b.y); o[6] = f2bf(b.z); o[7] = f2bf(b.w);
  return o;
}
__device__ __forceinline__ u16x8 add_cvt8(const float* __restrict__ s0,
                                          const float* __restrict__ s1) {
  const float4 a0 = *reinterpret_cast<const float4*>(s0);
  const float4 b0 = *reinterpret_cast<const float4*>(s0 + 4);
  const float4 a1 = *reinterpret_cast<const float4*>(s1);
  const float4 b1 = *reinterpret_cast<const float4*>(s1 + 4);
  u16x8 o;
  o[0] = f2bf(a0.x + a1.x); o[1] = f2bf(a0.y + a1.y);
  o[2] = f2bf(a0.z + a1.z); o[3] = f2bf(a0.w + a1.w);
  o[4] = f2bf(b0.x + b1.x); o[5] = f2bf(b0.y + b1.y);
  o[6] = f2bf(b0.z + b1.z); o[7] = f2bf(b0.w + b1.w);
  return o;
}

// ---------------- csr_k: fully parallel CSR build + esum zero (1 block) ----------------

__global__ __launch_bounds__(256) void csr_k(const int* __restrict__ w2c,
                                             int* __restrict__ offs,
                                             int* __restrict__ wlist,
                                             int* __restrict__ bmap,
                                             float* __restrict__ esum) {
  __shared__ int cnt[KCL], cur[KCL];
  __shared__ int wsA[2], wsB[2];
  __shared__ int totb_s;
  const int tid = threadIdx.x, lane = tid & 63, w = tid >> 6;

  if (tid < KCL) cnt[tid] = 0;
  __syncthreads();
  for (int v = tid; v < VV; v += 256) atomicAdd(&cnt[w2c[v]], 1);
  __syncthreads();

  // parallel exclusive scan over cnt[0..127] (2 waves)
  int c = 0, x = 0;
  if (tid < KCL) {
    c = cnt[tid];
    x = c;
#pragma unroll
    for (int off = 1; off < 64; off <<= 1) {
      const int y = __shfl_up(x, off, 64);
      if (lane >= off) x += y;
    }
    if (lane == 63) wsA[w] = x;
  }
  __syncthreads();
  int nb = 0, xs = 0;
  if (tid < KCL) {
    const int base = (w == 1) ? wsA[0] : 0;
    const int excl = base + x - c;
    offs[tid] = excl;
    cur[tid] = excl;
    if (tid == KCL - 1) offs[KCL] = base + x;
    // second scan: per-cluster 64-word block counts
    nb = (c + 63) >> 6;
    xs = nb;
#pragma unroll
    for (int off = 1; off < 64; off <<= 1) {
      const int y = __shfl_up(xs, off, 64);
      if (lane >= off) xs += y;
    }
    if (lane == 63) wsB[w] = xs;
  }
  __syncthreads();
  if (tid < KCL) {
    const int base = (w == 1) ? wsB[0] : 0;
    const int b0 = base + xs - nb;
    for (int bb = 0; bb < nb; ++bb) bmap[b0 + bb] = (tid << 8) | bb;
    if (tid == KCL - 1) totb_s = base + xs;
  }
  __syncthreads();
  const int totb = totb_s;
  for (int i = totb + tid; i < MAXB; i += 256) bmap[i] = -1;
  for (int v = tid; v < VV; v += 256) {
    const int pos = atomicAdd(&cur[w2c[v]], 1);
    wlist[pos] = v;
  }
  for (int i = tid; i < CS; i += 256) esum[i] = 0.f;
}

// ---------------- prep_stream: grid-stride streaming cvt + embeddings ----------------

__global__ __launch_bounds__(256) void prep_stream(
    const float* __restrict__ w0, const float* __restrict__ w1,
    const float* __restrict__ w2, const float* __restrict__ w3,
    const float* __restrict__ w4, const float* __restrict__ w5,
    const float* __restrict__ tpw, u16* __restrict__ dstW,
    const float* __restrict__ ec0, const float* __restrict__ es0, u16* __restrict__ d0,
    const float* __restrict__ ec1, const float* __restrict__ es1, u16* __restrict__ d1,
    const float* __restrict__ ec2, const float* __restrict__ es2, u16* __restrict__ d2,
    const float* __restrict__ ec3, const float* __restrict__ es3, u16* __restrict__ d3) {
  const int b = blockIdx.x, tid = threadIdx.x;
  for (int i = b * 256 + tid; i < NELEM8; i += PREPB * 256) {
    const int idx = i * 8;
    if (idx < WTOT) {
      const int wi = idx >> 16;
      const float* s = wi == 0 ? w0 : wi == 1 ? w1 : wi == 2 ? w2
                     : wi == 3 ? w3 : wi == 4 ? w4 : w5;
      *reinterpret_cast<u16x8*>(dstW + idx) = cvt8(s + (idx & 65535));
    } else if (idx < WT2) {
      *reinterpret_cast<u16x8*>(dstW + idx) = cvt8(tpw + (idx - WTOT));
    } else {
      const int off = idx - WT2;
      const int seg = off >> 21;
      const int o = off & ((CS * HD) - 1);
      const int h = o & 255, row = o >> 8;
      const int k = row >> 6, si = row & 63;
      const float* ec = seg == 0 ? ec0 : seg == 1 ? ec1 : seg == 2 ? ec2 : ec3;
      const float* es = seg == 0 ? es0 : seg == 1 ? es1 : seg == 2 ? es2 : es3;
      u16* d = seg == 0 ? d0 : seg == 1 ? d1 : seg == 2 ? d2 : d3;
      *reinterpret_cast<u16x8*>(d + o) = add_cvt8(ec + k * HD + h, es + si * HD + h);
    }
  }
}

// ---------------- batched residual-MLP GEMMs ----------

template<int LAYER>
__global__ __launch_bounds__(256) void mlp_k(
    const u16* __restrict__ E0, const u16* __restrict__ E1, const u16* __restrict__ E2,
    u16* __restrict__ H0, u16* __restrict__ H1, u16* __restrict__ H2,
    const u16* __restrict__ Wall,
    const float* __restrict__ bb0, const float* __restrict__ bb1, const float* __restrict__ bb2,
    float* __restrict__ SHf, u16* __restrict__ Xbf, u16* __restrict__ PHb) {
  __shared__ char lds[16384];
  const int tid = threadIdx.x, lane = tid & 63, wid = tid >> 6;
  const int z = blockIdx.z;
  const u16* Eb = z == 0 ? E0 : z == 1 ? E1 : E2;
  u16* Hb = z == 0 ? H0 : z == 1 ? H1 : H2;
  const u16* A = (LAYER == 1) ? Eb : (const u16*)Hb;
  const u16* B = Wall + (size_t)(2 * z + (LAYER - 1)) * 65536;
  const float* bias = z == 0 ? bb0 : z == 1 ? bb1 : bb2;

  const int rm = blockIdx.y * 64, cn = blockIdx.x * 64;
  const u16* Ag = A + (size_t)rm * HD;
  const u16* Bg = B + (size_t)cn * HD;

  f32x4 acc[4];
#pragma unroll
  for (int i = 0; i < 4; ++i) acc[i] = (f32x4){0.f, 0.f, 0.f, 0.f};
  const int ra = wid * 16 + (lane & 15);
  const int rb0 = lane & 15;
  const int ko = (lane >> 4) * 8;

  for (int kc = 0; kc < HD; kc += 64) {
    if (kc) __syncthreads();
#pragma unroll
    for (int i = 0; i < 2; ++i) {
      const int c = i * 256 + tid;
      const int r = c >> 3, cb = c & 7;
      const int gq = cb ^ (r & 7);
      gl2lds16(Ag + (size_t)r * HD + kc + gq * 8, (u16*)&lds[c * 16]);
      gl2lds16(Bg + (size_t)r * HD + kc + gq * 8, (u16*)&lds[8192 + c * 16]);
    }
    __syncthreads();
#pragma unroll
    for (int kk = 0; kk < 64; kk += 32) {
      const int kb = (kk + ko) * 2;
      const bh8 af = *reinterpret_cast<const bh8*>(&lds[ra * 128 + (kb ^ ((ra & 7) << 4))]);
#pragma unroll
      for (int nj = 0; nj < 4; ++nj) {
        const int rb = nj * 16 + rb0;
        const bh8 bf = *reinterpret_cast<const bh8*>(&lds[8192 + rb * 128 + (kb ^ ((rb & 7) << 4))]);
        acc[nj] = __builtin_amdgcn_mfma_f32_16x16x32_bf16(af, bf, acc[nj], 0, 0, 0);
      }
    }
  }

  const int g = lane >> 4, c0 = lane & 15;
#pragma unroll
  for (int nj = 0; nj < 4; ++nj) {
    const int nidx = cn + nj * 16 + c0;
    const float bv = bias[nidx];
#pragma unroll
    for (int reg = 0; reg < 4; ++reg) {
      const int midx = rm + wid * 16 + g * 4 + reg;
      float v = acc[nj][reg] + bv;
      if (LAYER == 2) v += bf2f(Eb[(size_t)midx * 256 + nidx]);
      v = fmaxf(v, 0.f);
      if (LAYER == 1) {
        Hb[(size_t)midx * 256 + nidx] = f2bf(v);
      } else {
        if (z == 0) SHf[(size_t)midx * 256 + nidx] = v;
        else if (z == 1) Xbf[(size_t)midx * 256 + nidx] = f2bf(v);
        else PHb[(size_t)midx * 256 + nidx] = f2bf(v);
      }
    }
  }
}

// ---------------- transition row-lse: quarter-grid, 2D-XCD regions, counted vmcnt ------

__global__ __launch_bounds__(512) void rlse_k(const u16* __restrict__ A,
                                              const u16* __restrict__ B,
                                              float* __restrict__ part,
                                              int quarter) {
  __shared__ char lds[131072];
  const int tid = threadIdx.x;
  const int lane = tid & 63, w = tid >> 6;
  const int wr = w >> 2, wc = w & 3;
  const int c0 = lane & 15, g = lane >> 4;

  const int bid = blockIdx.x;
  const int xcd = bid & 7, idx = bid >> 3;
  const int by = quarter * 8 + (xcd >> 2) * 4 + (idx >> 3);
  const int bx = (xcd & 3) * 8 + (idx & 7);
  const int rm = by * 256, cn = bx * 256;

  int offA[2][8], offB[2][4];
#pragma unroll
  for (int h = 0; h < 2; ++h) {
    const int kb = (h * 32 + g * 8) * 2;
#pragma unroll
    for (int mi = 0; mi < 8; ++mi) {
      const int ar = wr * 128 + mi * 16 + c0;
      offA[h][mi] = ar * 128 + (kb ^ ((ar & 7) << 4));
    }
#pragma unroll
    for (int nj = 0; nj < 4; ++nj) {
      const int br = wc * 64 + nj * 16 + c0;
      offB[h][nj] = 32768 + br * 128 + (kb ^ ((br & 7) << 4));
    }
  }

  f32x4 acc[8][4];
#pragma unroll
  for (int i = 0; i < 8; ++i)
#pragma unroll
    for (int j = 0; j < 4; ++j) acc[i][j] = (f32x4){0.f, 0.f, 0.f, 0.f};

  auto STAGE = [&](int kt, int hb) {
    const int kc = kt * 64;
    const int bo = hb * 65536;
#pragma unroll
    for (int q = 0; q < 4; ++q) {
      const int c = q * 512 + tid;
      const int r = c >> 3, cb = c & 7;
      const int gq = cb ^ (r & 7);
      gl2lds16(A + (size_t)(rm + r) * HD + kc + gq * 8, (u16*)&lds[bo + c * 16]);
    }
#pragma unroll
    for (int q = 0; q < 4; ++q) {
      const int c = q * 512 + tid;
      const int r = c >> 3, cb = c & 7;
      const int gq = cb ^ (r & 7);
      gl2lds16(B + (size_t)(cn + r) * HD + kc + gq * 8, (u16*)&lds[bo + 32768 + c * 16]);
    }
  };

  STAGE(0, 0);
  STAGE(1, 1);

  for (int kt = 0; kt < 4; ++kt) {
    if (kt < 3) asm volatile("s_waitcnt vmcnt(8)" ::: "memory");
    else        asm volatile("s_waitcnt vmcnt(0)" ::: "memory");
    __builtin_amdgcn_sched_barrier(0);
    __builtin_amdgcn_s_barrier();
    const int bo = (kt & 1) * 65536;
    __builtin_amdgcn_s_setprio(1);
#pragma unroll
    for (int h = 0; h < 2; ++h) {
      bh8 af[8], bf[4];
#pragma unroll
      for (int mi = 0; mi < 8; ++mi)
        af[mi] = *reinterpret_cast<const bh8*>(&lds[bo + offA[h][mi]]);
#pragma unroll
      for (int nj = 0; nj < 4; ++nj)
        bf[nj] = *reinterpret_cast<const bh8*>(&lds[bo + offB[h][nj]]);
#pragma unroll
      for (int mi = 0; mi < 8; ++mi)
#pragma unroll
        for (int nj = 0; nj < 4; ++nj)
          acc[mi][nj] = __builtin_amdgcn_mfma_f32_16x16x32_bf16(af[mi], bf[nj], acc[mi][nj], 0, 0, 0);
    }
    __builtin_amdgcn_s_setprio(0);
    __builtin_amdgcn_s_barrier();
    __builtin_amdgcn_sched_barrier(0);
    if (kt < 2) STAGE(kt + 2, kt & 1);
  }

  float rs[8][4];
#pragma unroll
  for (int mi = 0; mi < 8; ++mi)
#pragma unroll
    for (int reg = 0; reg < 4; ++reg) {
      float s = 0.f;
#pragma unroll
      for (int nj = 0; nj < 4; ++nj) s += exp2f(acc[mi][nj][reg] * LOG2E);
      rs[mi][reg] = s;
    }
#pragma unroll
  for (int off = 1; off < 16; off <<= 1)
#pragma unroll
    for (int mi = 0; mi < 8; ++mi)
#pragma unroll
      for (int reg = 0; reg < 4; ++reg)
        rs[mi][reg] += __shfl_xor(rs[mi][reg], off, 64);

  float* Lf = reinterpret_cast<float*>(lds);
  if (c0 == 0) {
#pragma unroll
    for (int mi = 0; mi < 8; ++mi)
#pragma unroll
      for (int reg = 0; reg < 4; ++reg)
        Lf[(wr * 128 + mi * 16 + g * 4 + reg) * 4 + wc] = rs[mi][reg];
  }
  __syncthreads();
  if (tid < 256)
    part[(size_t)bx * CS + rm + tid] = Lf[tid * 4] + Lf[tid * 4 + 1] + Lf[tid * 4 + 2] + Lf[tid * 4 + 3];
}

// ---------------- fused rred + head_dot ----------------

__global__ __launch_bounds__(256) void hr_k(const float* __restrict__ part,
                                            float* __restrict__ rlse,
                                            const float* __restrict__ sh,
                                            const float* __restrict__ wv,
                                            const float* __restrict__ bv,
                                            float* __restrict__ logits) {
  const int b = blockIdx.x, tid = threadIdx.x;
  if (b < 32) {
    const int i = b * 256 + tid;
    float s = 0.f;
#pragma unroll 8
    for (int bb = 0; bb < 32; ++bb) s += part[(size_t)bb * CS + i];
    rlse[i] = logf(s);
  } else {
    const int lane = tid & 63, wid = tid >> 6;
    const int row = (b - 32) * 4 + wid;
    float s = 0.f;
#pragma unroll
    for (int q = 0; q < 4; ++q)
      s += sh[(size_t)row * HD + q * 64 + lane] * wv[q * 64 + lane];
    for (int off = 32; off; off >>= 1) s += __shfl_xor(s, off, 64);
    if (lane == 0) logits[row] = s + bv[0];
  }
}

// ---------------- leaf-gen GEMM 64x64 (standalone, emit inline) ----------------

__global__ __launch_bounds__(256) void leaf_k(
    const u16* __restrict__ A, const u16* __restrict__ B,
    const float* __restrict__ row_lse,
    const float* __restrict__ lall, const float* __restrict__ esum,
    const int* __restrict__ text, const int* __restrict__ w2c,
    u16* __restrict__ leafb, float* __restrict__ leafsc) {
  __shared__ char lds[16384];
  __shared__ float wmax[4];
  const int tid = threadIdx.x;
  const int lane = tid & 63;
  const int wid = tid >> 6;

  const int bi = blockIdx.x;
  if (bi >= NB * (TT - 1)) {               // identity leaf
    const int n = bi - NB * (TT - 1);
    if (n < NB) {
      u16* node = leafb + ((size_t)n * 256 + 255) * 4096;
      for (int c = tid; c < 4096; c += 256) node[c] = ((c >> 6) == (c & 63)) ? (u16)0x3F80 : (u16)0;
      if (tid == 0) leafsc[n * 256 + 255] = 0.f;
    }
    return;
  }
  const int nn = bi / (TT - 1);
  const int ttv = bi % (TT - 1) + 1;
  const int wcur = text[nn * TT + ttv];
  const int rm = w2c[text[nn * TT + ttv - 1]] * 64;
  const int cn = w2c[wcur] * 64;
  const u16* Ag = A + (size_t)rm * HD;
  const u16* Bg = B + (size_t)cn * HD;

  f32x4 acc[4];
#pragma unroll
  for (int i = 0; i < 4; ++i) acc[i] = (f32x4){0.f, 0.f, 0.f, 0.f};
  const int ra = wid * 16 + (lane & 15);
  const int rb0 = lane & 15;
  const int ko = (lane >> 4) * 8;

  for (int kc = 0; kc < HD; kc += 64) {
    if (kc) __syncthreads();
#pragma unroll
    for (int i = 0; i < 2; ++i) {
      const int c = i * 256 + tid;
      const int r = c >> 3, cb = c & 7;
      const int gq = cb ^ (r & 7);
      gl2lds16(Ag + (size_t)r * HD + kc + gq * 8, (u16*)&lds[c * 16]);
      gl2lds16(Bg + (size_t)r * HD + kc + gq * 8, (u16*)&lds[8192 + c * 16]);
    }
    __syncthreads();
#pragma unroll
    for (int kk = 0; kk < 64; kk += 32) {
      const int kb = (kk + ko) * 2;
      const bh8 af = *reinterpret_cast<const bh8*>(&lds[ra * 128 + (kb ^ ((ra & 7) << 4))]);
#pragma unroll
      for (int nj = 0; nj < 4; ++nj) {
        const int rb = nj * 16 + rb0;
        const bh8 bf = *reinterpret_cast<const bh8*>(&lds[8192 + rb * 128 + (kb ^ ((rb & 7) << 4))]);
        acc[nj] = __builtin_amdgcn_mfma_f32_16x16x32_bf16(af, bf, acc[nj], 0, 0, 0);
      }
    }
  }

  const int g = lane >> 4, c0 = lane & 15;
  float L[4][4];
  float mx = -1e30f;
#pragma unroll
  for (int nj = 0; nj < 4; ++nj) {
    const int col = nj * 16 + c0;
    const float ev = lall[(size_t)wcur * 64 + col] - logf(esum[cn + col]);
#pragma unroll
    for (int reg = 0; reg < 4; ++reg) {
      const float l = acc[nj][reg] - row_lse[rm + wid * 16 + g * 4 + reg] + ev;
      L[nj][reg] = l;
      mx = fmaxf(mx, l);
    }
  }
#pragma unroll
  for (int off = 1; off < 64; off <<= 1) mx = fmaxf(mx, __shfl_xor(mx, off, 64));
  if (lane == 0) wmax[wid] = mx;
  __syncthreads();
  const float m = fmaxf(fmaxf(wmax[0], wmax[1]), fmaxf(wmax[2], wmax[3]));
  float* ftile = reinterpret_cast<float*>(lds);
#pragma unroll
  for (int nj = 0; nj < 4; ++nj)
#pragma unroll
    for (int reg = 0; reg < 4; ++reg)
      ftile[(wid * 16 + g * 4 + reg) * 64 + nj * 16 + c0] = exp2f((L[nj][reg] - m) * LOG2E);
  __syncthreads();
  const int leaf = ttv - 1;
  u16* node = leafb + ((size_t)nn * 256 + leaf) * 4096;
  const int rr = tid >> 2, cb = (tid & 3) * 16;
  u16x8 o0, o1;
  if ((leaf & 1) == 0) {
#pragma unroll
    for (int e = 0; e < 8; ++e) o0[e] = f2bf(ftile[rr * 64 + cb + e]);
#pragma unroll
    for (int e = 0; e < 8; ++e) o1[e] = f2bf(ftile[rr * 64 + cb + 8 + e]);
  } else {
#pragma unroll
    for (int e = 0; e < 8; ++e) o0[e] = f2bf(ftile[(cb + e) * 64 + rr]);
#pragma unroll
    for (int e = 0; e < 8; ++e) o1[e] = f2bf(ftile[(cb + 8 + e) * 64 + rr]);
  }
  *reinterpret_cast<u16x8*>(node + rr * 64 + cb) = o0;
  *reinterpret_cast<u16x8*>(node + rr * 64 + cb + 8) = o1;
  if (tid == 0) leafsc[nn * 256 + leaf] = m;
}

// ---------------- quad combine (stage + core) ----------------

__device__ __forceinline__ void comb4_stage(
    char* lds, const u16* s0, const u16* s1, const u16* s2, const u16* s3, int tid) {
  const u16* srcs[4] = {s0, s1, s2, s3};
  const int sr = tid >> 3, scb = (tid & 7) * 16;
#pragma unroll
  for (int nd = 0; nd < 4; ++nd)
#pragma unroll
    for (int rep = 0; rep < 2; ++rep) {
      const int r = rep * 32 + sr;
      const bh8 v = *reinterpret_cast<const bh8*>(srcs[nd] + r * 64 + (scb >> 1));
      *reinterpret_cast<bh8*>(&lds[nd * 8192 + r * 128 + (scb ^ ((r & 7) << 4))]) = v;
    }
  __syncthreads();
}

__device__ __forceinline__ void comb4_core(
    char* lds, float* wpm,
    float sc0, float sc1, float sc2, float sc3,
    u16* node, float* dsc, int parity, int tid) {
  const int lane = tid & 63, w = tid >> 6;
  const int p = w >> 1, h = w & 1;
  const int abase = p * 16384, bbase = abase + 8192;
  const int c0 = lane & 15, g = lane >> 4;
  f32x4 a2[2][4];
#pragma unroll
  for (int mi = 0; mi < 2; ++mi)
#pragma unroll
    for (int nj = 0; nj < 4; ++nj) a2[mi][nj] = (f32x4){0.f, 0.f, 0.f, 0.f};
#pragma unroll
  for (int kk = 0; kk < 64; kk += 32) {
    const int kb = (kk + g * 8) * 2;
    bh8 af[2], bf[4];
#pragma unroll
    for (int mi = 0; mi < 2; ++mi) {
      const int ar = h * 32 + mi * 16 + c0;
      af[mi] = *reinterpret_cast<const bh8*>(&lds[abase + ar * 128 + (kb ^ ((ar & 7) << 4))]);
    }
#pragma unroll
    for (int nj = 0; nj < 4; ++nj) {
      const int br = nj * 16 + c0;
      bf[nj] = *reinterpret_cast<const bh8*>(&lds[bbase + br * 128 + (kb ^ ((br & 7) << 4))]);
    }
#pragma unroll
    for (int mi = 0; mi < 2; ++mi)
#pragma unroll
      for (int nj = 0; nj < 4; ++nj)
        a2[mi][nj] = __builtin_amdgcn_mfma_f32_16x16x32_bf16(af[mi], bf[nj], a2[mi][nj], 0, 0, 0);
  }
  float mx = 0.f;
#pragma unroll
  for (int mi = 0; mi < 2; ++mi)
#pragma unroll
    for (int nj = 0; nj < 4; ++nj)
#pragma unroll
      for (int reg = 0; reg < 4; ++reg) mx = fmaxf(mx, a2[mi][nj][reg]);
#pragma unroll
  for (int off = 1; off < 64; off <<= 1) mx = fmaxf(mx, __shfl_xor(mx, off, 64));
  if (lane == 0) wpm[w] = mx;
  __syncthreads();
  const float mp = fmaxf(wpm[p * 2], wpm[p * 2 + 1]);
  const float invp = 1.0f / mp;
#pragma unroll
  for (int mi = 0; mi < 2; ++mi)
#pragma unroll
    for (int nj = 0; nj < 4; ++nj)
#pragma unroll
      for (int reg = 0; reg < 4; ++reg) {
        const int row = h * 32 + mi * 16 + g * 4 + reg;
        const int col = nj * 16 + c0;
        const u16 val = f2bf(a2[mi][nj][reg] * invp);
        if (p == 0)
          *reinterpret_cast<u16*>(&lds[32768 + row * 128 + ((col * 2) ^ ((row & 7) << 4))]) = val;
        else
          *reinterpret_cast<u16*>(&lds[40960 + col * 128 + ((row * 2) ^ ((col & 7) << 4))]) = val;
      }
  __syncthreads();

  f32x4 acc[4];
#pragma unroll
  for (int i = 0; i < 4; ++i) acc[i] = (f32x4){0.f, 0.f, 0.f, 0.f};
  const int ra = w * 16 + c0;
#pragma unroll
  for (int kk = 0; kk < 64; kk += 32) {
    const int kb = (kk + g * 8) * 2;
    const bh8 af = *reinterpret_cast<const bh8*>(&lds[32768 + ra * 128 + (kb ^ ((ra & 7) << 4))]);
#pragma unroll
    for (int nj = 0; nj < 4; ++nj) {
      const int rb = nj * 16 + c0;
      const bh8 bf = *reinterpret_cast<const bh8*>(&lds[40960 + rb * 128 + (kb ^ ((rb & 7) << 4))]);
      acc[nj] = __builtin_amdgcn_mfma_f32_16x16x32_bf16(af, bf, acc[nj], 0, 0, 0);
    }
  }
  float mx2 = 0.f;
#pragma unroll
  for (int nj = 0; nj < 4; ++nj)
#pragma unroll
    for (int reg = 0; reg < 4; ++reg) mx2 = fmaxf(mx2, acc[nj][reg]);
#pragma unroll
  for (int off = 1; off < 64; off <<= 1) mx2 = fmaxf(mx2, __shfl_xor(mx2, off, 64));
  if (lane == 0) wpm[4 + w] = mx2;
  __syncthreads();
  const float m = fmaxf(fmaxf(wpm[4], wpm[5]), fmaxf(wpm[6], wpm[7]));
  const float inv = 1.0f / m;
  float* ftile = reinterpret_cast<float*>(lds);
#pragma unroll
  for (int nj = 0; nj < 4; ++nj)
#pragma unroll
    for (int reg = 0; reg < 4; ++reg)
      ftile[(w * 16 + g * 4 + reg) * 64 + nj * 16 + c0] = acc[nj][reg] * inv;
  __syncthreads();
  const int rr = tid >> 2, cb = (tid & 3) * 16;
  u16x8 o0, o1;
  if (parity == 0) {
#pragma unroll
    for (int e = 0; e < 8; ++e) o0[e] = f2bf(ftile[rr * 64 + cb + e]);
#pragma unroll
    for (int e = 0; e < 8; ++e) o1[e] = f2bf(ftile[rr * 64 + cb + 8 + e]);
  } else {
#pragma unroll
    for (int e = 0; e < 8; ++e) o0[e] = f2bf(ftile[(cb + e) * 64 + rr]);
#pragma unroll
    for (int e = 0; e < 8; ++e) o1[e] = f2bf(ftile[(cb + 8 + e) * 64 + rr]);
  }
  *reinterpret_cast<u16x8*>(node + rr * 64 + cb) = o0;
  *reinterpret_cast<u16x8*>(node + rr * 64 + cb + 8) = o1;
  if (tid == 0)
    *dsc = sc0 + sc1 + sc2 + sc3
         + logf(fmaxf(wpm[0], wpm[1])) + logf(fmaxf(wpm[2], wpm[3])) + logf(m);
}

__global__ __launch_bounds__(256) void comb4_k(const u16* __restrict__ src,
                                               const float* __restrict__ scs,
                                               u16* __restrict__ dst,
                                               float* __restrict__ scd, int U) {
  const int n = blockIdx.x / U, u = blockIdx.x % U;
  __shared__ char lds[49152];
  __shared__ float wpm[8];
  const u16* base = src + ((size_t)(n * 4 * U + 4 * u)) * 4096;
  const float* sb = scs + n * 4 * U + 4 * u;
  comb4_stage(lds, base, base + 4096, base + 2 * 4096, base + 3 * 4096, threadIdx.x);
  comb4_core(lds, wpm, sb[0], sb[1], sb[2], sb[3],
             dst + ((size_t)(n * U + u)) * 4096, &scd[n * U + u], u & 1, threadIdx.x);
}

// ---------------- tail: 16 -> 4 -> 1 + hlse + final ----------------

__global__ __launch_bounds__(256) void tail_k(
    const u16* __restrict__ nodes, const float* __restrict__ nsc,
    u16* __restrict__ scratch, float* __restrict__ ssc,
    const float* __restrict__ hlog, const float* __restrict__ lall,
    const float* __restrict__ esum, const int* __restrict__ text,
    const int* __restrict__ w2c, float* __restrict__ out) {
  __shared__ char lds[49152];
  __shared__ float wpm[8];
  __shared__ float redm[4];
  __shared__ float hl_s;
  const int n = blockIdx.x, tid = threadIdx.x;
  const int lane = tid & 63, w = tid >> 6;

  float mm = -1e30f;
  for (int i = tid; i < CS; i += 256) mm = fmaxf(mm, hlog[i]);
  for (int off = 32; off; off >>= 1) mm = fmaxf(mm, __shfl_xor(mm, off, 64));
  if (lane == 0) redm[w] = mm;
  __syncthreads();
  const float M = fmaxf(fmaxf(redm[0], redm[1]), fmaxf(redm[2], redm[3]));
  float sx = 0.f;
  for (int i = tid; i < CS; i += 256) sx += expf(hlog[i] - M);
  for (int off = 32; off; off >>= 1) sx += __shfl_xor(sx, off, 64);
  __syncthreads();
  if (lane == 0) redm[w] = sx;
  __syncthreads();
  if (tid == 0) hl_s = M + logf(redm[0] + redm[1] + redm[2] + redm[3]);
  __syncthreads();
  const float hlse = hl_s;

  const u16* src = nodes + (size_t)n * 16 * 4096;
  const float* sc = nsc + n * 16;
  u16* scr = scratch + (size_t)n * 64 * 4096;
  float* scs = ssc + n * 64;
  for (int i = 0; i < 4; ++i) {
    comb4_stage(lds, src + (size_t)(4 * i) * 4096, src + (size_t)(4 * i + 1) * 4096,
                src + (size_t)(4 * i + 2) * 4096, src + (size_t)(4 * i + 3) * 4096, tid);
    comb4_core(lds, wpm, sc[4 * i], sc[4 * i + 1], sc[4 * i + 2], sc[4 * i + 3],
               scr + (size_t)i * 4096, &scs[i], i & 1, tid);
    __syncthreads();
  }
  comb4_stage(lds, scr, scr + 4096, scr + 2 * 4096, scr + 3 * 4096, tid);
  comb4_core(lds, wpm, scs[0], scs[1], scs[2], scs[3], scr + 4 * 4096, &scs[4], 0, tid);
  __syncthreads();

  if (tid < 64) {
    const int i = tid;
    const int w0 = text[n * TT];
    const int cc = w2c[w0];
    const float ev = lall[(size_t)w0 * 64 + i] - logf(esum[cc * 64 + i]);
    float a0 = hlog[cc * 64 + i] - hlse + ev;
    float m0 = a0;
    for (int off = 32; off; off >>= 1) m0 = fmaxf(m0, __shfl_xor(m0, off, 64));
    const float lin = expf(a0 - m0);
    const u16* row = scr + 4 * 4096 + i * 64;
    float rs = 0.f;
#pragma unroll
    for (int e8 = 0; e8 < 8; ++e8) {
      const u16x8 v = *reinterpret_cast<const u16x8*>(row + e8 * 8);
#pragma unroll
      for (int e = 0; e < 8; ++e) rs += bf2f(v[e]);
    }
    float v = lin * rs;
    for (int off = 32; off; off >>= 1) v += __shfl_xor(v, off, 64);
    if (i == 0) out[n] = m0 + scs[4] + logf(v);
  }
}

// ---------------- emission GEMM ----------------

__global__ __launch_bounds__(256) void emis_k(
    const u16* __restrict__ Wpb, const u16* __restrict__ PHb,
    const float* __restrict__ bp,
    const int* __restrict__ offs, const int* __restrict__ wlist,
    const int* __restrict__ map,
    float* __restrict__ esum, float* __restrict__ logits_all) {
  const int ent = map[blockIdx.x];
  if (ent < 0) return;
  const int c = ent >> 8, blk = ent & 255;
  __shared__ char lds[16384];
  __shared__ int wid_s[64];
  const int tid = threadIdx.x, lane = tid & 63, wid = tid >> 6;
  const int st = offs[c], cnt = offs[c + 1] - st;
  if (tid < 64) {
    const int idx = blk * 64 + tid;
    wid_s[tid] = (idx < cnt) ? wlist[st + idx] : -1;
  }
  __syncthreads();

  f32x4 acc[4];
#pragma unroll
  for (int i = 0; i < 4; ++i) acc[i] = (f32x4){0.f, 0.f, 0.f, 0.f};

  const int ra = wid * 16 + (lane & 15);
  const int rb0 = lane & 15;
  const int ko = (lane >> 4) * 8;
  const u16* Bg = PHb + (size_t)(c * 64) * HD;

  for (int kc = 0; kc < HD; kc += 64) {
    if (kc) __syncthreads();
#pragma unroll
    for (int i = 0; i < 2; ++i) {
      const int cc = i * 256 + tid;
      const int r = cc >> 3, cb = cc & 7;
      const int gq = cb ^ (r & 7);
      const int wv = max(wid_s[r], 0);
      gl2lds16(Wpb + (size_t)wv * HD + kc + gq * 8, (u16*)&lds[cc * 16]);
      gl2lds16(Bg + (size_t)r * HD + kc + gq * 8, (u16*)&lds[8192 + cc * 16]);
    }
    __syncthreads();
#pragma unroll
    for (int kk = 0; kk < 64; kk += 32) {
      const int kb = (kk + ko) * 2;
      const bh8 af = *reinterpret_cast<const bh8*>(&lds[ra * 128 + (kb ^ ((ra & 7) << 4))]);
#pragma unroll
      for (int nj = 0; nj < 4; ++nj) {
        const int rb = nj * 16 + rb0;
        const bh8 bf = *reinterpret_cast<const bh8*>(&lds[8192 + rb * 128 + (kb ^ ((rb & 7) << 4))]);
        acc[nj] = __builtin_amdgcn_mfma_f32_16x16x32_bf16(af, bf, acc[nj], 0, 0, 0);
      }
    }
  }

  const int g = lane >> 4, c0 = lane & 15;
#pragma unroll
  for (int nj = 0; nj < 4; ++nj) {
    float se = 0.f;
#pragma unroll
    for (int reg = 0; reg < 4; ++reg) {
      const int row = wid * 16 + g * 4 + reg;
      const int w = wid_s[row];
      if (w >= 0) {
        const float lg = acc[nj][reg] + bp[w];
        logits_all[(size_t)w * 64 + nj * 16 + c0] = lg;
        se += expf(lg);
      }
    }
    se += __shfl_xor(se, 16, 64);
    se += __shfl_xor(se, 32, 64);
    if (g == 0) atomicAdd(&esum[c * 64 + nj * 16 + c0], se);
  }
}

// ---------------- host orchestration ----------------

extern "C" void kernel_launch(void* const* d_in, const int* in_sizes, int n_in,
                              void* d_out, int out_size, void* d_ws, size_t ws_size,
                              hipStream_t stream) {
  (void)in_sizes; (void)n_in; (void)out_size; (void)ws_size;
  const int* text = (const int*)d_in[0];
  const int* w2c  = (const int*)d_in[1];
  const float* sec = (const float*)d_in[2];
  const float* ses = (const float*)d_in[3];
  const float* stc = (const float*)d_in[4];
  const float* sts = (const float*)d_in[5];
  const float* nec = (const float*)d_in[6];
  const float* nes = (const float*)d_in[7];
  const float* pec = (const float*)d_in[8];
  const float* pes = (const float*)d_in[9];
  const float* srw1 = (const float*)d_in[10];
  const float* srb1 = (const float*)d_in[11];
  const float* srw2 = (const float*)d_in[12];
  const float* srb2 = (const float*)d_in[13];
  const float* trw1 = (const float*)d_in[14];
  const float* trb1 = (const float*)d_in[15];
  const float* trw2 = (const float*)d_in[16];
  const float* trb2 = (const float*)d_in[17];
  const float* tew1 = (const float*)d_in[18];
  const float* teb1 = (const float*)d_in[19];
  const float* tew2 = (const float*)d_in[20];
  const float* teb2 = (const float*)d_in[21];
  const float* sow = (const float*)d_in[22];
  const float* sob = (const float*)d_in[23];
  const float* tpw = (const float*)d_in[24];
  const float* tpb = (const float*)d_in[25];
  float* out = (float*)d_out;

  char* p = (char*)d_ws;
  auto carve = [&](size_t bytes) -> char* {
    char* r = p; p += (bytes + 255) & ~(size_t)255; return r;
  };
  u16* Wall = (u16*)carve((size_t)WT2 * 2);
  u16* Wpb  = Wall + WTOT;
  u16* EbS  = (u16*)carve((size_t)CS * HD * 2);
  u16* EbT  = (u16*)carve((size_t)CS * HD * 2);
  u16* NSEb = (u16*)carve((size_t)CS * HD * 2);
  u16* EbP  = (u16*)carve((size_t)CS * HD * 2);
  u16* Hb0  = (u16*)carve((size_t)CS * HD * 2);
  u16* Hb1  = (u16*)carve((size_t)CS * HD * 2);
  u16* Hb2  = (u16*)carve((size_t)CS * HD * 2);
  float* SHf = (float*)carve((size_t)CS * HD * 4);
  u16* Xbf  = (u16*)carve((size_t)CS * HD * 2);
  u16* PHb  = (u16*)carve((size_t)CS * HD * 2);
  float* hlog  = (float*)carve(CS * 4);
  float* part  = (float*)carve((size_t)32 * CS * 4);
  float* rlse  = (float*)carve(CS * 4);
  int* offs    = (int*)carve((KCL + 1) * 4);
  int* wlist   = (int*)carve(VV * 4);
  int* bmap    = (int*)carve(MAXB * 4);
  float* esum  = (float*)carve(CS * 4);
  float* lall  = (float*)carve((size_t)VV * 64 * 4);
  u16*   bufA  = (u16*)carve((size_t)NB * 256 * 4096 * 2);
  u16*   bufB  = (u16*)carve((size_t)NB * 64 * 4096 * 2);
  float* scA   = (float*)carve((size_t)NB * 256 * 4);
  float* scB   = (float*)carve((size_t)NB * 256 * 4);

  // CSR first (tiny): doubles as first-kernel-overhead probe
  csr_k<<<1, 256, 0, stream>>>(w2c, offs, wlist, bmap, esum);

  prep_stream<<<PREPB, 256, 0, stream>>>(
      srw1, srw2, trw1, trw2, tew1, tew2, tpw, Wall,
      sec, ses, EbS, stc, sts, EbT, nec, nes, NSEb, pec, pes, EbP);

  mlp_k<1><<<dim3(4, 128, 3), 256, 0, stream>>>(
      EbS, EbT, EbP, Hb0, Hb1, Hb2, Wall, srb1, trb1, teb1, nullptr, nullptr, nullptr);
  mlp_k<2><<<dim3(4, 128, 3), 256, 0, stream>>>(
      EbS, EbT, EbP, Hb0, Hb1, Hb2, Wall, srb2, trb2, teb2, SHf, Xbf, PHb);

  // transition row-logsumexp: 4 quarter-grids
  for (int q = 0; q < 4; ++q)
    rlse_k<<<256, 512, 0, stream>>>(Xbf, NSEb, part, q);
  hr_k<<<32 + CS / 4, 256, 0, stream>>>(part, rlse, SHf, sow, sob, hlog);

  emis_k<<<MAXB, 256, 0, stream>>>(Wpb, PHb, tpb, offs, wlist, bmap, esum, lall);

  // leaves (standalone blocks, emit inline, identity folded)
  leaf_k<<<dim3(NB * (TT - 1) + NB), 256, 0, stream>>>(
      Xbf, NSEb, rlse, lall, esum, text, w2c, bufA, scA);

  // quad-tree: 256 -> 64 -> 16, then tail (16 -> 4 -> 1 + final)
  comb4_k<<<NB * 64, 256, 0, stream>>>(bufA, scA, bufB, scB, 64);
  comb4_k<<<NB * 16, 256, 0, stream>>>(bufB, scB, bufA, scA, 16);
  tail_k<<<NB, 256, 0, stream>>>(bufA, scA, bufB, scB, hlog, lall, esum, text, w2c, out);
}

// Round 17
// 204.068 us; speedup vs baseline: 1.0920x; 1.0288x over previous
//
#include <hip/hip_runtime.h>
#include <hip/hip_bf16.h>

// FactoredHmmLm forward on MI355X.
//  1. csr_k: fully parallel CSR build (shuffle scans) + esum zero
//  2. prep_stream: grid-stride streaming weight-cvt + NSE embedding only
//  3. residual MLPs: batched mlp_k<1>/<2>; LAYER1 computes embeddings in-register
//     (no EbS/EbT/EbP buffers); LAYER2 recomputes f32 emb for the skip term
//  4. rlse_k: single 1024-block grid, 256x256 tiles, 2D-XCD regions, counted vmcnt
//  5. hr_k: rred + head_dot fused
//  6. emis_k: MFMA 64-word blocks + atomic exp-sum
//  7. leaf_k: standalone leaf GEMMs (emit inline, identity folded)
//  8. comb4 L1 + L2 + tail_k (16 -> 4 -> 1 + hlse + final)

using u16 = unsigned short;
typedef __attribute__((ext_vector_type(8))) short bh8;     // 8 bf16 (4 VGPRs)
typedef __attribute__((ext_vector_type(4))) float f32x4;
typedef __attribute__((ext_vector_type(8))) unsigned short u16x8;

#define HD 256
#define TT 256
#define NB 16
#define KCL 128
#define CS 8192
#define VV 10000
#define MAXB 320
#define LOG2E 1.44269504f
#define WTOT (6 * 65536)
#define WT2  (WTOT + VV * HD)
#define NELEM8 ((WT2 + CS * HD) / 8)         // weights + NSE embedding only
#define PREPB 1024

__device__ __forceinline__ u16 f2bf(float v) {
  union { float f; unsigned int i; } u; u.f = v;
  unsigned int r = u.i + 0x7fffu + ((u.i >> 16) & 1u);   // RNE
  return (u16)(r >> 16);
}
__device__ __forceinline__ float bf2f(u16 u) {
  union { unsigned int i; float f; } x; x.i = ((unsigned int)u) << 16; return x.f;
}
__device__ __forceinline__ void gl2lds16(const u16* g, u16* l) {
  __builtin_amdgcn_global_load_lds(
      (const __attribute__((address_space(1))) unsigned int*)g,
      (__attribute__((address_space(3))) unsigned int*)l, 16, 0, 0);
}
__device__ __forceinline__ u16x8 cvt8(const float* __restrict__ s) {
  const float4 a = *reinterpret_cast<const float4*>(s);
  const float4 b = *reinterpret_cast<const float4*>(s + 4);
  u16x8 o;
  o[0] = f2bf(a.x); o[1] = f2bf(a.y); o[2] = f2bf(a.z); o[3] = f2bf(a.w);
  o[4] = f2bf(b.x); o[5] = f2bf(b.y); o[6] = f2bf(b.z); o[7] = f2bf(b.w);
  return o;
}
__device__ __forceinline__ u16x8 add_cvt8(const float* __restrict__ s0,
                                          const float* __restrict__ s1) {
  const float4 a0 = *reinterpret_cast<const float4*>(s0);
  const float4 b0 = *reinterpret_cast<const float4*>(s0 + 4);
  const float4 a1 = *reinterpret_cast<const float4*>(s1);
  const float4 b1 = *reinterpret_cast<const float4*>(s1 + 4);
  u16x8 o;
  o[0] = f2bf(a0.x + a1.x); o[1] = f2bf(a0.y + a1.y);
  o[2] = f2bf(a0.z + a1.z); o[3] = f2bf(a0.w + a1.w);
  o[4] = f2bf(b0.x + b1.x); o[5] = f2bf(b0.y + b1.y);
  o[6] = f2bf(b0.z + b1.z); o[7] = f2bf(b0.w + b1.w);
  return o;
}

// ---------------- csr_k: fully parallel CSR build + esum zero (1 block) ----------------

__global__ __launch_bounds__(256) void csr_k(const int* __restrict__ w2c,
                                             int* __restrict__ offs,
                                             int* __restrict__ wlist,
                                             int* __restrict__ bmap,
                                             float* __restrict__ esum) {
  __shared__ int cnt[KCL], cur[KCL];
  __shared__ int wsA[2], wsB[2];
  __shared__ int totb_s;
  const int tid = threadIdx.x, lane = tid & 63, w = tid >> 6;

  if (tid < KCL) cnt[tid] = 0;
  __syncthreads();
  for (int v = tid; v < VV; v += 256) atomicAdd(&cnt[w2c[v]], 1);
  __syncthreads();

  int c = 0, x = 0;
  if (tid < KCL) {
    c = cnt[tid];
    x = c;
#pragma unroll
    for (int off = 1; off < 64; off <<= 1) {
      const int y = __shfl_up(x, off, 64);
      if (lane >= off) x += y;
    }
    if (lane == 63) wsA[w] = x;
  }
  __syncthreads();
  int nb = 0, xs = 0;
  if (tid < KCL) {
    const int base = (w == 1) ? wsA[0] : 0;
    const int excl = base + x - c;
    offs[tid] = excl;
    cur[tid] = excl;
    if (tid == KCL - 1) offs[KCL] = base + x;
    nb = (c + 63) >> 6;
    xs = nb;
#pragma unroll
    for (int off = 1; off < 64; off <<= 1) {
      const int y = __shfl_up(xs, off, 64);
      if (lane >= off) xs += y;
    }
    if (lane == 63) wsB[w] = xs;
  }
  __syncthreads();
  if (tid < KCL) {
    const int base = (w == 1) ? wsB[0] : 0;
    const int b0 = base + xs - nb;
    for (int bb = 0; bb < nb; ++bb) bmap[b0 + bb] = (tid << 8) | bb;
    if (tid == KCL - 1) totb_s = base + xs;
  }
  __syncthreads();
  const int totb = totb_s;
  for (int i = totb + tid; i < MAXB; i += 256) bmap[i] = -1;
  for (int v = tid; v < VV; v += 256) {
    const int pos = atomicAdd(&cur[w2c[v]], 1);
    wlist[pos] = v;
  }
  for (int i = tid; i < CS; i += 256) esum[i] = 0.f;
}

// ---------------- prep_stream: weights -> bf16 + NSE embedding ----------------

__global__ __launch_bounds__(256) void prep_stream(
    const float* __restrict__ w0, const float* __restrict__ w1,
    const float* __restrict__ w2, const float* __restrict__ w3,
    const float* __restrict__ w4, const float* __restrict__ w5,
    const float* __restrict__ tpw, u16* __restrict__ dstW,
    const float* __restrict__ nec, const float* __restrict__ nes,
    u16* __restrict__ dNSE) {
  const int b = blockIdx.x, tid = threadIdx.x;
  for (int i = b * 256 + tid; i < NELEM8; i += PREPB * 256) {
    const int idx = i * 8;
    if (idx < WTOT) {
      const int wi = idx >> 16;
      const float* s = wi == 0 ? w0 : wi == 1 ? w1 : wi == 2 ? w2
                     : wi == 3 ? w3 : wi == 4 ? w4 : w5;
      *reinterpret_cast<u16x8*>(dstW + idx) = cvt8(s + (idx & 65535));
    } else if (idx < WT2) {
      *reinterpret_cast<u16x8*>(dstW + idx) = cvt8(tpw + (idx - WTOT));
    } else {
      const int o = idx - WT2;                // 0 .. CS*HD-1
      const int h = o & 255, row = o >> 8;
      const int k = row >> 6, si = row & 63;
      *reinterpret_cast<u16x8*>(dNSE + o) = add_cvt8(nec + k * HD + h, nes + si * HD + h);
    }
  }
}

// ---------------- batched residual-MLP GEMMs (LAYER1: emb computed in-register) --------

template<int LAYER>
__global__ __launch_bounds__(256) void mlp_k(
    const float* __restrict__ ec0, const float* __restrict__ es0,
    const float* __restrict__ ec1, const float* __restrict__ es1,
    const float* __restrict__ ec2, const float* __restrict__ es2,
    u16* __restrict__ H0, u16* __restrict__ H1, u16* __restrict__ H2,
    const u16* __restrict__ Wall,
    const float* __restrict__ bb0, const float* __restrict__ bb1, const float* __restrict__ bb2,
    float* __restrict__ SHf, u16* __restrict__ Xbf, u16* __restrict__ PHb) {
  __shared__ char lds[16384];
  const int tid = threadIdx.x, lane = tid & 63, wid = tid >> 6;
  const int z = blockIdx.z;
  const float* ec = z == 0 ? ec0 : z == 1 ? ec1 : ec2;
  const float* es = z == 0 ? es0 : z == 1 ? es1 : es2;
  u16* Hb = z == 0 ? H0 : z == 1 ? H1 : H2;
  const u16* B = Wall + (size_t)(2 * z + (LAYER - 1)) * 65536;
  const float* bias = z == 0 ? bb0 : z == 1 ? bb1 : bb2;

  const int rm = blockIdx.y * 64, cn = blockIdx.x * 64;
  const u16* Bg = B + (size_t)cn * HD;

  f32x4 acc[4];
#pragma unroll
  for (int i = 0; i < 4; ++i) acc[i] = (f32x4){0.f, 0.f, 0.f, 0.f};
  const int ra = wid * 16 + (lane & 15);
  const int rb0 = lane & 15;
  const int ko = (lane >> 4) * 8;

  for (int kc = 0; kc < HD; kc += 64) {
    if (kc) __syncthreads();
#pragma unroll
    for (int i = 0; i < 2; ++i) {
      const int c = i * 256 + tid;
      const int r = c >> 3, cb = c & 7;
      const int gq = cb ^ (r & 7);
      if (LAYER == 1) {
        // compute emb in-register, write SWIZZLED LDS directly (ds_write path)
        const int grow = rm + r;
        const int krow = grow >> 6, srow = grow & 63;
        const int h0 = kc + cb * 8;
        const u16x8 v = add_cvt8(ec + krow * HD + h0, es + srow * HD + h0);
        *reinterpret_cast<u16x8*>(&lds[r * 128 + ((cb * 16) ^ ((r & 7) << 4))]) = v;
      } else {
        gl2lds16(Hb + (size_t)(rm + r) * HD + kc + gq * 8, (u16*)&lds[c * 16]);
      }
      gl2lds16(Bg + (size_t)r * HD + kc + gq * 8, (u16*)&lds[8192 + c * 16]);
    }
    __syncthreads();
#pragma unroll
    for (int kk = 0; kk < 64; kk += 32) {
      const int kb = (kk + ko) * 2;
      const bh8 af = *reinterpret_cast<const bh8*>(&lds[ra * 128 + (kb ^ ((ra & 7) << 4))]);
#pragma unroll
      for (int nj = 0; nj < 4; ++nj) {
        const int rb = nj * 16 + rb0;
        const bh8 bf = *reinterpret_cast<const bh8*>(&lds[8192 + rb * 128 + (kb ^ ((rb & 7) << 4))]);
        acc[nj] = __builtin_amdgcn_mfma_f32_16x16x32_bf16(af, bf, acc[nj], 0, 0, 0);
      }
    }
  }

  const int g = lane >> 4, c0 = lane & 15;
#pragma unroll
  for (int nj = 0; nj < 4; ++nj) {
    const int nidx = cn + nj * 16 + c0;
    const float bv = bias[nidx];
#pragma unroll
    for (int reg = 0; reg < 4; ++reg) {
      const int midx = rm + wid * 16 + g * 4 + reg;
      float v = acc[nj][reg] + bv;
      if (LAYER == 2)
        v += ec[(midx >> 6) * HD + nidx] + es[(midx & 63) * HD + nidx];
      v = fmaxf(v, 0.f);
      if (LAYER == 1) {
        Hb[(size_t)midx * 256 + nidx] = f2bf(v);
      } else {
        if (z == 0) SHf[(size_t)midx * 256 + nidx] = v;
        else if (z == 1) Xbf[(size_t)midx * 256 + nidx] = f2bf(v);
        else PHb[(size_t)midx * 256 + nidx] = f2bf(v);
      }
    }
  }
}

// ---------------- transition row-lse: 256x256, 2D-XCD regions, counted vmcnt ----------

__global__ __launch_bounds__(512) void rlse_k(const u16* __restrict__ A,
                                              const u16* __restrict__ B,
                                              float* __restrict__ part) {
  __shared__ char lds[131072];
  const int tid = threadIdx.x;
  const int lane = tid & 63, w = tid >> 6;
  const int wr = w >> 2, wc = w & 3;
  const int c0 = lane & 15, g = lane >> 4;

  const int bid = blockIdx.x;                  // 1024 = 32x32 tiles
  const int xcd = bid & 7, idx = bid >> 3;
  const int by = (xcd >> 2) * 16 + (idx >> 3);
  const int bx = (xcd & 3) * 8 + (idx & 7);
  const int rm = by * 256, cn = bx * 256;

  int offA[2][8], offB[2][4];
#pragma unroll
  for (int h = 0; h < 2; ++h) {
    const int kb = (h * 32 + g * 8) * 2;
#pragma unroll
    for (int mi = 0; mi < 8; ++mi) {
      const int ar = wr * 128 + mi * 16 + c0;
      offA[h][mi] = ar * 128 + (kb ^ ((ar & 7) << 4));
    }
#pragma unroll
    for (int nj = 0; nj < 4; ++nj) {
      const int br = wc * 64 + nj * 16 + c0;
      offB[h][nj] = 32768 + br * 128 + (kb ^ ((br & 7) << 4));
    }
  }

  f32x4 acc[8][4];
#pragma unroll
  for (int i = 0; i < 8; ++i)
#pragma unroll
    for (int j = 0; j < 4; ++j) acc[i][j] = (f32x4){0.f, 0.f, 0.f, 0.f};

  auto STAGE = [&](int kt, int hb) {
    const int kc = kt * 64;
    const int bo = hb * 65536;
#pragma unroll
    for (int q = 0; q < 4; ++q) {
      const int c = q * 512 + tid;
      const int r = c >> 3, cb = c & 7;
      const int gq = cb ^ (r & 7);
      gl2lds16(A + (size_t)(rm + r) * HD + kc + gq * 8, (u16*)&lds[bo + c * 16]);
    }
#pragma unroll
    for (int q = 0; q < 4; ++q) {
      const int c = q * 512 + tid;
      const int r = c >> 3, cb = c & 7;
      const int gq = cb ^ (r & 7);
      gl2lds16(B + (size_t)(cn + r) * HD + kc + gq * 8, (u16*)&lds[bo + 32768 + c * 16]);
    }
  };

  STAGE(0, 0);
  STAGE(1, 1);

  for (int kt = 0; kt < 4; ++kt) {
    if (kt < 3) asm volatile("s_waitcnt vmcnt(8)" ::: "memory");
    else        asm volatile("s_waitcnt vmcnt(0)" ::: "memory");
    __builtin_amdgcn_sched_barrier(0);
    __builtin_amdgcn_s_barrier();
    const int bo = (kt & 1) * 65536;
    __builtin_amdgcn_s_setprio(1);
#pragma unroll
    for (int h = 0; h < 2; ++h) {
      bh8 af[8], bf[4];
#pragma unroll
      for (int mi = 0; mi < 8; ++mi)
        af[mi] = *reinterpret_cast<const bh8*>(&lds[bo + offA[h][mi]]);
#pragma unroll
      for (int nj = 0; nj < 4; ++nj)
        bf[nj] = *reinterpret_cast<const bh8*>(&lds[bo + offB[h][nj]]);
#pragma unroll
      for (int mi = 0; mi < 8; ++mi)
#pragma unroll
        for (int nj = 0; nj < 4; ++nj)
          acc[mi][nj] = __builtin_amdgcn_mfma_f32_16x16x32_bf16(af[mi], bf[nj], acc[mi][nj], 0, 0, 0);
    }
    __builtin_amdgcn_s_setprio(0);
    __builtin_amdgcn_s_barrier();
    __builtin_amdgcn_sched_barrier(0);
    if (kt < 2) STAGE(kt + 2, kt & 1);
  }

  float rs[8][4];
#pragma unroll
  for (int mi = 0; mi < 8; ++mi)
#pragma unroll
    for (int reg = 0; reg < 4; ++reg) {
      float s = 0.f;
#pragma unroll
      for (int nj = 0; nj < 4; ++nj) s += exp2f(acc[mi][nj][reg] * LOG2E);
      rs[mi][reg] = s;
    }
#pragma unroll
  for (int off = 1; off < 16; off <<= 1)
#pragma unroll
    for (int mi = 0; mi < 8; ++mi)
#pragma unroll
      for (int reg = 0; reg < 4; ++reg)
        rs[mi][reg] += __shfl_xor(rs[mi][reg], off, 64);

  float* Lf = reinterpret_cast<float*>(lds);
  if (c0 == 0) {
#pragma unroll
    for (int mi = 0; mi < 8; ++mi)
#pragma unroll
      for (int reg = 0; reg < 4; ++reg)
        Lf[(wr * 128 + mi * 16 + g * 4 + reg) * 4 + wc] = rs[mi][reg];
  }
  __syncthreads();
  if (tid < 256)
    part[(size_t)bx * CS + rm + tid] = Lf[tid * 4] + Lf[tid * 4 + 1] + Lf[tid * 4 + 2] + Lf[tid * 4 + 3];
}

// ---------------- fused rred + head_dot ----------------

__global__ __launch_bounds__(256) void hr_k(const float* __restrict__ part,
                                            float* __restrict__ rlse,
                                            const float* __restrict__ sh,
                                            const float* __restrict__ wv,
                                            const float* __restrict__ bv,
                                            float* __restrict__ logits) {
  const int b = blockIdx.x, tid = threadIdx.x;
  if (b < 32) {
    const int i = b * 256 + tid;
    float s = 0.f;
#pragma unroll 8
    for (int bb = 0; bb < 32; ++bb) s += part[(size_t)bb * CS + i];
    rlse[i] = logf(s);
  } else {
    const int lane = tid & 63, wid = tid >> 6;
    const int row = (b - 32) * 4 + wid;
    float s = 0.f;
#pragma unroll
    for (int q = 0; q < 4; ++q)
      s += sh[(size_t)row * HD + q * 64 + lane] * wv[q * 64 + lane];
    for (int off = 32; off; off >>= 1) s += __shfl_xor(s, off, 64);
    if (lane == 0) logits[row] = s + bv[0];
  }
}

// ---------------- leaf-gen GEMM 64x64 (standalone, emit inline) ----------------

__global__ __launch_bounds__(256) void leaf_k(
    const u16* __restrict__ A, const u16* __restrict__ B,
    const float* __restrict__ row_lse,
    const float* __restrict__ lall, const float* __restrict__ esum,
    const int* __restrict__ text, const int* __restrict__ w2c,
    u16* __restrict__ leafb, float* __restrict__ leafsc) {
  __shared__ char lds[16384];
  __shared__ float wmax[4];
  const int tid = threadIdx.x;
  const int lane = tid & 63;
  const int wid = tid >> 6;

  const int bi = blockIdx.x;
  if (bi >= NB * (TT - 1)) {               // identity leaf
    const int n = bi - NB * (TT - 1);
    if (n < NB) {
      u16* node = leafb + ((size_t)n * 256 + 255) * 4096;
      for (int c = tid; c < 4096; c += 256) node[c] = ((c >> 6) == (c & 63)) ? (u16)0x3F80 : (u16)0;
      if (tid == 0) leafsc[n * 256 + 255] = 0.f;
    }
    return;
  }
  const int nn = bi / (TT - 1);
  const int ttv = bi % (TT - 1) + 1;
  const int wcur = text[nn * TT + ttv];
  const int rm = w2c[text[nn * TT + ttv - 1]] * 64;
  const int cn = w2c[wcur] * 64;
  const u16* Ag = A + (size_t)rm * HD;
  const u16* Bg = B + (size_t)cn * HD;

  f32x4 acc[4];
#pragma unroll
  for (int i = 0; i < 4; ++i) acc[i] = (f32x4){0.f, 0.f, 0.f, 0.f};
  const int ra = wid * 16 + (lane & 15);
  const int rb0 = lane & 15;
  const int ko = (lane >> 4) * 8;

  for (int kc = 0; kc < HD; kc += 64) {
    if (kc) __syncthreads();
#pragma unroll
    for (int i = 0; i < 2; ++i) {
      const int c = i * 256 + tid;
      const int r = c >> 3, cb = c & 7;
      const int gq = cb ^ (r & 7);
      gl2lds16(Ag + (size_t)r * HD + kc + gq * 8, (u16*)&lds[c * 16]);
      gl2lds16(Bg + (size_t)r * HD + kc + gq * 8, (u16*)&lds[8192 + c * 16]);
    }
    __syncthreads();
#pragma unroll
    for (int kk = 0; kk < 64; kk += 32) {
      const int kb = (kk + ko) * 2;
      const bh8 af = *reinterpret_cast<const bh8*>(&lds[ra * 128 + (kb ^ ((ra & 7) << 4))]);
#pragma unroll
      for (int nj = 0; nj < 4; ++nj) {
        const int rb = nj * 16 + rb0;
        const bh8 bf = *reinterpret_cast<const bh8*>(&lds[8192 + rb * 128 + (kb ^ ((rb & 7) << 4))]);
        acc[nj] = __builtin_amdgcn_mfma_f32_16x16x32_bf16(af, bf, acc[nj], 0, 0, 0);
      }
    }
  }

  const int g = lane >> 4, c0 = lane & 15;
  float L[4][4];
  float mx = -1e30f;
#pragma unroll
  for (int nj = 0; nj < 4; ++nj) {
    const int col = nj * 16 + c0;
    const float ev = lall[(size_t)wcur * 64 + col] - logf(esum[cn + col]);
#pragma unroll
    for (int reg = 0; reg < 4; ++reg) {
      const float l = acc[nj][reg] - row_lse[rm + wid * 16 + g * 4 + reg] + ev;
      L[nj][reg] = l;
      mx = fmaxf(mx, l);
    }
  }
#pragma unroll
  for (int off = 1; off < 64; off <<= 1) mx = fmaxf(mx, __shfl_xor(mx, off, 64));
  if (lane == 0) wmax[wid] = mx;
  __syncthreads();
  const float m = fmaxf(fmaxf(wmax[0], wmax[1]), fmaxf(wmax[2], wmax[3]));
  float* ftile = reinterpret_cast<float*>(lds);
#pragma unroll
  for (int nj = 0; nj < 4; ++nj)
#pragma unroll
    for (int reg = 0; reg < 4; ++reg)
      ftile[(wid * 16 + g * 4 + reg) * 64 + nj * 16 + c0] = exp2f((L[nj][reg] - m) * LOG2E);
  __syncthreads();
  const int leaf = ttv - 1;
  u16* node = leafb + ((size_t)nn * 256 + leaf) * 4096;
  const int rr = tid >> 2, cb = (tid & 3) * 16;
  u16x8 o0, o1;
  if ((leaf & 1) == 0) {
#pragma unroll
    for (int e = 0; e < 8; ++e) o0[e] = f2bf(ftile[rr * 64 + cb + e]);
#pragma unroll
    for (int e = 0; e < 8; ++e) o1[e] = f2bf(ftile[rr * 64 + cb + 8 + e]);
  } else {
#pragma unroll
    for (int e = 0; e < 8; ++e) o0[e] = f2bf(ftile[(cb + e) * 64 + rr]);
#pragma unroll
    for (int e = 0; e < 8; ++e) o1[e] = f2bf(ftile[(cb + 8 + e) * 64 + rr]);
  }
  *reinterpret_cast<u16x8*>(node + rr * 64 + cb) = o0;
  *reinterpret_cast<u16x8*>(node + rr * 64 + cb + 8) = o1;
  if (tid == 0) leafsc[nn * 256 + leaf] = m;
}

// ---------------- quad combine (stage + core) ----------------

__device__ __forceinline__ void comb4_stage(
    char* lds, const u16* s0, const u16* s1, const u16* s2, const u16* s3, int tid) {
  const u16* srcs[4] = {s0, s1, s2, s3};
  const int sr = tid >> 3, scb = (tid & 7) * 16;
#pragma unroll
  for (int nd = 0; nd < 4; ++nd)
#pragma unroll
    for (int rep = 0; rep < 2; ++rep) {
      const int r = rep * 32 + sr;
      const bh8 v = *reinterpret_cast<const bh8*>(srcs[nd] + r * 64 + (scb >> 1));
      *reinterpret_cast<bh8*>(&lds[nd * 8192 + r * 128 + (scb ^ ((r & 7) << 4))]) = v;
    }
  __syncthreads();
}

__device__ __forceinline__ void comb4_core(
    char* lds, float* wpm,
    float sc0, float sc1, float sc2, float sc3,
    u16* node, float* dsc, int parity, int tid) {
  const int lane = tid & 63, w = tid >> 6;
  const int p = w >> 1, h = w & 1;
  const int abase = p * 16384, bbase = abase + 8192;
  const int c0 = lane & 15, g = lane >> 4;
  f32x4 a2[2][4];
#pragma unroll
  for (int mi = 0; mi < 2; ++mi)
#pragma unroll
    for (int nj = 0; nj < 4; ++nj) a2[mi][nj] = (f32x4){0.f, 0.f, 0.f, 0.f};
#pragma unroll
  for (int kk = 0; kk < 64; kk += 32) {
    const int kb = (kk + g * 8) * 2;
    bh8 af[2], bf[4];
#pragma unroll
    for (int mi = 0; mi < 2; ++mi) {
      const int ar = h * 32 + mi * 16 + c0;
      af[mi] = *reinterpret_cast<const bh8*>(&lds[abase + ar * 128 + (kb ^ ((ar & 7) << 4))]);
    }
#pragma unroll
    for (int nj = 0; nj < 4; ++nj) {
      const int br = nj * 16 + c0;
      bf[nj] = *reinterpret_cast<const bh8*>(&lds[bbase + br * 128 + (kb ^ ((br & 7) << 4))]);
    }
#pragma unroll
    for (int mi = 0; mi < 2; ++mi)
#pragma unroll
      for (int nj = 0; nj < 4; ++nj)
        a2[mi][nj] = __builtin_amdgcn_mfma_f32_16x16x32_bf16(af[mi], bf[nj], a2[mi][nj], 0, 0, 0);
  }
  float mx = 0.f;
#pragma unroll
  for (int mi = 0; mi < 2; ++mi)
#pragma unroll
    for (int nj = 0; nj < 4; ++nj)
#pragma unroll
      for (int reg = 0; reg < 4; ++reg) mx = fmaxf(mx, a2[mi][nj][reg]);
#pragma unroll
  for (int off = 1; off < 64; off <<= 1) mx = fmaxf(mx, __shfl_xor(mx, off, 64));
  if (lane == 0) wpm[w] = mx;
  __syncthreads();
  const float mp = fmaxf(wpm[p * 2], wpm[p * 2 + 1]);
  const float invp = 1.0f / mp;
#pragma unroll
  for (int mi = 0; mi < 2; ++mi)
#pragma unroll
    for (int nj = 0; nj < 4; ++nj)
#pragma unroll
      for (int reg = 0; reg < 4; ++reg) {
        const int row = h * 32 + mi * 16 + g * 4 + reg;
        const int col = nj * 16 + c0;
        const u16 val = f2bf(a2[mi][nj][reg] * invp);
        if (p == 0)
          *reinterpret_cast<u16*>(&lds[32768 + row * 128 + ((col * 2) ^ ((row & 7) << 4))]) = val;
        else
          *reinterpret_cast<u16*>(&lds[40960 + col * 128 + ((row * 2) ^ ((col & 7) << 4))]) = val;
      }
  __syncthreads();

  f32x4 acc[4];
#pragma unroll
  for (int i = 0; i < 4; ++i) acc[i] = (f32x4){0.f, 0.f, 0.f, 0.f};
  const int ra = w * 16 + c0;
#pragma unroll
  for (int kk = 0; kk < 64; kk += 32) {
    const int kb = (kk + g * 8) * 2;
    const bh8 af = *reinterpret_cast<const bh8*>(&lds[32768 + ra * 128 + (kb ^ ((ra & 7) << 4))]);
#pragma unroll
    for (int nj = 0; nj < 4; ++nj) {
      const int rb = nj * 16 + c0;
      const bh8 bf = *reinterpret_cast<const bh8*>(&lds[40960 + rb * 128 + (kb ^ ((rb & 7) << 4))]);
      acc[nj] = __builtin_amdgcn_mfma_f32_16x16x32_bf16(af, bf, acc[nj], 0, 0, 0);
    }
  }
  float mx2 = 0.f;
#pragma unroll
  for (int nj = 0; nj < 4; ++nj)
#pragma unroll
    for (int reg = 0; reg < 4; ++reg) mx2 = fmaxf(mx2, acc[nj][reg]);
#pragma unroll
  for (int off = 1; off < 64; off <<= 1) mx2 = fmaxf(mx2, __shfl_xor(mx2, off, 64));
  if (lane == 0) wpm[4 + w] = mx2;
  __syncthreads();
  const float m = fmaxf(fmaxf(wpm[4], wpm[5]), fmaxf(wpm[6], wpm[7]));
  const float inv = 1.0f / m;
  float* ftile = reinterpret_cast<float*>(lds);
#pragma unroll
  for (int nj = 0; nj < 4; ++nj)
#pragma unroll
    for (int reg = 0; reg < 4; ++reg)
      ftile[(w * 16 + g * 4 + reg) * 64 + nj * 16 + c0] = acc[nj][reg] * inv;
  __syncthreads();
  const int rr = tid >> 2, cb = (tid & 3) * 16;
  u16x8 o0, o1;
  if (parity == 0) {
#pragma unroll
    for (int e = 0; e < 8; ++e) o0[e] = f2bf(ftile[rr * 64 + cb + e]);
#pragma unroll
    for (int e = 0; e < 8; ++e) o1[e] = f2bf(ftile[rr * 64 + cb + 8 + e]);
  } else {
#pragma unroll
    for (int e = 0; e < 8; ++e) o0[e] = f2bf(ftile[(cb + e) * 64 + rr]);
#pragma unroll
    for (int e = 0; e < 8; ++e) o1[e] = f2bf(ftile[(cb + 8 + e) * 64 + rr]);
  }
  *reinterpret_cast<u16x8*>(node + rr * 64 + cb) = o0;
  *reinterpret_cast<u16x8*>(node + rr * 64 + cb + 8) = o1;
  if (tid == 0)
    *dsc = sc0 + sc1 + sc2 + sc3
         + logf(fmaxf(wpm[0], wpm[1])) + logf(fmaxf(wpm[2], wpm[3])) + logf(m);
}

__global__ __launch_bounds__(256) void comb4_k(const u16* __restrict__ src,
                                               const float* __restrict__ scs,
                                               u16* __restrict__ dst,
                                               float* __restrict__ scd, int U) {
  const int n = blockIdx.x / U, u = blockIdx.x % U;
  __shared__ char lds[49152];
  __shared__ float wpm[8];
  const u16* base = src + ((size_t)(n * 4 * U + 4 * u)) * 4096;
  const float* sb = scs + n * 4 * U + 4 * u;
  comb4_stage(lds, base, base + 4096, base + 2 * 4096, base + 3 * 4096, threadIdx.x);
  comb4_core(lds, wpm, sb[0], sb[1], sb[2], sb[3],
             dst + ((size_t)(n * U + u)) * 4096, &scd[n * U + u], u & 1, threadIdx.x);
}

// ---------------- tail: 16 -> 4 -> 1 + hlse + final ----------------

__global__ __launch_bounds__(256) void tail_k(
    const u16* __restrict__ nodes, const float* __restrict__ nsc,
    u16* __restrict__ scratch, float* __restrict__ ssc,
    const float* __restrict__ hlog, const float* __restrict__ lall,
    const float* __restrict__ esum, const int* __restrict__ text,
    const int* __restrict__ w2c, float* __restrict__ out) {
  __shared__ char lds[49152];
  __shared__ float wpm[8];
  __shared__ float redm[4];
  __shared__ float hl_s;
  const int n = blockIdx.x, tid = threadIdx.x;
  const int lane = tid & 63, w = tid >> 6;

  float mm = -1e30f;
  for (int i = tid; i < CS; i += 256) mm = fmaxf(mm, hlog[i]);
  for (int off = 32; off; off >>= 1) mm = fmaxf(mm, __shfl_xor(mm, off, 64));
  if (lane == 0) redm[w] = mm;
  __syncthreads();
  const float M = fmaxf(fmaxf(redm[0], redm[1]), fmaxf(redm[2], redm[3]));
  float sx = 0.f;
  for (int i = tid; i < CS; i += 256) sx += expf(hlog[i] - M);
  for (int off = 32; off; off >>= 1) sx += __shfl_xor(sx, off, 64);
  __syncthreads();
  if (lane == 0) redm[w] = sx;
  __syncthreads();
  if (tid == 0) hl_s = M + logf(redm[0] + redm[1] + redm[2] + redm[3]);
  __syncthreads();
  const float hlse = hl_s;

  const u16* src = nodes + (size_t)n * 16 * 4096;
  const float* sc = nsc + n * 16;
  u16* scr = scratch + (size_t)n * 64 * 4096;
  float* scs = ssc + n * 64;
  for (int i = 0; i < 4; ++i) {
    comb4_stage(lds, src + (size_t)(4 * i) * 4096, src + (size_t)(4 * i + 1) * 4096,
                src + (size_t)(4 * i + 2) * 4096, src + (size_t)(4 * i + 3) * 4096, tid);
    comb4_core(lds, wpm, sc[4 * i], sc[4 * i + 1], sc[4 * i + 2], sc[4 * i + 3],
               scr + (size_t)i * 4096, &scs[i], i & 1, tid);
    __syncthreads();
  }
  comb4_stage(lds, scr, scr + 4096, scr + 2 * 4096, scr + 3 * 4096, tid);
  comb4_core(lds, wpm, scs[0], scs[1], scs[2], scs[3], scr + 4 * 4096, &scs[4], 0, tid);
  __syncthreads();

  if (tid < 64) {
    const int i = tid;
    const int w0 = text[n * TT];
    const int cc = w2c[w0];
    const float ev = lall[(size_t)w0 * 64 + i] - logf(esum[cc * 64 + i]);
    float a0 = hlog[cc * 64 + i] - hlse + ev;
    float m0 = a0;
    for (int off = 32; off; off >>= 1) m0 = fmaxf(m0, __shfl_xor(m0, off, 64));
    const float lin = expf(a0 - m0);
    const u16* row = scr + 4 * 4096 + i * 64;
    float rs = 0.f;
#pragma unroll
    for (int e8 = 0; e8 < 8; ++e8) {
      const u16x8 v = *reinterpret_cast<const u16x8*>(row + e8 * 8);
#pragma unroll
      for (int e = 0; e < 8; ++e) rs += bf2f(v[e]);
    }
    float v = lin * rs;
    for (int off = 32; off; off >>= 1) v += __shfl_xor(v, off, 64);
    if (i == 0) out[n] = m0 + scs[4] + logf(v);
  }
}

// ---------------- emission GEMM ----------------

__global__ __launch_bounds__(256) void emis_k(
    const u16* __restrict__ Wpb, const u16* __restrict__ PHb,
    const float* __restrict__ bp,
    const int* __restrict__ offs, const int* __restrict__ wlist,
    const int* __restrict__ map,
    float* __restrict__ esum, float* __restrict__ logits_all) {
  const int ent = map[blockIdx.x];
  if (ent < 0) return;
  const int c = ent >> 8, blk = ent & 255;
  __shared__ char lds[16384];
  __shared__ int wid_s[64];
  const int tid = threadIdx.x, lane = tid & 63, wid = tid >> 6;
  const int st = offs[c], cnt = offs[c + 1] - st;
  if (tid < 64) {
    const int idx = blk * 64 + tid;
    wid_s[tid] = (idx < cnt) ? wlist[st + idx] : -1;
  }
  __syncthreads();

  f32x4 acc[4];
#pragma unroll
  for (int i = 0; i < 4; ++i) acc[i] = (f32x4){0.f, 0.f, 0.f, 0.f};

  const int ra = wid * 16 + (lane & 15);
  const int rb0 = lane & 15;
  const int ko = (lane >> 4) * 8;
  const u16* Bg = PHb + (size_t)(c * 64) * HD;

  for (int kc = 0; kc < HD; kc += 64) {
    if (kc) __syncthreads();
#pragma unroll
    for (int i = 0; i < 2; ++i) {
      const int cc = i * 256 + tid;
      const int r = cc >> 3, cb = cc & 7;
      const int gq = cb ^ (r & 7);
      const int wv = max(wid_s[r], 0);
      gl2lds16(Wpb + (size_t)wv * HD + kc + gq * 8, (u16*)&lds[cc * 16]);
      gl2lds16(Bg + (size_t)r * HD + kc + gq * 8, (u16*)&lds[8192 + cc * 16]);
    }
    __syncthreads();
#pragma unroll
    for (int kk = 0; kk < 64; kk += 32) {
      const int kb = (kk + ko) * 2;
      const bh8 af = *reinterpret_cast<const bh8*>(&lds[ra * 128 + (kb ^ ((ra & 7) << 4))]);
#pragma unroll
      for (int nj = 0; nj < 4; ++nj) {
        const int rb = nj * 16 + rb0;
        const bh8 bf = *reinterpret_cast<const bh8*>(&lds[8192 + rb * 128 + (kb ^ ((rb & 7) << 4))]);
        acc[nj] = __builtin_amdgcn_mfma_f32_16x16x32_bf16(af, bf, acc[nj], 0, 0, 0);
      }
    }
  }

  const int g = lane >> 4, c0 = lane & 15;
#pragma unroll
  for (int nj = 0; nj < 4; ++nj) {
    float se = 0.f;
#pragma unroll
    for (int reg = 0; reg < 4; ++reg) {
      const int row = wid * 16 + g * 4 + reg;
      const int w = wid_s[row];
      if (w >= 0) {
        const float lg = acc[nj][reg] + bp[w];
        logits_all[(size_t)w * 64 + nj * 16 + c0] = lg;
        se += expf(lg);
      }
    }
    se += __shfl_xor(se, 16, 64);
    se += __shfl_xor(se, 32, 64);
    if (g == 0) atomicAdd(&esum[c * 64 + nj * 16 + c0], se);
  }
}

// ---------------- host orchestration ----------------

extern "C" void kernel_launch(void* const* d_in, const int* in_sizes, int n_in,
                              void* d_out, int out_size, void* d_ws, size_t ws_size,
                              hipStream_t stream) {
  (void)in_sizes; (void)n_in; (void)out_size; (void)ws_size;
  const int* text = (const int*)d_in[0];
  const int* w2c  = (const int*)d_in[1];
  const float* sec = (const float*)d_in[2];
  const float* ses = (const float*)d_in[3];
  const float* stc = (const float*)d_in[4];
  const float* sts = (const float*)d_in[5];
  const float* nec = (const float*)d_in[6];
  const float* nes = (const float*)d_in[7];
  const float* pec = (const float*)d_in[8];
  const float* pes = (const float*)d_in[9];
  const float* srw1 = (const float*)d_in[10];
  const float* srb1 = (const float*)d_in[11];
  const float* srw2 = (const float*)d_in[12];
  const float* srb2 = (const float*)d_in[13];
  const float* trw1 = (const float*)d_in[14];
  const float* trb1 = (const float*)d_in[15];
  const float* trw2 = (const float*)d_in[16];
  const float* trb2 = (const float*)d_in[17];
  const float* tew1 = (const float*)d_in[18];
  const float* teb1 = (const float*)d_in[19];
  const float* tew2 = (const float*)d_in[20];
  const float* teb2 = (const float*)d_in[21];
  const float* sow = (const float*)d_in[22];
  const float* sob = (const float*)d_in[23];
  const float* tpw = (const float*)d_in[24];
  const float* tpb = (const float*)d_in[25];
  float* out = (float*)d_out;

  char* p = (char*)d_ws;
  auto carve = [&](size_t bytes) -> char* {
    char* r = p; p += (bytes + 255) & ~(size_t)255; return r;
  };
  u16* Wall = (u16*)carve((size_t)WT2 * 2);
  u16* Wpb  = Wall + WTOT;
  u16* NSEb = (u16*)carve((size_t)CS * HD * 2);
  u16* Hb0  = (u16*)carve((size_t)CS * HD * 2);
  u16* Hb1  = (u16*)carve((size_t)CS * HD * 2);
  u16* Hb2  = (u16*)carve((size_t)CS * HD * 2);
  float* SHf = (float*)carve((size_t)CS * HD * 4);
  u16* Xbf  = (u16*)carve((size_t)CS * HD * 2);
  u16* PHb  = (u16*)carve((size_t)CS * HD * 2);
  float* hlog  = (float*)carve(CS * 4);
  float* part  = (float*)carve((size_t)32 * CS * 4);
  float* rlse  = (float*)carve(CS * 4);
  int* offs    = (int*)carve((KCL + 1) * 4);
  int* wlist   = (int*)carve(VV * 4);
  int* bmap    = (int*)carve(MAXB * 4);
  float* esum  = (float*)carve(CS * 4);
  float* lall  = (float*)carve((size_t)VV * 64 * 4);
  u16*   bufA  = (u16*)carve((size_t)NB * 256 * 4096 * 2);
  u16*   bufB  = (u16*)carve((size_t)NB * 64 * 4096 * 2);
  float* scA   = (float*)carve((size_t)NB * 256 * 4);
  float* scB   = (float*)carve((size_t)NB * 256 * 4);

  csr_k<<<1, 256, 0, stream>>>(w2c, offs, wlist, bmap, esum);

  prep_stream<<<PREPB, 256, 0, stream>>>(
      srw1, srw2, trw1, trw2, tew1, tew2, tpw, Wall, nec, nes, NSEb);

  mlp_k<1><<<dim3(4, 128, 3), 256, 0, stream>>>(
      sec, ses, stc, sts, pec, pes, Hb0, Hb1, Hb2, Wall,
      srb1, trb1, teb1, nullptr, nullptr, nullptr);
  mlp_k<2><<<dim3(4, 128, 3), 256, 0, stream>>>(
      sec, ses, stc, sts, pec, pes, Hb0, Hb1, Hb2, Wall,
      srb2, trb2, teb2, SHf, Xbf, PHb);

  rlse_k<<<1024, 512, 0, stream>>>(Xbf, NSEb, part);
  hr_k<<<32 + CS / 4, 256, 0, stream>>>(part, rlse, SHf, sow, sob, hlog);

  emis_k<<<MAXB, 256, 0, stream>>>(Wpb, PHb, tpb, offs, wlist, bmap, esum, lall);

  leaf_k<<<dim3(NB * (TT - 1) + NB), 256, 0, stream>>>(
      Xbf, NSEb, rlse, lall, esum, text, w2c, bufA, scA);

  comb4_k<<<NB * 64, 256, 0, stream>>>(bufA, scA, bufB, scB, 64);
  comb4_k<<<NB * 16, 256, 0, stream>>>(bufB, scB, bufA, scA, 16);
  tail_k<<<NB, 256, 0, stream>>>(bufA, scA, bufB, scB, hlog, lall, esum, text, w2c, out);
}

// Round 18
// 150.069 us; speedup vs baseline: 1.4850x; 1.3598x over previous
//
#include <hip/hip_runtime.h>
#include <hip/hip_bf16.h>

// FactoredHmmLm forward on MI355X.
// KEY ALGEBRA: nse[k*64+s] = nec[k]+nes[s]  =>  tr[i,k*64+s] = T1[i,k]+T2[i,s]
//   => rlse[i] = lse_k(T1) + lse_s(T2)   (exact; kills the 8192^2 GEMM)
//   => leaf tile(cp,cc)[r][s] = T1[rm+r,cc]+T2[rm+r,s]  (elementwise; kills leaf GEMMs)
//  1. csr_k: parallel CSR build + esum zero
//  2. prep_stream: weights -> bf16 only
//  3. mlp_k<1>/<2>: batched residual MLPs (LAYER1 computes embeddings in-register)
//  4. t12_k: T12 = X @ [nec;nes]^T (8192x192) + rlse  (one small MFMA GEMM)
//  5. hd_k: start-head dot
//  6. emis_k: MFMA 64-word blocks + atomic exp-sum
//  7. leaf2_k: ELEMENTWISE leaf build from T12 (+ identity leaves)
//  8. comb4 L1 + L2 + tail_k (16 -> 4 -> 1 + hlse + final)

using u16 = unsigned short;
typedef __attribute__((ext_vector_type(8))) short bh8;     // 8 bf16 (4 VGPRs)
typedef __attribute__((ext_vector_type(4))) float f32x4;
typedef __attribute__((ext_vector_type(8))) unsigned short u16x8;

#define HD 256
#define TT 256
#define NB 16
#define KCL 128
#define CS 8192
#define VV 10000
#define MAXB 320
#define LOG2E 1.44269504f
#define WTOT (6 * 65536)
#define WT2  (WTOT + VV * HD)
#define NELEM8 (WT2 / 8)                     // weights only
#define PREPB 1024

__device__ __forceinline__ u16 f2bf(float v) {
  union { float f; unsigned int i; } u; u.f = v;
  unsigned int r = u.i + 0x7fffu + ((u.i >> 16) & 1u);   // RNE
  return (u16)(r >> 16);
}
__device__ __forceinline__ float bf2f(u16 u) {
  union { unsigned int i; float f; } x; x.i = ((unsigned int)u) << 16; return x.f;
}
__device__ __forceinline__ void gl2lds16(const u16* g, u16* l) {
  __builtin_amdgcn_global_load_lds(
      (const __attribute__((address_space(1))) unsigned int*)g,
      (__attribute__((address_space(3))) unsigned int*)l, 16, 0, 0);
}
__device__ __forceinline__ u16x8 cvt8(const float* __restrict__ s) {
  const float4 a = *reinterpret_cast<const float4*>(s);
  const float4 b = *reinterpret_cast<const float4*>(s + 4);
  u16x8 o;
  o[0] = f2bf(a.x); o[1] = f2bf(a.y); o[2] = f2bf(a.z); o[3] = f2bf(a.w);
  o[4] = f2bf(b.x); o[5] = f2bf(b.y); o[6] = f2bf(b.z); o[7] = f2bf(b.w);
  return o;
}
__device__ __forceinline__ u16x8 add_cvt8(const float* __restrict__ s0,
                                          const float* __restrict__ s1) {
  const float4 a0 = *reinterpret_cast<const float4*>(s0);
  const float4 b0 = *reinterpret_cast<const float4*>(s0 + 4);
  const float4 a1 = *reinterpret_cast<const float4*>(s1);
  const float4 b1 = *reinterpret_cast<const float4*>(s1 + 4);
  u16x8 o;
  o[0] = f2bf(a0.x + a1.x); o[1] = f2bf(a0.y + a1.y);
  o[2] = f2bf(a0.z + a1.z); o[3] = f2bf(a0.w + a1.w);
  o[4] = f2bf(b0.x + b1.x); o[5] = f2bf(b0.y + b1.y);
  o[6] = f2bf(b0.z + b1.z); o[7] = f2bf(b0.w + b1.w);
  return o;
}

// ---------------- csr_k ----------------

__global__ __launch_bounds__(256) void csr_k(const int* __restrict__ w2c,
                                             int* __restrict__ offs,
                                             int* __restrict__ wlist,
                                             int* __restrict__ bmap,
                                             float* __restrict__ esum) {
  __shared__ int cnt[KCL], cur[KCL];
  __shared__ int wsA[2], wsB[2];
  __shared__ int totb_s;
  const int tid = threadIdx.x, lane = tid & 63, w = tid >> 6;

  if (tid < KCL) cnt[tid] = 0;
  __syncthreads();
  for (int v = tid; v < VV; v += 256) atomicAdd(&cnt[w2c[v]], 1);
  __syncthreads();

  int c = 0, x = 0;
  if (tid < KCL) {
    c = cnt[tid];
    x = c;
#pragma unroll
    for (int off = 1; off < 64; off <<= 1) {
      const int y = __shfl_up(x, off, 64);
      if (lane >= off) x += y;
    }
    if (lane == 63) wsA[w] = x;
  }
  __syncthreads();
  int nb = 0, xs = 0;
  if (tid < KCL) {
    const int base = (w == 1) ? wsA[0] : 0;
    const int excl = base + x - c;
    offs[tid] = excl;
    cur[tid] = excl;
    if (tid == KCL - 1) offs[KCL] = base + x;
    nb = (c + 63) >> 6;
    xs = nb;
#pragma unroll
    for (int off = 1; off < 64; off <<= 1) {
      const int y = __shfl_up(xs, off, 64);
      if (lane >= off) xs += y;
    }
    if (lane == 63) wsB[w] = xs;
  }
  __syncthreads();
  if (tid < KCL) {
    const int base = (w == 1) ? wsB[0] : 0;
    const int b0 = base + xs - nb;
    for (int bb = 0; bb < nb; ++bb) bmap[b0 + bb] = (tid << 8) | bb;
    if (tid == KCL - 1) totb_s = base + xs;
  }
  __syncthreads();
  const int totb = totb_s;
  for (int i = totb + tid; i < MAXB; i += 256) bmap[i] = -1;
  for (int v = tid; v < VV; v += 256) {
    const int pos = atomicAdd(&cur[w2c[v]], 1);
    wlist[pos] = v;
  }
  for (int i = tid; i < CS; i += 256) esum[i] = 0.f;
}

// ---------------- prep_stream: weights -> bf16 only ----------------

__global__ __launch_bounds__(256) void prep_stream(
    const float* __restrict__ w0, const float* __restrict__ w1,
    const float* __restrict__ w2, const float* __restrict__ w3,
    const float* __restrict__ w4, const float* __restrict__ w5,
    const float* __restrict__ tpw, u16* __restrict__ dstW) {
  const int b = blockIdx.x, tid = threadIdx.x;
  for (int i = b * 256 + tid; i < NELEM8; i += PREPB * 256) {
    const int idx = i * 8;
    if (idx < WTOT) {
      const int wi = idx >> 16;
      const float* s = wi == 0 ? w0 : wi == 1 ? w1 : wi == 2 ? w2
                     : wi == 3 ? w3 : wi == 4 ? w4 : w5;
      *reinterpret_cast<u16x8*>(dstW + idx) = cvt8(s + (idx & 65535));
    } else {
      *reinterpret_cast<u16x8*>(dstW + idx) = cvt8(tpw + (idx - WTOT));
    }
  }
}

// ---------------- batched residual-MLP GEMMs (LAYER1: emb in-register) --------

template<int LAYER>
__global__ __launch_bounds__(256) void mlp_k(
    const float* __restrict__ ec0, const float* __restrict__ es0,
    const float* __restrict__ ec1, const float* __restrict__ es1,
    const float* __restrict__ ec2, const float* __restrict__ es2,
    u16* __restrict__ H0, u16* __restrict__ H1, u16* __restrict__ H2,
    const u16* __restrict__ Wall,
    const float* __restrict__ bb0, const float* __restrict__ bb1, const float* __restrict__ bb2,
    float* __restrict__ SHf, u16* __restrict__ Xbf, u16* __restrict__ PHb) {
  __shared__ char lds[16384];
  const int tid = threadIdx.x, lane = tid & 63, wid = tid >> 6;
  const int z = blockIdx.z;
  const float* ec = z == 0 ? ec0 : z == 1 ? ec1 : ec2;
  const float* es = z == 0 ? es0 : z == 1 ? es1 : es2;
  u16* Hb = z == 0 ? H0 : z == 1 ? H1 : H2;
  const u16* B = Wall + (size_t)(2 * z + (LAYER - 1)) * 65536;
  const float* bias = z == 0 ? bb0 : z == 1 ? bb1 : bb2;

  const int rm = blockIdx.y * 64, cn = blockIdx.x * 64;
  const u16* Bg = B + (size_t)cn * HD;

  f32x4 acc[4];
#pragma unroll
  for (int i = 0; i < 4; ++i) acc[i] = (f32x4){0.f, 0.f, 0.f, 0.f};
  const int ra = wid * 16 + (lane & 15);
  const int rb0 = lane & 15;
  const int ko = (lane >> 4) * 8;

  for (int kc = 0; kc < HD; kc += 64) {
    if (kc) __syncthreads();
#pragma unroll
    for (int i = 0; i < 2; ++i) {
      const int c = i * 256 + tid;
      const int r = c >> 3, cb = c & 7;
      const int gq = cb ^ (r & 7);
      if (LAYER == 1) {
        const int grow = rm + r;
        const int krow = grow >> 6, srow = grow & 63;
        const int h0 = kc + cb * 8;
        const u16x8 v = add_cvt8(ec + krow * HD + h0, es + srow * HD + h0);
        *reinterpret_cast<u16x8*>(&lds[r * 128 + ((cb * 16) ^ ((r & 7) << 4))]) = v;
      } else {
        gl2lds16(Hb + (size_t)(rm + r) * HD + kc + gq * 8, (u16*)&lds[c * 16]);
      }
      gl2lds16(Bg + (size_t)r * HD + kc + gq * 8, (u16*)&lds[8192 + c * 16]);
    }
    __syncthreads();
#pragma unroll
    for (int kk = 0; kk < 64; kk += 32) {
      const int kb = (kk + ko) * 2;
      const bh8 af = *reinterpret_cast<const bh8*>(&lds[ra * 128 + (kb ^ ((ra & 7) << 4))]);
#pragma unroll
      for (int nj = 0; nj < 4; ++nj) {
        const int rb = nj * 16 + rb0;
        const bh8 bf = *reinterpret_cast<const bh8*>(&lds[8192 + rb * 128 + (kb ^ ((rb & 7) << 4))]);
        acc[nj] = __builtin_amdgcn_mfma_f32_16x16x32_bf16(af, bf, acc[nj], 0, 0, 0);
      }
    }
  }

  const int g = lane >> 4, c0 = lane & 15;
#pragma unroll
  for (int nj = 0; nj < 4; ++nj) {
    const int nidx = cn + nj * 16 + c0;
    const float bv = bias[nidx];
#pragma unroll
    for (int reg = 0; reg < 4; ++reg) {
      const int midx = rm + wid * 16 + g * 4 + reg;
      float v = acc[nj][reg] + bv;
      if (LAYER == 2)
        v += ec[(midx >> 6) * HD + nidx] + es[(midx & 63) * HD + nidx];
      v = fmaxf(v, 0.f);
      if (LAYER == 1) {
        Hb[(size_t)midx * 256 + nidx] = f2bf(v);
      } else {
        if (z == 0) SHf[(size_t)midx * 256 + nidx] = v;
        else if (z == 1) Xbf[(size_t)midx * 256 + nidx] = f2bf(v);
        else PHb[(size_t)midx * 256 + nidx] = f2bf(v);
      }
    }
  }
}

// ---------------- t12_k: T12 = X @ [nec;nes]^T (8192x192) + rlse ----------------

__global__ __launch_bounds__(256) void t12_k(
    const u16* __restrict__ Xbf, const float* __restrict__ nec,
    const float* __restrict__ nes,
    float* __restrict__ T12, float* __restrict__ rlse) {
  __shared__ char lds[32768];   // A 8KB @0 | B 24KB @8192 (192 rows x 128B)
  const int tid = threadIdx.x, lane = tid & 63, wid = tid >> 6;
  const int rm = blockIdx.x * 64;
  const int ra = wid * 16 + (lane & 15);
  const int rb0 = lane & 15;
  const int ko = (lane >> 4) * 8;

  f32x4 acc[12];
#pragma unroll
  for (int i = 0; i < 12; ++i) acc[i] = (f32x4){0.f, 0.f, 0.f, 0.f};

  for (int kc = 0; kc < HD; kc += 64) {
    if (kc) __syncthreads();
#pragma unroll
    for (int i = 0; i < 2; ++i) {
      const int c = i * 256 + tid;
      const int r = c >> 3, cb = c & 7;
      const int gq = cb ^ (r & 7);
      gl2lds16(Xbf + (size_t)(rm + r) * HD + kc + gq * 8, (u16*)&lds[c * 16]);
    }
#pragma unroll
    for (int i = 0; i < 6; ++i) {
      const int c = i * 256 + tid;          // 0..1535 -> 192 rows x 8 chunks
      const int r = c >> 3, cb = c & 7;
      const float* src = (r < KCL) ? (nec + r * HD + kc + cb * 8)
                                   : (nes + (r - KCL) * HD + kc + cb * 8);
      const u16x8 v = cvt8(src);
      *reinterpret_cast<u16x8*>(&lds[8192 + r * 128 + ((cb * 16) ^ ((r & 7) << 4))]) = v;
    }
    __syncthreads();
#pragma unroll
    for (int kk = 0; kk < 64; kk += 32) {
      const int kb = (kk + ko) * 2;
      const bh8 af = *reinterpret_cast<const bh8*>(&lds[ra * 128 + (kb ^ ((ra & 7) << 4))]);
#pragma unroll
      for (int nj = 0; nj < 12; ++nj) {
        const int rb = nj * 16 + rb0;
        const bh8 bf = *reinterpret_cast<const bh8*>(&lds[8192 + rb * 128 + (kb ^ ((rb & 7) << 4))]);
        acc[nj] = __builtin_amdgcn_mfma_f32_16x16x32_bf16(af, bf, acc[nj], 0, 0, 0);
      }
    }
  }

  const int g = lane >> 4, c0 = lane & 15;
  float rs1[4] = {0.f, 0.f, 0.f, 0.f};
  float rs2[4] = {0.f, 0.f, 0.f, 0.f};
#pragma unroll
  for (int nj = 0; nj < 12; ++nj) {
    const int col = nj * 16 + c0;
#pragma unroll
    for (int reg = 0; reg < 4; ++reg) {
      const int row = rm + wid * 16 + g * 4 + reg;
      const float v = acc[nj][reg];
      T12[(size_t)row * 192 + col] = v;
      const float e = exp2f(v * LOG2E);
      if (nj < 8) rs1[reg] += e; else rs2[reg] += e;
    }
  }
#pragma unroll
  for (int off = 1; off < 16; off <<= 1)
#pragma unroll
    for (int reg = 0; reg < 4; ++reg) {
      rs1[reg] += __shfl_xor(rs1[reg], off, 64);
      rs2[reg] += __shfl_xor(rs2[reg], off, 64);
    }
  if (c0 == 0) {
#pragma unroll
    for (int reg = 0; reg < 4; ++reg)
      rlse[rm + wid * 16 + g * 4 + reg] = logf(rs1[reg]) + logf(rs2[reg]);
  }
}

// ---------------- hd_k: start-head dot ----------------

__global__ __launch_bounds__(256) void hd_k(const float* __restrict__ sh,
                                            const float* __restrict__ wv,
                                            const float* __restrict__ bv,
                                            float* __restrict__ logits) {
  const int tid = threadIdx.x, lane = tid & 63, wid = tid >> 6;
  const int row = blockIdx.x * 4 + wid;
  float s = 0.f;
#pragma unroll
  for (int q = 0; q < 4; ++q)
    s += sh[(size_t)row * HD + q * 64 + lane] * wv[q * 64 + lane];
  for (int off = 32; off; off >>= 1) s += __shfl_xor(s, off, 64);
  if (lane == 0) logits[row] = s + bv[0];
}

// ---------------- leaf2_k: elementwise leaf build from T12 ----------------

__global__ __launch_bounds__(256) void leaf2_k(
    const float* __restrict__ T12, const float* __restrict__ rlse,
    const float* __restrict__ lall, const float* __restrict__ esum,
    const int* __restrict__ text, const int* __restrict__ w2c,
    u16* __restrict__ leafb, float* __restrict__ leafsc) {
  __shared__ float ftile[4096];
  __shared__ float wmax[4];
  __shared__ float ev_s[64];
  const int tid = threadIdx.x, lane = tid & 63, w = tid >> 6;
  const int bi = blockIdx.x;
  if (bi >= NB * (TT - 1)) {               // identity leaf (odd parity; I^T = I)
    const int n = bi - NB * (TT - 1);
    if (n < NB) {
      u16* node = leafb + ((size_t)n * 256 + 255) * 4096;
      for (int c = tid; c < 4096; c += 256) node[c] = ((c >> 6) == (c & 63)) ? (u16)0x3F80 : (u16)0;
      if (tid == 0) leafsc[n * 256 + 255] = 0.f;
    }
    return;
  }
  const int nn = bi / (TT - 1);
  const int ttv = bi % (TT - 1) + 1;
  const int wcur = text[nn * TT + ttv];
  const int cp = w2c[text[nn * TT + ttv - 1]];
  const int cc = w2c[wcur];
  const int rm = cp * 64;

  if (tid < 64)
    ev_s[tid] = lall[(size_t)wcur * 64 + tid] - logf(esum[cc * 64 + tid]);
  __syncthreads();

  const int r = tid >> 2, cb = (tid & 3) * 16;
  const int grow = rm + r;
  const float base = T12[(size_t)grow * 192 + cc] - rlse[grow];
  const float* t2row = T12 + (size_t)grow * 192 + 128 + cb;
  float L[16];
  float mx = -1e30f;
#pragma unroll
  for (int e = 0; e < 16; ++e) {
    L[e] = base + t2row[e] + ev_s[cb + e];
    mx = fmaxf(mx, L[e]);
  }
#pragma unroll
  for (int off = 1; off < 64; off <<= 1) mx = fmaxf(mx, __shfl_xor(mx, off, 64));
  if (lane == 0) wmax[w] = mx;
  __syncthreads();
  const float m = fmaxf(fmaxf(wmax[0], wmax[1]), fmaxf(wmax[2], wmax[3]));
#pragma unroll
  for (int e = 0; e < 16; ++e)
    ftile[r * 64 + cb + e] = exp2f((L[e] - m) * LOG2E);
  __syncthreads();

  const int leaf = ttv - 1;
  u16* node = leafb + ((size_t)nn * 256 + leaf) * 4096;
  u16x8 o0, o1;
  if ((leaf & 1) == 0) {
#pragma unroll
    for (int e = 0; e < 8; ++e) o0[e] = f2bf(ftile[r * 64 + cb + e]);
#pragma unroll
    for (int e = 0; e < 8; ++e) o1[e] = f2bf(ftile[r * 64 + cb + 8 + e]);
  } else {
#pragma unroll
    for (int e = 0; e < 8; ++e) o0[e] = f2bf(ftile[(cb + e) * 64 + r]);
#pragma unroll
    for (int e = 0; e < 8; ++e) o1[e] = f2bf(ftile[(cb + 8 + e) * 64 + r]);
  }
  *reinterpret_cast<u16x8*>(node + r * 64 + cb) = o0;
  *reinterpret_cast<u16x8*>(node + r * 64 + cb + 8) = o1;
  if (tid == 0) leafsc[nn * 256 + leaf] = m;
}

// ---------------- quad combine (stage + core) ----------------

__device__ __forceinline__ void comb4_stage(
    char* lds, const u16* s0, const u16* s1, const u16* s2, const u16* s3, int tid) {
  const u16* srcs[4] = {s0, s1, s2, s3};
  const int sr = tid >> 3, scb = (tid & 7) * 16;
#pragma unroll
  for (int nd = 0; nd < 4; ++nd)
#pragma unroll
    for (int rep = 0; rep < 2; ++rep) {
      const int r = rep * 32 + sr;
      const bh8 v = *reinterpret_cast<const bh8*>(srcs[nd] + r * 64 + (scb >> 1));
      *reinterpret_cast<bh8*>(&lds[nd * 8192 + r * 128 + (scb ^ ((r & 7) << 4))]) = v;
    }
  __syncthreads();
}

__device__ __forceinline__ void comb4_core(
    char* lds, float* wpm,
    float sc0, float sc1, float sc2, float sc3,
    u16* node, float* dsc, int parity, int tid) {
  const int lane = tid & 63, w = tid >> 6;
  const int p = w >> 1, h = w & 1;
  const int abase = p * 16384, bbase = abase + 8192;
  const int c0 = lane & 15, g = lane >> 4;
  f32x4 a2[2][4];
#pragma unroll
  for (int mi = 0; mi < 2; ++mi)
#pragma unroll
    for (int nj = 0; nj < 4; ++nj) a2[mi][nj] = (f32x4){0.f, 0.f, 0.f, 0.f};
#pragma unroll
  for (int kk = 0; kk < 64; kk += 32) {
    const int kb = (kk + g * 8) * 2;
    bh8 af[2], bf[4];
#pragma unroll
    for (int mi = 0; mi < 2; ++mi) {
      const int ar = h * 32 + mi * 16 + c0;
      af[mi] = *reinterpret_cast<const bh8*>(&lds[abase + ar * 128 + (kb ^ ((ar & 7) << 4))]);
    }
#pragma unroll
    for (int nj = 0; nj < 4; ++nj) {
      const int br = nj * 16 + c0;
      bf[nj] = *reinterpret_cast<const bh8*>(&lds[bbase + br * 128 + (kb ^ ((br & 7) << 4))]);
    }
#pragma unroll
    for (int mi = 0; mi < 2; ++mi)
#pragma unroll
      for (int nj = 0; nj < 4; ++nj)
        a2[mi][nj] = __builtin_amdgcn_mfma_f32_16x16x32_bf16(af[mi], bf[nj], a2[mi][nj], 0, 0, 0);
  }
  float mx = 0.f;
#pragma unroll
  for (int mi = 0; mi < 2; ++mi)
#pragma unroll
    for (int nj = 0; nj < 4; ++nj)
#pragma unroll
      for (int reg = 0; reg < 4; ++reg) mx = fmaxf(mx, a2[mi][nj][reg]);
#pragma unroll
  for (int off = 1; off < 64; off <<= 1) mx = fmaxf(mx, __shfl_xor(mx, off, 64));
  if (lane == 0) wpm[w] = mx;
  __syncthreads();
  const float mp = fmaxf(wpm[p * 2], wpm[p * 2 + 1]);
  const float invp = 1.0f / mp;
#pragma unroll
  for (int mi = 0; mi < 2; ++mi)
#pragma unroll
    for (int nj = 0; nj < 4; ++nj)
#pragma unroll
      for (int reg = 0; reg < 4; ++reg) {
        const int row = h * 32 + mi * 16 + g * 4 + reg;
        const int col = nj * 16 + c0;
        const u16 val = f2bf(a2[mi][nj][reg] * invp);
        if (p == 0)
          *reinterpret_cast<u16*>(&lds[32768 + row * 128 + ((col * 2) ^ ((row & 7) << 4))]) = val;
        else
          *reinterpret_cast<u16*>(&lds[40960 + col * 128 + ((row * 2) ^ ((col & 7) << 4))]) = val;
      }
  __syncthreads();

  f32x4 acc[4];
#pragma unroll
  for (int i = 0; i < 4; ++i) acc[i] = (f32x4){0.f, 0.f, 0.f, 0.f};
  const int ra = w * 16 + c0;
#pragma unroll
  for (int kk = 0; kk < 64; kk += 32) {
    const int kb = (kk + g * 8) * 2;
    const bh8 af = *reinterpret_cast<const bh8*>(&lds[32768 + ra * 128 + (kb ^ ((ra & 7) << 4))]);
#pragma unroll
    for (int nj = 0; nj < 4; ++nj) {
      const int rb = nj * 16 + c0;
      const bh8 bf = *reinterpret_cast<const bh8*>(&lds[40960 + rb * 128 + (kb ^ ((rb & 7) << 4))]);
      acc[nj] = __builtin_amdgcn_mfma_f32_16x16x32_bf16(af, bf, acc[nj], 0, 0, 0);
    }
  }
  float mx2 = 0.f;
#pragma unroll
  for (int nj = 0; nj < 4; ++nj)
#pragma unroll
    for (int reg = 0; reg < 4; ++reg) mx2 = fmaxf(mx2, acc[nj][reg]);
#pragma unroll
  for (int off = 1; off < 64; off <<= 1) mx2 = fmaxf(mx2, __shfl_xor(mx2, off, 64));
  if (lane == 0) wpm[4 + w] = mx2;
  __syncthreads();
  const float m = fmaxf(fmaxf(wpm[4], wpm[5]), fmaxf(wpm[6], wpm[7]));
  const float inv = 1.0f / m;
  float* ftile = reinterpret_cast<float*>(lds);
#pragma unroll
  for (int nj = 0; nj < 4; ++nj)
#pragma unroll
    for (int reg = 0; reg < 4; ++reg)
      ftile[(w * 16 + g * 4 + reg) * 64 + nj * 16 + c0] = acc[nj][reg] * inv;
  __syncthreads();
  const int rr = tid >> 2, cb = (tid & 3) * 16;
  u16x8 o0, o1;
  if (parity == 0) {
#pragma unroll
    for (int e = 0; e < 8; ++e) o0[e] = f2bf(ftile[rr * 64 + cb + e]);
#pragma unroll
    for (int e = 0; e < 8; ++e) o1[e] = f2bf(ftile[rr * 64 + cb + 8 + e]);
  } else {
#pragma unroll
    for (int e = 0; e < 8; ++e) o0[e] = f2bf(ftile[(cb + e) * 64 + rr]);
#pragma unroll
    for (int e = 0; e < 8; ++e) o1[e] = f2bf(ftile[(cb + 8 + e) * 64 + rr]);
  }
  *reinterpret_cast<u16x8*>(node + rr * 64 + cb) = o0;
  *reinterpret_cast<u16x8*>(node + rr * 64 + cb + 8) = o1;
  if (tid == 0)
    *dsc = sc0 + sc1 + sc2 + sc3
         + logf(fmaxf(wpm[0], wpm[1])) + logf(fmaxf(wpm[2], wpm[3])) + logf(m);
}

__global__ __launch_bounds__(256) void comb4_k(const u16* __restrict__ src,
                                               const float* __restrict__ scs,
                                               u16* __restrict__ dst,
                                               float* __restrict__ scd, int U) {
  const int n = blockIdx.x / U, u = blockIdx.x % U;
  __shared__ char lds[49152];
  __shared__ float wpm[8];
  const u16* base = src + ((size_t)(n * 4 * U + 4 * u)) * 4096;
  const float* sb = scs + n * 4 * U + 4 * u;
  comb4_stage(lds, base, base + 4096, base + 2 * 4096, base + 3 * 4096, threadIdx.x);
  comb4_core(lds, wpm, sb[0], sb[1], sb[2], sb[3],
             dst + ((size_t)(n * U + u)) * 4096, &scd[n * U + u], u & 1, threadIdx.x);
}

// ---------------- tail: 16 -> 4 -> 1 + hlse + final ----------------

__global__ __launch_bounds__(256) void tail_k(
    const u16* __restrict__ nodes, const float* __restrict__ nsc,
    u16* __restrict__ scratch, float* __restrict__ ssc,
    const float* __restrict__ hlog, const float* __restrict__ lall,
    const float* __restrict__ esum, const int* __restrict__ text,
    const int* __restrict__ w2c, float* __restrict__ out) {
  __shared__ char lds[49152];
  __shared__ float wpm[8];
  __shared__ float redm[4];
  __shared__ float hl_s;
  const int n = blockIdx.x, tid = threadIdx.x;
  const int lane = tid & 63, w = tid >> 6;

  float mm = -1e30f;
  for (int i = tid; i < CS; i += 256) mm = fmaxf(mm, hlog[i]);
  for (int off = 32; off; off >>= 1) mm = fmaxf(mm, __shfl_xor(mm, off, 64));
  if (lane == 0) redm[w] = mm;
  __syncthreads();
  const float M = fmaxf(fmaxf(redm[0], redm[1]), fmaxf(redm[2], redm[3]));
  float sx = 0.f;
  for (int i = tid; i < CS; i += 256) sx += expf(hlog[i] - M);
  for (int off = 32; off; off >>= 1) sx += __shfl_xor(sx, off, 64);
  __syncthreads();
  if (lane == 0) redm[w] = sx;
  __syncthreads();
  if (tid == 0) hl_s = M + logf(redm[0] + redm[1] + redm[2] + redm[3]);
  __syncthreads();
  const float hlse = hl_s;

  const u16* src = nodes + (size_t)n * 16 * 4096;
  const float* sc = nsc + n * 16;
  u16* scr = scratch + (size_t)n * 64 * 4096;
  float* scs = ssc + n * 64;
  for (int i = 0; i < 4; ++i) {
    comb4_stage(lds, src + (size_t)(4 * i) * 4096, src + (size_t)(4 * i + 1) * 4096,
                src + (size_t)(4 * i + 2) * 4096, src + (size_t)(4 * i + 3) * 4096, tid);
    comb4_core(lds, wpm, sc[4 * i], sc[4 * i + 1], sc[4 * i + 2], sc[4 * i + 3],
               scr + (size_t)i * 4096, &scs[i], i & 1, tid);
    __syncthreads();
  }
  comb4_stage(lds, scr, scr + 4096, scr + 2 * 4096, scr + 3 * 4096, tid);
  comb4_core(lds, wpm, scs[0], scs[1], scs[2], scs[3], scr + 4 * 4096, &scs[4], 0, tid);
  __syncthreads();

  if (tid < 64) {
    const int i = tid;
    const int w0 = text[n * TT];
    const int cc = w2c[w0];
    const float ev = lall[(size_t)w0 * 64 + i] - logf(esum[cc * 64 + i]);
    float a0 = hlog[cc * 64 + i] - hlse + ev;
    float m0 = a0;
    for (int off = 32; off; off >>= 1) m0 = fmaxf(m0, __shfl_xor(m0, off, 64));
    const float lin = expf(a0 - m0);
    const u16* row = scr + 4 * 4096 + i * 64;
    float rs = 0.f;
#pragma unroll
    for (int e8 = 0; e8 < 8; ++e8) {
      const u16x8 v = *reinterpret_cast<const u16x8*>(row + e8 * 8);
#pragma unroll
      for (int e = 0; e < 8; ++e) rs += bf2f(v[e]);
    }
    float v = lin * rs;
    for (int off = 32; off; off >>= 1) v += __shfl_xor(v, off, 64);
    if (i == 0) out[n] = m0 + scs[4] + logf(v);
  }
}

// ---------------- emission GEMM ----------------

__global__ __launch_bounds__(256) void emis_k(
    const u16* __restrict__ Wpb, const u16* __restrict__ PHb,
    const float* __restrict__ bp,
    const int* __restrict__ offs, const int* __restrict__ wlist,
    const int* __restrict__ map,
    float* __restrict__ esum, float* __restrict__ logits_all) {
  const int ent = map[blockIdx.x];
  if (ent < 0) return;
  const int c = ent >> 8, blk = ent & 255;
  __shared__ char lds[16384];
  __shared__ int wid_s[64];
  const int tid = threadIdx.x, lane = tid & 63, wid = tid >> 6;
  const int st = offs[c], cnt = offs[c + 1] - st;
  if (tid < 64) {
    const int idx = blk * 64 + tid;
    wid_s[tid] = (idx < cnt) ? wlist[st + idx] : -1;
  }
  __syncthreads();

  f32x4 acc[4];
#pragma unroll
  for (int i = 0; i < 4; ++i) acc[i] = (f32x4){0.f, 0.f, 0.f, 0.f};

  const int ra = wid * 16 + (lane & 15);
  const int rb0 = lane & 15;
  const int ko = (lane >> 4) * 8;
  const u16* Bg = PHb + (size_t)(c * 64) * HD;

  for (int kc = 0; kc < HD; kc += 64) {
    if (kc) __syncthreads();
#pragma unroll
    for (int i = 0; i < 2; ++i) {
      const int cc = i * 256 + tid;
      const int r = cc >> 3, cb = cc & 7;
      const int gq = cb ^ (r & 7);
      const int wv = max(wid_s[r], 0);
      gl2lds16(Wpb + (size_t)wv * HD + kc + gq * 8, (u16*)&lds[cc * 16]);
      gl2lds16(Bg + (size_t)r * HD + kc + gq * 8, (u16*)&lds[8192 + cc * 16]);
    }
    __syncthreads();
#pragma unroll
    for (int kk = 0; kk < 64; kk += 32) {
      const int kb = (kk + ko) * 2;
      const bh8 af = *reinterpret_cast<const bh8*>(&lds[ra * 128 + (kb ^ ((ra & 7) << 4))]);
#pragma unroll
      for (int nj = 0; nj < 4; ++nj) {
        const int rb = nj * 16 + rb0;
        const bh8 bf = *reinterpret_cast<const bh8*>(&lds[8192 + rb * 128 + (kb ^ ((rb & 7) << 4))]);
        acc[nj] = __builtin_amdgcn_mfma_f32_16x16x32_bf16(af, bf, acc[nj], 0, 0, 0);
      }
    }
  }

  const int g = lane >> 4, c0 = lane & 15;
#pragma unroll
  for (int nj = 0; nj < 4; ++nj) {
    float se = 0.f;
#pragma unroll
    for (int reg = 0; reg < 4; ++reg) {
      const int row = wid * 16 + g * 4 + reg;
      const int w = wid_s[row];
      if (w >= 0) {
        const float lg = acc[nj][reg] + bp[w];
        logits_all[(size_t)w * 64 + nj * 16 + c0] = lg;
        se += expf(lg);
      }
    }
    se += __shfl_xor(se, 16, 64);
    se += __shfl_xor(se, 32, 64);
    if (g == 0) atomicAdd(&esum[c * 64 + nj * 16 + c0], se);
  }
}

// ---------------- host orchestration ----------------

extern "C" void kernel_launch(void* const* d_in, const int* in_sizes, int n_in,
                              void* d_out, int out_size, void* d_ws, size_t ws_size,
                              hipStream_t stream) {
  (void)in_sizes; (void)n_in; (void)out_size; (void)ws_size;
  const int* text = (const int*)d_in[0];
  const int* w2c  = (const int*)d_in[1];
  const float* sec = (const float*)d_in[2];
  const float* ses = (const float*)d_in[3];
  const float* stc = (const float*)d_in[4];
  const float* sts = (const float*)d_in[5];
  const float* nec = (const float*)d_in[6];
  const float* nes = (const float*)d_in[7];
  const float* pec = (const float*)d_in[8];
  const float* pes = (const float*)d_in[9];
  const float* srw1 = (const float*)d_in[10];
  const float* srb1 = (const float*)d_in[11];
  const float* srw2 = (const float*)d_in[12];
  const float* srb2 = (const float*)d_in[13];
  const float* trw1 = (const float*)d_in[14];
  const float* trb1 = (const float*)d_in[15];
  const float* trw2 = (const float*)d_in[16];
  const float* trb2 = (const float*)d_in[17];
  const float* tew1 = (const float*)d_in[18];
  const float* teb1 = (const float*)d_in[19];
  const float* tew2 = (const float*)d_in[20];
  const float* teb2 = (const float*)d_in[21];
  const float* sow = (const float*)d_in[22];
  const float* sob = (const float*)d_in[23];
  const float* tpw = (const float*)d_in[24];
  const float* tpb = (const float*)d_in[25];
  float* out = (float*)d_out;

  char* p = (char*)d_ws;
  auto carve = [&](size_t bytes) -> char* {
    char* r = p; p += (bytes + 255) & ~(size_t)255; return r;
  };
  u16* Wall = (u16*)carve((size_t)WT2 * 2);
  u16* Wpb  = Wall + WTOT;
  u16* Hb0  = (u16*)carve((size_t)CS * HD * 2);
  u16* Hb1  = (u16*)carve((size_t)CS * HD * 2);
  u16* Hb2  = (u16*)carve((size_t)CS * HD * 2);
  float* SHf = (float*)carve((size_t)CS * HD * 4);
  u16* Xbf  = (u16*)carve((size_t)CS * HD * 2);
  u16* PHb  = (u16*)carve((size_t)CS * HD * 2);
  float* T12  = (float*)carve((size_t)CS * 192 * 4);
  float* hlog  = (float*)carve(CS * 4);
  float* rlse  = (float*)carve(CS * 4);
  int* offs    = (int*)carve((KCL + 1) * 4);
  int* wlist   = (int*)carve(VV * 4);
  int* bmap    = (int*)carve(MAXB * 4);
  float* esum  = (float*)carve(CS * 4);
  float* lall  = (float*)carve((size_t)VV * 64 * 4);
  u16*   bufA  = (u16*)carve((size_t)NB * 256 * 4096 * 2);
  u16*   bufB  = (u16*)carve((size_t)NB * 64 * 4096 * 2);
  float* scA   = (float*)carve((size_t)NB * 256 * 4);
  float* scB   = (float*)carve((size_t)NB * 256 * 4);

  csr_k<<<1, 256, 0, stream>>>(w2c, offs, wlist, bmap, esum);

  prep_stream<<<PREPB, 256, 0, stream>>>(
      srw1, srw2, trw1, trw2, tew1, tew2, tpw, Wall);

  mlp_k<1><<<dim3(4, 128, 3), 256, 0, stream>>>(
      sec, ses, stc, sts, pec, pes, Hb0, Hb1, Hb2, Wall,
      srb1, trb1, teb1, nullptr, nullptr, nullptr);
  mlp_k<2><<<dim3(4, 128, 3), 256, 0, stream>>>(
      sec, ses, stc, sts, pec, pes, Hb0, Hb1, Hb2, Wall,
      srb2, trb2, teb2, SHf, Xbf, PHb);

  // T1|T2 + rlse (replaces the 8192x8192 transition GEMM entirely)
  t12_k<<<CS / 64, 256, 0, stream>>>(Xbf, nec, nes, T12, rlse);

  hd_k<<<CS / 4, 256, 0, stream>>>(SHf, sow, sob, hlog);

  emis_k<<<MAXB, 256, 0, stream>>>(Wpb, PHb, tpb, offs, wlist, bmap, esum, lall);

  // elementwise leaves from T12 (identity leaves in same grid)
  leaf2_k<<<dim3(NB * (TT - 1) + NB), 256, 0, stream>>>(
      T12, rlse, lall, esum, text, w2c, bufA, scA);

  comb4_k<<<NB * 64, 256, 0, stream>>>(bufA, scA, bufB, scB, 64);
  comb4_k<<<NB * 16, 256, 0, stream>>>(bufB, scB, bufA, scA, 16);
  tail_k<<<NB, 256, 0, stream>>>(bufA, scA, bufB, scB, hlog, lall, esum, text, w2c, out);
}

// Round 19
// 135.833 us; speedup vs baseline: 1.6406x; 1.1048x over previous
//
#include <hip/hip_runtime.h>
#include <hip/hip_bf16.h>

// FactoredHmmLm forward on MI355X.
// ALGEBRA: nse[k*64+s]=nec[k]+nes[s] => tr[i,k*64+s]=T1[i,k]+T2[i,s]
//   => rlse = lse(T1)+lse(T2); leaf tiles are elementwise from T12.
//  1. prep_all: weights->bf16 (grid-stride) + CSR/esum (last block)
//  2. mlp_k<1>/<2>: batched residual MLPs (emb in-register)
//  3. t12_k: T12 = X @ [nec;nes]^T (8192x192) + rlse
//  4. hd_k: start-head dot
//  5. emis_k: MFMA 64-word blocks + atomic exp-sum
//  6. leafc2_k: build 4 elementwise leaves in swizzled LDS + combine -> 64 nodes/seq
//  7. comb4_k x2 (64->16->4) + tail2_k (4->1 + hlse + final)

using u16 = unsigned short;
typedef __attribute__((ext_vector_type(8))) short bh8;     // 8 bf16 (4 VGPRs)
typedef __attribute__((ext_vector_type(4))) float f32x4;
typedef __attribute__((ext_vector_type(8))) unsigned short u16x8;

#define HD 256
#define TT 256
#define NB 16
#define KCL 128
#define CS 8192
#define VV 10000
#define MAXB 320
#define LOG2E 1.44269504f
#define WTOT (6 * 65536)
#define WT2  (WTOT + VV * HD)
#define NELEM8 (WT2 / 8)                     // weights only
#define PREPB 1024

__device__ __forceinline__ u16 f2bf(float v) {
  union { float f; unsigned int i; } u; u.f = v;
  unsigned int r = u.i + 0x7fffu + ((u.i >> 16) & 1u);   // RNE
  return (u16)(r >> 16);
}
__device__ __forceinline__ float bf2f(u16 u) {
  union { unsigned int i; float f; } x; x.i = ((unsigned int)u) << 16; return x.f;
}
__device__ __forceinline__ void gl2lds16(const u16* g, u16* l) {
  __builtin_amdgcn_global_load_lds(
      (const __attribute__((address_space(1))) unsigned int*)g,
      (__attribute__((address_space(3))) unsigned int*)l, 16, 0, 0);
}
__device__ __forceinline__ u16x8 cvt8(const float* __restrict__ s) {
  const float4 a = *reinterpret_cast<const float4*>(s);
  const float4 b = *reinterpret_cast<const float4*>(s + 4);
  u16x8 o;
  o[0] = f2bf(a.x); o[1] = f2bf(a.y); o[2] = f2bf(a.z); o[3] = f2bf(a.w);
  o[4] = f2bf(b.x); o[5] = f2bf(b.y); o[6] = f2bf(b.z); o[7] = f2bf(b.w);
  return o;
}
__device__ __forceinline__ u16x8 add_cvt8(const float* __restrict__ s0,
                                          const float* __restrict__ s1) {
  const float4 a0 = *reinterpret_cast<const float4*>(s0);
  const float4 b0 = *reinterpret_cast<const float4*>(s0 + 4);
  const float4 a1 = *reinterpret_cast<const float4*>(s1);
  const float4 b1 = *reinterpret_cast<const float4*>(s1 + 4);
  u16x8 o;
  o[0] = f2bf(a0.x + a1.x); o[1] = f2bf(a0.y + a1.y);
  o[2] = f2bf(a0.z + a1.z); o[3] = f2bf(a0.w + a1.w);
  o[4] = f2bf(b0.x + b1.x); o[5] = f2bf(b0.y + b1.y);
  o[6] = f2bf(b0.z + b1.z); o[7] = f2bf(b0.w + b1.w);
  return o;
}

// ---------------- prep_all: weights -> bf16 + CSR/esum (last block) ----------------

__global__ __launch_bounds__(256) void prep_all(
    const float* __restrict__ w0, const float* __restrict__ w1,
    const float* __restrict__ w2, const float* __restrict__ w3,
    const float* __restrict__ w4, const float* __restrict__ w5,
    const float* __restrict__ tpw, u16* __restrict__ dstW,
    const int* __restrict__ w2c, int* __restrict__ offs,
    int* __restrict__ wlist, int* __restrict__ bmap, float* __restrict__ esum) {
  const int b = blockIdx.x, tid = threadIdx.x;
  if (b < PREPB) {
    for (int i = b * 256 + tid; i < NELEM8; i += PREPB * 256) {
      const int idx = i * 8;
      if (idx < WTOT) {
        const int wi = idx >> 16;
        const float* s = wi == 0 ? w0 : wi == 1 ? w1 : wi == 2 ? w2
                       : wi == 3 ? w3 : wi == 4 ? w4 : w5;
        *reinterpret_cast<u16x8*>(dstW + idx) = cvt8(s + (idx & 65535));
      } else {
        *reinterpret_cast<u16x8*>(dstW + idx) = cvt8(tpw + (idx - WTOT));
      }
    }
    return;
  }
  // CSR build (fully parallel) + esum zero
  __shared__ int cnt[KCL], cur[KCL];
  __shared__ int wsA[2], wsB[2];
  __shared__ int totb_s;
  const int lane = tid & 63, w = tid >> 6;
  if (tid < KCL) cnt[tid] = 0;
  __syncthreads();
  for (int v = tid; v < VV; v += 256) atomicAdd(&cnt[w2c[v]], 1);
  __syncthreads();
  int c = 0, x = 0;
  if (tid < KCL) {
    c = cnt[tid];
    x = c;
#pragma unroll
    for (int off = 1; off < 64; off <<= 1) {
      const int y = __shfl_up(x, off, 64);
      if (lane >= off) x += y;
    }
    if (lane == 63) wsA[w] = x;
  }
  __syncthreads();
  int nb = 0, xs = 0;
  if (tid < KCL) {
    const int base = (w == 1) ? wsA[0] : 0;
    const int excl = base + x - c;
    offs[tid] = excl;
    cur[tid] = excl;
    if (tid == KCL - 1) offs[KCL] = base + x;
    nb = (c + 63) >> 6;
    xs = nb;
#pragma unroll
    for (int off = 1; off < 64; off <<= 1) {
      const int y = __shfl_up(xs, off, 64);
      if (lane >= off) xs += y;
    }
    if (lane == 63) wsB[w] = xs;
  }
  __syncthreads();
  if (tid < KCL) {
    const int base = (w == 1) ? wsB[0] : 0;
    const int b0 = base + xs - nb;
    for (int bb = 0; bb < nb; ++bb) bmap[b0 + bb] = (tid << 8) | bb;
    if (tid == KCL - 1) totb_s = base + xs;
  }
  __syncthreads();
  const int totb = totb_s;
  for (int i = totb + tid; i < MAXB; i += 256) bmap[i] = -1;
  for (int v = tid; v < VV; v += 256) {
    const int pos = atomicAdd(&cur[w2c[v]], 1);
    wlist[pos] = v;
  }
  for (int i = tid; i < CS; i += 256) esum[i] = 0.f;
}

// ---------------- batched residual-MLP GEMMs (LAYER1: emb in-register) --------

template<int LAYER>
__global__ __launch_bounds__(256) void mlp_k(
    const float* __restrict__ ec0, const float* __restrict__ es0,
    const float* __restrict__ ec1, const float* __restrict__ es1,
    const float* __restrict__ ec2, const float* __restrict__ es2,
    u16* __restrict__ H0, u16* __restrict__ H1, u16* __restrict__ H2,
    const u16* __restrict__ Wall,
    const float* __restrict__ bb0, const float* __restrict__ bb1, const float* __restrict__ bb2,
    float* __restrict__ SHf, u16* __restrict__ Xbf, u16* __restrict__ PHb) {
  __shared__ char lds[16384];
  const int tid = threadIdx.x, lane = tid & 63, wid = tid >> 6;
  const int z = blockIdx.z;
  const float* ec = z == 0 ? ec0 : z == 1 ? ec1 : ec2;
  const float* es = z == 0 ? es0 : z == 1 ? es1 : es2;
  u16* Hb = z == 0 ? H0 : z == 1 ? H1 : H2;
  const u16* B = Wall + (size_t)(2 * z + (LAYER - 1)) * 65536;
  const float* bias = z == 0 ? bb0 : z == 1 ? bb1 : bb2;

  const int rm = blockIdx.y * 64, cn = blockIdx.x * 64;
  const u16* Bg = B + (size_t)cn * HD;

  f32x4 acc[4];
#pragma unroll
  for (int i = 0; i < 4; ++i) acc[i] = (f32x4){0.f, 0.f, 0.f, 0.f};
  const int ra = wid * 16 + (lane & 15);
  const int rb0 = lane & 15;
  const int ko = (lane >> 4) * 8;

  for (int kc = 0; kc < HD; kc += 64) {
    if (kc) __syncthreads();
#pragma unroll
    for (int i = 0; i < 2; ++i) {
      const int c = i * 256 + tid;
      const int r = c >> 3, cb = c & 7;
      const int gq = cb ^ (r & 7);
      if (LAYER == 1) {
        const int grow = rm + r;
        const int krow = grow >> 6, srow = grow & 63;
        const int h0 = kc + cb * 8;
        const u16x8 v = add_cvt8(ec + krow * HD + h0, es + srow * HD + h0);
        *reinterpret_cast<u16x8*>(&lds[r * 128 + ((cb * 16) ^ ((r & 7) << 4))]) = v;
      } else {
        gl2lds16(Hb + (size_t)(rm + r) * HD + kc + gq * 8, (u16*)&lds[c * 16]);
      }
      gl2lds16(Bg + (size_t)r * HD + kc + gq * 8, (u16*)&lds[8192 + c * 16]);
    }
    __syncthreads();
#pragma unroll
    for (int kk = 0; kk < 64; kk += 32) {
      const int kb = (kk + ko) * 2;
      const bh8 af = *reinterpret_cast<const bh8*>(&lds[ra * 128 + (kb ^ ((ra & 7) << 4))]);
#pragma unroll
      for (int nj = 0; nj < 4; ++nj) {
        const int rb = nj * 16 + rb0;
        const bh8 bf = *reinterpret_cast<const bh8*>(&lds[8192 + rb * 128 + (kb ^ ((rb & 7) << 4))]);
        acc[nj] = __builtin_amdgcn_mfma_f32_16x16x32_bf16(af, bf, acc[nj], 0, 0, 0);
      }
    }
  }

  const int g = lane >> 4, c0 = lane & 15;
#pragma unroll
  for (int nj = 0; nj < 4; ++nj) {
    const int nidx = cn + nj * 16 + c0;
    const float bv = bias[nidx];
#pragma unroll
    for (int reg = 0; reg < 4; ++reg) {
      const int midx = rm + wid * 16 + g * 4 + reg;
      float v = acc[nj][reg] + bv;
      if (LAYER == 2)
        v += ec[(midx >> 6) * HD + nidx] + es[(midx & 63) * HD + nidx];
      v = fmaxf(v, 0.f);
      if (LAYER == 1) {
        Hb[(size_t)midx * 256 + nidx] = f2bf(v);
      } else {
        if (z == 0) SHf[(size_t)midx * 256 + nidx] = v;
        else if (z == 1) Xbf[(size_t)midx * 256 + nidx] = f2bf(v);
        else PHb[(size_t)midx * 256 + nidx] = f2bf(v);
      }
    }
  }
}

// ---------------- t12_k: T12 = X @ [nec;nes]^T (8192x192) + rlse ----------------

__global__ __launch_bounds__(256) void t12_k(
    const u16* __restrict__ Xbf, const float* __restrict__ nec,
    const float* __restrict__ nes,
    float* __restrict__ T12, float* __restrict__ rlse) {
  __shared__ char lds[32768];   // A 8KB @0 | B 24KB @8192 (192 rows x 128B)
  const int tid = threadIdx.x, lane = tid & 63, wid = tid >> 6;
  const int rm = blockIdx.x * 64;
  const int ra = wid * 16 + (lane & 15);
  const int rb0 = lane & 15;
  const int ko = (lane >> 4) * 8;

  f32x4 acc[12];
#pragma unroll
  for (int i = 0; i < 12; ++i) acc[i] = (f32x4){0.f, 0.f, 0.f, 0.f};

  for (int kc = 0; kc < HD; kc += 64) {
    if (kc) __syncthreads();
#pragma unroll
    for (int i = 0; i < 2; ++i) {
      const int c = i * 256 + tid;
      const int r = c >> 3, cb = c & 7;
      const int gq = cb ^ (r & 7);
      gl2lds16(Xbf + (size_t)(rm + r) * HD + kc + gq * 8, (u16*)&lds[c * 16]);
    }
#pragma unroll
    for (int i = 0; i < 6; ++i) {
      const int c = i * 256 + tid;          // 0..1535 -> 192 rows x 8 chunks
      const int r = c >> 3, cb = c & 7;
      const float* src = (r < KCL) ? (nec + r * HD + kc + cb * 8)
                                   : (nes + (r - KCL) * HD + kc + cb * 8);
      const u16x8 v = cvt8(src);
      *reinterpret_cast<u16x8*>(&lds[8192 + r * 128 + ((cb * 16) ^ ((r & 7) << 4))]) = v;
    }
    __syncthreads();
#pragma unroll
    for (int kk = 0; kk < 64; kk += 32) {
      const int kb = (kk + ko) * 2;
      const bh8 af = *reinterpret_cast<const bh8*>(&lds[ra * 128 + (kb ^ ((ra & 7) << 4))]);
#pragma unroll
      for (int nj = 0; nj < 12; ++nj) {
        const int rb = nj * 16 + rb0;
        const bh8 bf = *reinterpret_cast<const bh8*>(&lds[8192 + rb * 128 + (kb ^ ((rb & 7) << 4))]);
        acc[nj] = __builtin_amdgcn_mfma_f32_16x16x32_bf16(af, bf, acc[nj], 0, 0, 0);
      }
    }
  }

  const int g = lane >> 4, c0 = lane & 15;
  float rs1[4] = {0.f, 0.f, 0.f, 0.f};
  float rs2[4] = {0.f, 0.f, 0.f, 0.f};
#pragma unroll
  for (int nj = 0; nj < 12; ++nj) {
    const int col = nj * 16 + c0;
#pragma unroll
    for (int reg = 0; reg < 4; ++reg) {
      const int row = rm + wid * 16 + g * 4 + reg;
      const float v = acc[nj][reg];
      T12[(size_t)row * 192 + col] = v;
      const float e = exp2f(v * LOG2E);
      if (nj < 8) rs1[reg] += e; else rs2[reg] += e;
    }
  }
#pragma unroll
  for (int off = 1; off < 16; off <<= 1)
#pragma unroll
    for (int reg = 0; reg < 4; ++reg) {
      rs1[reg] += __shfl_xor(rs1[reg], off, 64);
      rs2[reg] += __shfl_xor(rs2[reg], off, 64);
    }
  if (c0 == 0) {
#pragma unroll
    for (int reg = 0; reg < 4; ++reg)
      rlse[rm + wid * 16 + g * 4 + reg] = logf(rs1[reg]) + logf(rs2[reg]);
  }
}

// ---------------- hd_k: start-head dot ----------------

__global__ __launch_bounds__(256) void hd_k(const float* __restrict__ sh,
                                            const float* __restrict__ wv,
                                            const float* __restrict__ bv,
                                            float* __restrict__ logits) {
  const int tid = threadIdx.x, lane = tid & 63, wid = tid >> 6;
  const int row = blockIdx.x * 4 + wid;
  float s = 0.f;
#pragma unroll
  for (int q = 0; q < 4; ++q)
    s += sh[(size_t)row * HD + q * 64 + lane] * wv[q * 64 + lane];
  for (int off = 32; off; off >>= 1) s += __shfl_xor(s, off, 64);
  if (lane == 0) logits[row] = s + bv[0];
}

// ---------------- emission GEMM ----------------

__global__ __launch_bounds__(256) void emis_k(
    const u16* __restrict__ Wpb, const u16* __restrict__ PHb,
    const float* __restrict__ bp,
    const int* __restrict__ offs, const int* __restrict__ wlist,
    const int* __restrict__ map,
    float* __restrict__ esum, float* __restrict__ logits_all) {
  const int ent = map[blockIdx.x];
  if (ent < 0) return;
  const int c = ent >> 8, blk = ent & 255;
  __shared__ char lds[16384];
  __shared__ int wid_s[64];
  const int tid = threadIdx.x, lane = tid & 63, wid = tid >> 6;
  const int st = offs[c], cnt = offs[c + 1] - st;
  if (tid < 64) {
    const int idx = blk * 64 + tid;
    wid_s[tid] = (idx < cnt) ? wlist[st + idx] : -1;
  }
  __syncthreads();

  f32x4 acc[4];
#pragma unroll
  for (int i = 0; i < 4; ++i) acc[i] = (f32x4){0.f, 0.f, 0.f, 0.f};

  const int ra = wid * 16 + (lane & 15);
  const int rb0 = lane & 15;
  const int ko = (lane >> 4) * 8;
  const u16* Bg = PHb + (size_t)(c * 64) * HD;

  for (int kc = 0; kc < HD; kc += 64) {
    if (kc) __syncthreads();
#pragma unroll
    for (int i = 0; i < 2; ++i) {
      const int cc = i * 256 + tid;
      const int r = cc >> 3, cb = cc & 7;
      const int gq = cb ^ (r & 7);
      const int wv = max(wid_s[r], 0);
      gl2lds16(Wpb + (size_t)wv * HD + kc + gq * 8, (u16*)&lds[cc * 16]);
      gl2lds16(Bg + (size_t)r * HD + kc + gq * 8, (u16*)&lds[8192 + cc * 16]);
    }
    __syncthreads();
#pragma unroll
    for (int kk = 0; kk < 64; kk += 32) {
      const int kb = (kk + ko) * 2;
      const bh8 af = *reinterpret_cast<const bh8*>(&lds[ra * 128 + (kb ^ ((ra & 7) << 4))]);
#pragma unroll
      for (int nj = 0; nj < 4; ++nj) {
        const int rb = nj * 16 + rb0;
        const bh8 bf = *reinterpret_cast<const bh8*>(&lds[8192 + rb * 128 + (kb ^ ((rb & 7) << 4))]);
        acc[nj] = __builtin_amdgcn_mfma_f32_16x16x32_bf16(af, bf, acc[nj], 0, 0, 0);
      }
    }
  }

  const int g = lane >> 4, c0 = lane & 15;
#pragma unroll
  for (int nj = 0; nj < 4; ++nj) {
    float se = 0.f;
#pragma unroll
    for (int reg = 0; reg < 4; ++reg) {
      const int row = wid * 16 + g * 4 + reg;
      const int w = wid_s[row];
      if (w >= 0) {
        const float lg = acc[nj][reg] + bp[w];
        logits_all[(size_t)w * 64 + nj * 16 + c0] = lg;
        se += expf(lg);
      }
    }
    se += __shfl_xor(se, 16, 64);
    se += __shfl_xor(se, 32, 64);
    if (g == 0) atomicAdd(&esum[c * 64 + nj * 16 + c0], se);
  }
}

// ---------------- quad combine core (tiles in swizzled LDS slots) ----------------
// slots at lds[0],[8192],[16384],[24576]; P1@32768 P2@40960; ftile reuses lds[0..16K].
// LDS element (row r, col c) of slot nd: lds[nd*8192 + r*128 + ((2c) ^ ((r&7)<<4))]
// (odd-parity nodes are transposed in this coordinate system).

__device__ __forceinline__ void comb4_core(
    char* lds, float* wpm,
    float sc0, float sc1, float sc2, float sc3,
    u16* node, float* dsc, int parity, int tid) {
  const int lane = tid & 63, w = tid >> 6;
  const int p = w >> 1, h = w & 1;
  const int abase = p * 16384, bbase = abase + 8192;
  const int c0 = lane & 15, g = lane >> 4;
  f32x4 a2[2][4];
#pragma unroll
  for (int mi = 0; mi < 2; ++mi)
#pragma unroll
    for (int nj = 0; nj < 4; ++nj) a2[mi][nj] = (f32x4){0.f, 0.f, 0.f, 0.f};
#pragma unroll
  for (int kk = 0; kk < 64; kk += 32) {
    const int kb = (kk + g * 8) * 2;
    bh8 af[2], bf[4];
#pragma unroll
    for (int mi = 0; mi < 2; ++mi) {
      const int ar = h * 32 + mi * 16 + c0;
      af[mi] = *reinterpret_cast<const bh8*>(&lds[abase + ar * 128 + (kb ^ ((ar & 7) << 4))]);
    }
#pragma unroll
    for (int nj = 0; nj < 4; ++nj) {
      const int br = nj * 16 + c0;
      bf[nj] = *reinterpret_cast<const bh8*>(&lds[bbase + br * 128 + (kb ^ ((br & 7) << 4))]);
    }
#pragma unroll
    for (int mi = 0; mi < 2; ++mi)
#pragma unroll
      for (int nj = 0; nj < 4; ++nj)
        a2[mi][nj] = __builtin_amdgcn_mfma_f32_16x16x32_bf16(af[mi], bf[nj], a2[mi][nj], 0, 0, 0);
  }
  float mx = 0.f;
#pragma unroll
  for (int mi = 0; mi < 2; ++mi)
#pragma unroll
    for (int nj = 0; nj < 4; ++nj)
#pragma unroll
      for (int reg = 0; reg < 4; ++reg) mx = fmaxf(mx, a2[mi][nj][reg]);
#pragma unroll
  for (int off = 1; off < 64; off <<= 1) mx = fmaxf(mx, __shfl_xor(mx, off, 64));
  if (lane == 0) wpm[w] = mx;
  __syncthreads();
  const float mp = fmaxf(wpm[p * 2], wpm[p * 2 + 1]);
  const float invp = 1.0f / mp;
#pragma unroll
  for (int mi = 0; mi < 2; ++mi)
#pragma unroll
    for (int nj = 0; nj < 4; ++nj)
#pragma unroll
      for (int reg = 0; reg < 4; ++reg) {
        const int row = h * 32 + mi * 16 + g * 4 + reg;
        const int col = nj * 16 + c0;
        const u16 val = f2bf(a2[mi][nj][reg] * invp);
        if (p == 0)
          *reinterpret_cast<u16*>(&lds[32768 + row * 128 + ((col * 2) ^ ((row & 7) << 4))]) = val;
        else
          *reinterpret_cast<u16*>(&lds[40960 + col * 128 + ((row * 2) ^ ((col & 7) << 4))]) = val;
      }
  __syncthreads();

  f32x4 acc[4];
#pragma unroll
  for (int i = 0; i < 4; ++i) acc[i] = (f32x4){0.f, 0.f, 0.f, 0.f};
  const int ra = w * 16 + c0;
#pragma unroll
  for (int kk = 0; kk < 64; kk += 32) {
    const int kb = (kk + g * 8) * 2;
    const bh8 af = *reinterpret_cast<const bh8*>(&lds[32768 + ra * 128 + (kb ^ ((ra & 7) << 4))]);
#pragma unroll
    for (int nj = 0; nj < 4; ++nj) {
      const int rb = nj * 16 + c0;
      const bh8 bf = *reinterpret_cast<const bh8*>(&lds[40960 + rb * 128 + (kb ^ ((rb & 7) << 4))]);
      acc[nj] = __builtin_amdgcn_mfma_f32_16x16x32_bf16(af, bf, acc[nj], 0, 0, 0);
    }
  }
  float mx2 = 0.f;
#pragma unroll
  for (int nj = 0; nj < 4; ++nj)
#pragma unroll
    for (int reg = 0; reg < 4; ++reg) mx2 = fmaxf(mx2, acc[nj][reg]);
#pragma unroll
  for (int off = 1; off < 64; off <<= 1) mx2 = fmaxf(mx2, __shfl_xor(mx2, off, 64));
  if (lane == 0) wpm[4 + w] = mx2;
  __syncthreads();
  const float m = fmaxf(fmaxf(wpm[4], wpm[5]), fmaxf(wpm[6], wpm[7]));
  const float inv = 1.0f / m;
  float* ftile = reinterpret_cast<float*>(lds);
#pragma unroll
  for (int nj = 0; nj < 4; ++nj)
#pragma unroll
    for (int reg = 0; reg < 4; ++reg)
      ftile[(w * 16 + g * 4 + reg) * 64 + nj * 16 + c0] = acc[nj][reg] * inv;
  __syncthreads();
  const int rr = tid >> 2, cb = (tid & 3) * 16;
  u16x8 o0, o1;
  if (parity == 0) {
#pragma unroll
    for (int e = 0; e < 8; ++e) o0[e] = f2bf(ftile[rr * 64 + cb + e]);
#pragma unroll
    for (int e = 0; e < 8; ++e) o1[e] = f2bf(ftile[rr * 64 + cb + 8 + e]);
  } else {
#pragma unroll
    for (int e = 0; e < 8; ++e) o0[e] = f2bf(ftile[(cb + e) * 64 + rr]);
#pragma unroll
    for (int e = 0; e < 8; ++e) o1[e] = f2bf(ftile[(cb + 8 + e) * 64 + rr]);
  }
  *reinterpret_cast<u16x8*>(node + rr * 64 + cb) = o0;
  *reinterpret_cast<u16x8*>(node + rr * 64 + cb + 8) = o1;
  if (tid == 0)
    *dsc = sc0 + sc1 + sc2 + sc3
         + logf(fmaxf(wpm[0], wpm[1])) + logf(fmaxf(wpm[2], wpm[3])) + logf(m);
}

__device__ __forceinline__ void comb4_stage(
    char* lds, const u16* s0, const u16* s1, const u16* s2, const u16* s3, int tid) {
  const u16* srcs[4] = {s0, s1, s2, s3};
  const int sr = tid >> 3, scb = (tid & 7) * 16;
#pragma unroll
  for (int nd = 0; nd < 4; ++nd)
#pragma unroll
    for (int rep = 0; rep < 2; ++rep) {
      const int r = rep * 32 + sr;
      const bh8 v = *reinterpret_cast<const bh8*>(srcs[nd] + r * 64 + (scb >> 1));
      *reinterpret_cast<bh8*>(&lds[nd * 8192 + r * 128 + (scb ^ ((r & 7) << 4))]) = v;
    }
  __syncthreads();
}

// ---------------- leafc2_k: 4 elementwise leaves in LDS + combine ----------------

__global__ __launch_bounds__(256) void leafc2_k(
    const float* __restrict__ T12, const float* __restrict__ rlse,
    const float* __restrict__ lall, const float* __restrict__ esum,
    const int* __restrict__ text, const int* __restrict__ w2c,
    u16* __restrict__ dst, float* __restrict__ scd) {
  __shared__ char lds[49152];
  __shared__ float wpm[8];
  __shared__ float scl[4];
  __shared__ float ev_s[64];
  const int tid = threadIdx.x, lane = tid & 63, w = tid >> 6;
  const int n = blockIdx.x >> 6, u = blockIdx.x & 63;
  const int r = tid >> 2, cb = (tid & 3) * 16;

  for (int j = 0; j < 4; ++j) {
    const int l = 4 * u + j;
    char* slot = &lds[j * 8192];
    __syncthreads();                          // ev_s / wpm reuse guard
    if (l == 255) {                           // identity (odd parity, I^T = I)
      for (int idx = tid; idx < 4096; idx += 256) {
        const int rr = idx >> 6, cc = idx & 63;
        const u16 val = (rr == cc) ? (u16)0x3F80 : (u16)0;
        *reinterpret_cast<u16*>(&slot[cc * 128 + ((rr * 2) ^ ((cc & 7) << 4))]) = val;
      }
      if (tid == 0) scl[j] = 0.f;
      continue;
    }
    const int ttv = l + 1;
    const int wcur = text[n * TT + ttv];
    const int cp = w2c[text[n * TT + ttv - 1]];
    const int cc = w2c[wcur];
    if (tid < 64)
      ev_s[tid] = lall[(size_t)wcur * 64 + tid] - logf(esum[cc * 64 + tid]);
    __syncthreads();
    const int grow = cp * 64 + r;
    const float base = T12[(size_t)grow * 192 + cc] - rlse[grow];
    const float* t2row = T12 + (size_t)grow * 192 + 128 + cb;
    float L[16];
    float mx = -1e30f;
#pragma unroll
    for (int e = 0; e < 16; ++e) {
      L[e] = base + t2row[e] + ev_s[cb + e];
      mx = fmaxf(mx, L[e]);
    }
#pragma unroll
    for (int off = 1; off < 64; off <<= 1) mx = fmaxf(mx, __shfl_xor(mx, off, 64));
    if (lane == 0) wpm[w] = mx;
    __syncthreads();
    const float m = fmaxf(fmaxf(wpm[0], wpm[1]), fmaxf(wpm[2], wpm[3]));
    if ((j & 1) == 0) {                       // even -> A-operand layout
      u16x8 o0, o1;
#pragma unroll
      for (int e = 0; e < 8; ++e) o0[e] = f2bf(exp2f((L[e] - m) * LOG2E));
#pragma unroll
      for (int e = 0; e < 8; ++e) o1[e] = f2bf(exp2f((L[8 + e] - m) * LOG2E));
      const int sw = (r & 7) << 4;
      *reinterpret_cast<u16x8*>(&slot[r * 128 + ((cb * 2) ^ sw)]) = o0;
      *reinterpret_cast<u16x8*>(&slot[r * 128 + ((cb * 2 + 16) ^ sw)]) = o1;
    } else {                                  // odd -> transposed B-operand layout
#pragma unroll
      for (int e = 0; e < 16; ++e) {
        const int col = cb + e;
        const u16 val = f2bf(exp2f((L[e] - m) * LOG2E));
        *reinterpret_cast<u16*>(&slot[col * 128 + ((r * 2) ^ ((col & 7) << 4))]) = val;
      }
    }
    if (tid == 0) scl[j] = m;
  }
  __syncthreads();
  comb4_core(lds, wpm, scl[0], scl[1], scl[2], scl[3],
             dst + ((size_t)(n * 64 + u)) * 4096, &scd[n * 64 + u], u & 1, tid);
}

__global__ __launch_bounds__(256) void comb4_k(const u16* __restrict__ src,
                                               const float* __restrict__ scs,
                                               u16* __restrict__ dst,
                                               float* __restrict__ scd, int U) {
  const int n = blockIdx.x / U, u = blockIdx.x % U;
  __shared__ char lds[49152];
  __shared__ float wpm[8];
  const u16* base = src + ((size_t)(n * 4 * U + 4 * u)) * 4096;
  const float* sb = scs + n * 4 * U + 4 * u;
  comb4_stage(lds, base, base + 4096, base + 2 * 4096, base + 3 * 4096, threadIdx.x);
  comb4_core(lds, wpm, sb[0], sb[1], sb[2], sb[3],
             dst + ((size_t)(n * U + u)) * 4096, &scd[n * U + u], u & 1, threadIdx.x);
}

// ---------------- tail2: 4 -> 1 + hlse + final (16 blocks) ----------------

__global__ __launch_bounds__(256) void tail2_k(
    const u16* __restrict__ nodes, const float* __restrict__ nsc,
    u16* __restrict__ rootb,
    const float* __restrict__ hlog, const float* __restrict__ lall,
    const float* __restrict__ esum, const int* __restrict__ text,
    const int* __restrict__ w2c, float* __restrict__ out) {
  __shared__ char lds[49152];
  __shared__ float wpm[8];
  __shared__ float redm[4];
  __shared__ float hl_s;
  __shared__ float rsc_s;
  const int n = blockIdx.x, tid = threadIdx.x;
  const int lane = tid & 63, w = tid >> 6;

  float mm = -1e30f;
  for (int i = tid; i < CS; i += 256) mm = fmaxf(mm, hlog[i]);
  for (int off = 32; off; off >>= 1) mm = fmaxf(mm, __shfl_xor(mm, off, 64));
  if (lane == 0) redm[w] = mm;
  __syncthreads();
  const float M = fmaxf(fmaxf(redm[0], redm[1]), fmaxf(redm[2], redm[3]));
  float sx = 0.f;
  for (int i = tid; i < CS; i += 256) sx += expf(hlog[i] - M);
  for (int off = 32; off; off >>= 1) sx += __shfl_xor(sx, off, 64);
  __syncthreads();
  if (lane == 0) redm[w] = sx;
  __syncthreads();
  if (tid == 0) hl_s = M + logf(redm[0] + redm[1] + redm[2] + redm[3]);
  __syncthreads();
  const float hlse = hl_s;

  const u16* src = nodes + (size_t)n * 4 * 4096;
  const float* sc = nsc + n * 4;
  u16* root = rootb + (size_t)n * 4096;
  comb4_stage(lds, src, src + 4096, src + 2 * 4096, src + 3 * 4096, tid);
  comb4_core(lds, wpm, sc[0], sc[1], sc[2], sc[3], root, &rsc_s, 0, tid);
  __syncthreads();

  if (tid < 64) {
    const int i = tid;
    const int w0 = text[n * TT];
    const int cc = w2c[w0];
    const float ev = lall[(size_t)w0 * 64 + i] - logf(esum[cc * 64 + i]);
    float a0 = hlog[cc * 64 + i] - hlse + ev;
    float m0 = a0;
    for (int off = 32; off; off >>= 1) m0 = fmaxf(m0, __shfl_xor(m0, off, 64));
    const float lin = expf(a0 - m0);
    const u16* row = root + i * 64;
    float rs = 0.f;
#pragma unroll
    for (int e8 = 0; e8 < 8; ++e8) {
      const u16x8 v = *reinterpret_cast<const u16x8*>(row + e8 * 8);
#pragma unroll
      for (int e = 0; e < 8; ++e) rs += bf2f(v[e]);
    }
    float v = lin * rs;
    for (int off = 32; off; off >>= 1) v += __shfl_xor(v, off, 64);
    if (i == 0) out[n] = m0 + rsc_s + logf(v);
  }
}

// ---------------- host orchestration ----------------

extern "C" void kernel_launch(void* const* d_in, const int* in_sizes, int n_in,
                              void* d_out, int out_size, void* d_ws, size_t ws_size,
                              hipStream_t stream) {
  (void)in_sizes; (void)n_in; (void)out_size; (void)ws_size;
  const int* text = (const int*)d_in[0];
  const int* w2c  = (const int*)d_in[1];
  const float* sec = (const float*)d_in[2];
  const float* ses = (const float*)d_in[3];
  const float* stc = (const float*)d_in[4];
  const float* sts = (const float*)d_in[5];
  const float* nec = (const float*)d_in[6];
  const float* nes = (const float*)d_in[7];
  const float* pec = (const float*)d_in[8];
  const float* pes = (const float*)d_in[9];
  const float* srw1 = (const float*)d_in[10];
  const float* srb1 = (const float*)d_in[11];
  const float* srw2 = (const float*)d_in[12];
  const float* srb2 = (const float*)d_in[13];
  const float* trw1 = (const float*)d_in[14];
  const float* trb1 = (const float*)d_in[15];
  const float* trw2 = (const float*)d_in[16];
  const float* trb2 = (const float*)d_in[17];
  const float* tew1 = (const float*)d_in[18];
  const float* teb1 = (const float*)d_in[19];
  const float* tew2 = (const float*)d_in[20];
  const float* teb2 = (const float*)d_in[21];
  const float* sow = (const float*)d_in[22];
  const float* sob = (const float*)d_in[23];
  const float* tpw = (const float*)d_in[24];
  const float* tpb = (const float*)d_in[25];
  float* out = (float*)d_out;

  char* p = (char*)d_ws;
  auto carve = [&](size_t bytes) -> char* {
    char* r = p; p += (bytes + 255) & ~(size_t)255; return r;
  };
  u16* Wall = (u16*)carve((size_t)WT2 * 2);
  u16* Wpb  = Wall + WTOT;
  u16* Hb0  = (u16*)carve((size_t)CS * HD * 2);
  u16* Hb1  = (u16*)carve((size_t)CS * HD * 2);
  u16* Hb2  = (u16*)carve((size_t)CS * HD * 2);
  float* SHf = (float*)carve((size_t)CS * HD * 4);
  u16* Xbf  = (u16*)carve((size_t)CS * HD * 2);
  u16* PHb  = (u16*)carve((size_t)CS * HD * 2);
  float* T12  = (float*)carve((size_t)CS * 192 * 4);
  float* hlog  = (float*)carve(CS * 4);
  float* rlse  = (float*)carve(CS * 4);
  int* offs    = (int*)carve((KCL + 1) * 4);
  int* wlist   = (int*)carve(VV * 4);
  int* bmap    = (int*)carve(MAXB * 4);
  float* esum  = (float*)carve(CS * 4);
  float* lall  = (float*)carve((size_t)VV * 64 * 4);
  u16*   bufA  = (u16*)carve((size_t)NB * 64 * 4096 * 2);   // L1 out
  u16*   bufB  = (u16*)carve((size_t)NB * 16 * 4096 * 2);   // L2 out
  u16*   bufC  = (u16*)carve((size_t)NB * 4 * 4096 * 2);    // L3 out
  u16*   rootb = (u16*)carve((size_t)NB * 4096 * 2);
  float* scA   = (float*)carve((size_t)NB * 64 * 4);
  float* scB   = (float*)carve((size_t)NB * 16 * 4);
  float* scC   = (float*)carve((size_t)NB * 4 * 4);

  prep_all<<<PREPB + 1, 256, 0, stream>>>(
      srw1, srw2, trw1, trw2, tew1, tew2, tpw, Wall,
      w2c, offs, wlist, bmap, esum);

  mlp_k<1><<<dim3(4, 128, 3), 256, 0, stream>>>(
      sec, ses, stc, sts, pec, pes, Hb0, Hb1, Hb2, Wall,
      srb1, trb1, teb1, nullptr, nullptr, nullptr);
  mlp_k<2><<<dim3(4, 128, 3), 256, 0, stream>>>(
      sec, ses, stc, sts, pec, pes, Hb0, Hb1, Hb2, Wall,
      srb2, trb2, teb2, SHf, Xbf, PHb);

  t12_k<<<CS / 64, 256, 0, stream>>>(Xbf, nec, nes, T12, rlse);
  hd_k<<<CS / 4, 256, 0, stream>>>(SHf, sow, sob, hlog);
  emis_k<<<MAXB, 256, 0, stream>>>(Wpb, PHb, tpb, offs, wlist, bmap, esum, lall);

  // fused elementwise-leaf + level-1 combine: 256 leaves -> 64 nodes per seq
  leafc2_k<<<NB * 64, 256, 0, stream>>>(
      T12, rlse, lall, esum, text, w2c, bufA, scA);

  comb4_k<<<NB * 16, 256, 0, stream>>>(bufA, scA, bufB, scB, 16);
  comb4_k<<<NB * 4, 256, 0, stream>>>(bufB, scB, bufC, scC, 4);
  tail2_k<<<NB, 256, 0, stream>>>(bufC, scC, rootb, hlog, lall, esum, text, w2c, out);
}

// Round 20
// 126.123 us; speedup vs baseline: 1.7669x; 1.0770x over previous
//
#include <hip/hip_runtime.h>
#include <hip/hip_bf16.h>

// FactoredHmmLm forward on MI355X.
// ALGEBRA: nse[k*64+s]=nec[k]+nes[s] => tr[i,k*64+s]=T1[i,k]+T2[i,s]
//   => rlse = lse(T1)+lse(T2); leaf tiles are elementwise from T12.
//  1. prep_all: weights->bf16 (grid-stride) + CSR/esum/hlog-init (last block)
//  2. mlp_k<1>/<2>: batched residual MLPs (emb in-register);
//     mlp2 z==0 fuses the start-head dot via atomicAdd into hlog (no SHf)
//  3. te_k: t12 GEMM (first 128 blocks) + emission GEMM (rest) in one launch
//  4. leafc2_k: 4 elementwise leaves in swizzled LDS + combine -> 64 nodes/seq
//  5. comb4_k x2 (64->16->4) + tail2_k (4->1 + hlse + final)

using u16 = unsigned short;
typedef __attribute__((ext_vector_type(8))) short bh8;     // 8 bf16 (4 VGPRs)
typedef __attribute__((ext_vector_type(4))) float f32x4;
typedef __attribute__((ext_vector_type(8))) unsigned short u16x8;

#define HD 256
#define TT 256
#define NB 16
#define KCL 128
#define CS 8192
#define VV 10000
#define MAXB 320
#define LOG2E 1.44269504f
#define WTOT (6 * 65536)
#define WT2  (WTOT + VV * HD)
#define NELEM8 (WT2 / 8)                     // weights only
#define PREPB 1024

__device__ __forceinline__ u16 f2bf(float v) {
  union { float f; unsigned int i; } u; u.f = v;
  unsigned int r = u.i + 0x7fffu + ((u.i >> 16) & 1u);   // RNE
  return (u16)(r >> 16);
}
__device__ __forceinline__ float bf2f(u16 u) {
  union { unsigned int i; float f; } x; x.i = ((unsigned int)u) << 16; return x.f;
}
__device__ __forceinline__ void gl2lds16(const u16* g, u16* l) {
  __builtin_amdgcn_global_load_lds(
      (const __attribute__((address_space(1))) unsigned int*)g,
      (__attribute__((address_space(3))) unsigned int*)l, 16, 0, 0);
}
__device__ __forceinline__ u16x8 cvt8(const float* __restrict__ s) {
  const float4 a = *reinterpret_cast<const float4*>(s);
  const float4 b = *reinterpret_cast<const float4*>(s + 4);
  u16x8 o;
  o[0] = f2bf(a.x); o[1] = f2bf(a.y); o[2] = f2bf(a.z); o[3] = f2bf(a.w);
  o[4] = f2bf(b.x); o[5] = f2bf(b.y); o[6] = f2bf(b.z); o[7] = f2bf(b.w);
  return o;
}
__device__ __forceinline__ u16x8 add_cvt8(const float* __restrict__ s0,
                                          const float* __restrict__ s1) {
  const float4 a0 = *reinterpret_cast<const float4*>(s0);
  const float4 b0 = *reinterpret_cast<const float4*>(s0 + 4);
  const float4 a1 = *reinterpret_cast<const float4*>(s1);
  const float4 b1 = *reinterpret_cast<const float4*>(s1 + 4);
  u16x8 o;
  o[0] = f2bf(a0.x + a1.x); o[1] = f2bf(a0.y + a1.y);
  o[2] = f2bf(a0.z + a1.z); o[3] = f2bf(a0.w + a1.w);
  o[4] = f2bf(b0.x + b1.x); o[5] = f2bf(b0.y + b1.y);
  o[6] = f2bf(b0.z + b1.z); o[7] = f2bf(b0.w + b1.w);
  return o;
}

// ---------------- prep_all: weights -> bf16 + CSR/esum/hlog (last block) ----------------

__global__ __launch_bounds__(256) void prep_all(
    const float* __restrict__ w0, const float* __restrict__ w1,
    const float* __restrict__ w2, const float* __restrict__ w3,
    const float* __restrict__ w4, const float* __restrict__ w5,
    const float* __restrict__ tpw, u16* __restrict__ dstW,
    const int* __restrict__ w2c, int* __restrict__ offs,
    int* __restrict__ wlist, int* __restrict__ bmap,
    float* __restrict__ esum, float* __restrict__ hlog,
    const float* __restrict__ sob) {
  const int b = blockIdx.x, tid = threadIdx.x;
  if (b < PREPB) {
    for (int i = b * 256 + tid; i < NELEM8; i += PREPB * 256) {
      const int idx = i * 8;
      if (idx < WTOT) {
        const int wi = idx >> 16;
        const float* s = wi == 0 ? w0 : wi == 1 ? w1 : wi == 2 ? w2
                       : wi == 3 ? w3 : wi == 4 ? w4 : w5;
        *reinterpret_cast<u16x8*>(dstW + idx) = cvt8(s + (idx & 65535));
      } else {
        *reinterpret_cast<u16x8*>(dstW + idx) = cvt8(tpw + (idx - WTOT));
      }
    }
    return;
  }
  __shared__ int cnt[KCL], cur[KCL];
  __shared__ int wsA[2], wsB[2];
  __shared__ int totb_s;
  const int lane = tid & 63, w = tid >> 6;
  if (tid < KCL) cnt[tid] = 0;
  __syncthreads();
  for (int v = tid; v < VV; v += 256) atomicAdd(&cnt[w2c[v]], 1);
  __syncthreads();
  int c = 0, x = 0;
  if (tid < KCL) {
    c = cnt[tid];
    x = c;
#pragma unroll
    for (int off = 1; off < 64; off <<= 1) {
      const int y = __shfl_up(x, off, 64);
      if (lane >= off) x += y;
    }
    if (lane == 63) wsA[w] = x;
  }
  __syncthreads();
  int nb = 0, xs = 0;
  if (tid < KCL) {
    const int base = (w == 1) ? wsA[0] : 0;
    const int excl = base + x - c;
    offs[tid] = excl;
    cur[tid] = excl;
    if (tid == KCL - 1) offs[KCL] = base + x;
    nb = (c + 63) >> 6;
    xs = nb;
#pragma unroll
    for (int off = 1; off < 64; off <<= 1) {
      const int y = __shfl_up(xs, off, 64);
      if (lane >= off) xs += y;
    }
    if (lane == 63) wsB[w] = xs;
  }
  __syncthreads();
  if (tid < KCL) {
    const int base = (w == 1) ? wsB[0] : 0;
    const int b0 = base + xs - nb;
    for (int bb = 0; bb < nb; ++bb) bmap[b0 + bb] = (tid << 8) | bb;
    if (tid == KCL - 1) totb_s = base + xs;
  }
  __syncthreads();
  const int totb = totb_s;
  for (int i = totb + tid; i < MAXB; i += 256) bmap[i] = -1;
  for (int v = tid; v < VV; v += 256) {
    const int pos = atomicAdd(&cur[w2c[v]], 1);
    wlist[pos] = v;
  }
  const float sb0 = sob[0];
  for (int i = tid; i < CS; i += 256) { esum[i] = 0.f; hlog[i] = sb0; }
}

// ---------------- batched residual-MLP GEMMs (LAYER1: emb in-register) --------
// LAYER2, z==0: fused start-head dot -> atomicAdd hlog (no SHf buffer)

template<int LAYER>
__global__ __launch_bounds__(256) void mlp_k(
    const float* __restrict__ ec0, const float* __restrict__ es0,
    const float* __restrict__ ec1, const float* __restrict__ es1,
    const float* __restrict__ ec2, const float* __restrict__ es2,
    u16* __restrict__ H0, u16* __restrict__ H1, u16* __restrict__ H2,
    const u16* __restrict__ Wall,
    const float* __restrict__ bb0, const float* __restrict__ bb1, const float* __restrict__ bb2,
    const float* __restrict__ sow, float* __restrict__ hlog,
    u16* __restrict__ Xbf, u16* __restrict__ PHb) {
  __shared__ char lds[16384];
  const int tid = threadIdx.x, lane = tid & 63, wid = tid >> 6;
  const int z = blockIdx.z;
  const float* ec = z == 0 ? ec0 : z == 1 ? ec1 : ec2;
  const float* es = z == 0 ? es0 : z == 1 ? es1 : es2;
  u16* Hb = z == 0 ? H0 : z == 1 ? H1 : H2;
  const u16* B = Wall + (size_t)(2 * z + (LAYER - 1)) * 65536;
  const float* bias = z == 0 ? bb0 : z == 1 ? bb1 : bb2;

  const int rm = blockIdx.y * 64, cn = blockIdx.x * 64;
  const u16* Bg = B + (size_t)cn * HD;

  f32x4 acc[4];
#pragma unroll
  for (int i = 0; i < 4; ++i) acc[i] = (f32x4){0.f, 0.f, 0.f, 0.f};
  const int ra = wid * 16 + (lane & 15);
  const int rb0 = lane & 15;
  const int ko = (lane >> 4) * 8;

  for (int kc = 0; kc < HD; kc += 64) {
    if (kc) __syncthreads();
#pragma unroll
    for (int i = 0; i < 2; ++i) {
      const int c = i * 256 + tid;
      const int r = c >> 3, cb = c & 7;
      const int gq = cb ^ (r & 7);
      if (LAYER == 1) {
        const int grow = rm + r;
        const int krow = grow >> 6, srow = grow & 63;
        const int h0 = kc + cb * 8;
        const u16x8 v = add_cvt8(ec + krow * HD + h0, es + srow * HD + h0);
        *reinterpret_cast<u16x8*>(&lds[r * 128 + ((cb * 16) ^ ((r & 7) << 4))]) = v;
      } else {
        gl2lds16(Hb + (size_t)(rm + r) * HD + kc + gq * 8, (u16*)&lds[c * 16]);
      }
      gl2lds16(Bg + (size_t)r * HD + kc + gq * 8, (u16*)&lds[8192 + c * 16]);
    }
    __syncthreads();
#pragma unroll
    for (int kk = 0; kk < 64; kk += 32) {
      const int kb = (kk + ko) * 2;
      const bh8 af = *reinterpret_cast<const bh8*>(&lds[ra * 128 + (kb ^ ((ra & 7) << 4))]);
#pragma unroll
      for (int nj = 0; nj < 4; ++nj) {
        const int rb = nj * 16 + rb0;
        const bh8 bf = *reinterpret_cast<const bh8*>(&lds[8192 + rb * 128 + (kb ^ ((rb & 7) << 4))]);
        acc[nj] = __builtin_amdgcn_mfma_f32_16x16x32_bf16(af, bf, acc[nj], 0, 0, 0);
      }
    }
  }

  const int g = lane >> 4, c0 = lane & 15;
  float pd[4] = {0.f, 0.f, 0.f, 0.f};         // head-dot partials (LAYER2 z==0)
#pragma unroll
  for (int nj = 0; nj < 4; ++nj) {
    const int nidx = cn + nj * 16 + c0;
    const float bv = bias[nidx];
#pragma unroll
    for (int reg = 0; reg < 4; ++reg) {
      const int midx = rm + wid * 16 + g * 4 + reg;
      float v = acc[nj][reg] + bv;
      if (LAYER == 2)
        v += ec[(midx >> 6) * HD + nidx] + es[(midx & 63) * HD + nidx];
      v = fmaxf(v, 0.f);
      if (LAYER == 1) {
        Hb[(size_t)midx * 256 + nidx] = f2bf(v);
      } else {
        if (z == 0) pd[reg] += v * sow[nidx];
        else if (z == 1) Xbf[(size_t)midx * 256 + nidx] = f2bf(v);
        else PHb[(size_t)midx * 256 + nidx] = f2bf(v);
      }
    }
  }
  if (LAYER == 2 && blockIdx.z == 0) {
#pragma unroll
    for (int off = 1; off < 16; off <<= 1)
#pragma unroll
      for (int reg = 0; reg < 4; ++reg)
        pd[reg] += __shfl_xor(pd[reg], off, 64);
    if (c0 == 0) {
#pragma unroll
      for (int reg = 0; reg < 4; ++reg)
        atomicAdd(&hlog[rm + wid * 16 + g * 4 + reg], pd[reg]);
    }
  }
}

// ---------------- te_k: t12 GEMM (blocks 0..127) + emission GEMM (blocks 128..) --------

__global__ __launch_bounds__(256) void te_k(
    const u16* __restrict__ Xbf, const float* __restrict__ nec,
    const float* __restrict__ nes,
    float* __restrict__ T12, float* __restrict__ rlse,
    const u16* __restrict__ Wpb, const u16* __restrict__ PHb,
    const float* __restrict__ bp,
    const int* __restrict__ offs, const int* __restrict__ wlist,
    const int* __restrict__ map,
    float* __restrict__ esum, float* __restrict__ logits_all) {
  __shared__ char lds[32768];
  const int tid = threadIdx.x, lane = tid & 63, wid = tid >> 6;
  const int rb0 = lane & 15;
  const int ko = (lane >> 4) * 8;
  const int g = lane >> 4, c0 = lane & 15;

  if (blockIdx.x < CS / 64) {
    // ---------- t12 part ----------
    const int rm = blockIdx.x * 64;
    const int ra = wid * 16 + (lane & 15);
    f32x4 acc[12];
#pragma unroll
    for (int i = 0; i < 12; ++i) acc[i] = (f32x4){0.f, 0.f, 0.f, 0.f};

    for (int kc = 0; kc < HD; kc += 64) {
      if (kc) __syncthreads();
#pragma unroll
      for (int i = 0; i < 2; ++i) {
        const int c = i * 256 + tid;
        const int r = c >> 3, cb = c & 7;
        const int gq = cb ^ (r & 7);
        gl2lds16(Xbf + (size_t)(rm + r) * HD + kc + gq * 8, (u16*)&lds[c * 16]);
      }
#pragma unroll
      for (int i = 0; i < 6; ++i) {
        const int c = i * 256 + tid;        // 0..1535 -> 192 rows x 8 chunks
        const int r = c >> 3, cb = c & 7;
        const float* src = (r < KCL) ? (nec + r * HD + kc + cb * 8)
                                     : (nes + (r - KCL) * HD + kc + cb * 8);
        const u16x8 v = cvt8(src);
        *reinterpret_cast<u16x8*>(&lds[8192 + r * 128 + ((cb * 16) ^ ((r & 7) << 4))]) = v;
      }
      __syncthreads();
#pragma unroll
      for (int kk = 0; kk < 64; kk += 32) {
        const int kb = (kk + ko) * 2;
        const bh8 af = *reinterpret_cast<const bh8*>(&lds[ra * 128 + (kb ^ ((ra & 7) << 4))]);
#pragma unroll
        for (int nj = 0; nj < 12; ++nj) {
          const int rb = nj * 16 + rb0;
          const bh8 bf = *reinterpret_cast<const bh8*>(&lds[8192 + rb * 128 + (kb ^ ((rb & 7) << 4))]);
          acc[nj] = __builtin_amdgcn_mfma_f32_16x16x32_bf16(af, bf, acc[nj], 0, 0, 0);
        }
      }
    }

    float rs1[4] = {0.f, 0.f, 0.f, 0.f};
    float rs2[4] = {0.f, 0.f, 0.f, 0.f};
#pragma unroll
    for (int nj = 0; nj < 12; ++nj) {
      const int col = nj * 16 + c0;
#pragma unroll
      for (int reg = 0; reg < 4; ++reg) {
        const int row = rm + wid * 16 + g * 4 + reg;
        const float v = acc[nj][reg];
        T12[(size_t)row * 192 + col] = v;
        const float e = exp2f(v * LOG2E);
        if (nj < 8) rs1[reg] += e; else rs2[reg] += e;
      }
    }
#pragma unroll
    for (int off = 1; off < 16; off <<= 1)
#pragma unroll
      for (int reg = 0; reg < 4; ++reg) {
        rs1[reg] += __shfl_xor(rs1[reg], off, 64);
        rs2[reg] += __shfl_xor(rs2[reg], off, 64);
      }
    if (c0 == 0) {
#pragma unroll
      for (int reg = 0; reg < 4; ++reg)
        rlse[rm + wid * 16 + g * 4 + reg] = logf(rs1[reg]) + logf(rs2[reg]);
    }
    return;
  }

  // ---------- emission part ----------
  const int ent = map[blockIdx.x - CS / 64];
  if (ent < 0) return;
  const int c = ent >> 8, blk = ent & 255;
  __shared__ int wid_s[64];
  const int st = offs[c], cnt = offs[c + 1] - st;
  if (tid < 64) {
    const int idx = blk * 64 + tid;
    wid_s[tid] = (idx < cnt) ? wlist[st + idx] : -1;
  }
  __syncthreads();

  f32x4 acc[4];
#pragma unroll
  for (int i = 0; i < 4; ++i) acc[i] = (f32x4){0.f, 0.f, 0.f, 0.f};
  const int ra = wid * 16 + (lane & 15);
  const u16* Bg = PHb + (size_t)(c * 64) * HD;

  for (int kc = 0; kc < HD; kc += 64) {
    if (kc) __syncthreads();
#pragma unroll
    for (int i = 0; i < 2; ++i) {
      const int cc = i * 256 + tid;
      const int r = cc >> 3, cb = cc & 7;
      const int gq = cb ^ (r & 7);
      const int wv = max(wid_s[r], 0);
      gl2lds16(Wpb + (size_t)wv * HD + kc + gq * 8, (u16*)&lds[cc * 16]);
      gl2lds16(Bg + (size_t)r * HD + kc + gq * 8, (u16*)&lds[8192 + cc * 16]);
    }
    __syncthreads();
#pragma unroll
    for (int kk = 0; kk < 64; kk += 32) {
      const int kb = (kk + ko) * 2;
      const bh8 af = *reinterpret_cast<const bh8*>(&lds[ra * 128 + (kb ^ ((ra & 7) << 4))]);
#pragma unroll
      for (int nj = 0; nj < 4; ++nj) {
        const int rb = nj * 16 + rb0;
        const bh8 bf = *reinterpret_cast<const bh8*>(&lds[8192 + rb * 128 + (kb ^ ((rb & 7) << 4))]);
        acc[nj] = __builtin_amdgcn_mfma_f32_16x16x32_bf16(af, bf, acc[nj], 0, 0, 0);
      }
    }
  }

#pragma unroll
  for (int nj = 0; nj < 4; ++nj) {
    float se = 0.f;
#pragma unroll
    for (int reg = 0; reg < 4; ++reg) {
      const int row = wid * 16 + g * 4 + reg;
      const int w = wid_s[row];
      if (w >= 0) {
        const float lg = acc[nj][reg] + bp[w];
        logits_all[(size_t)w * 64 + nj * 16 + c0] = lg;
        se += expf(lg);
      }
    }
    se += __shfl_xor(se, 16, 64);
    se += __shfl_xor(se, 32, 64);
    if (g == 0) atomicAdd(&esum[c * 64 + nj * 16 + c0], se);
  }
}

// ---------------- quad combine core (tiles in swizzled LDS slots) ----------------

__device__ __forceinline__ void comb4_core(
    char* lds, float* wpm,
    float sc0, float sc1, float sc2, float sc3,
    u16* node, float* dsc, int parity, int tid) {
  const int lane = tid & 63, w = tid >> 6;
  const int p = w >> 1, h = w & 1;
  const int abase = p * 16384, bbase = abase + 8192;
  const int c0 = lane & 15, g = lane >> 4;
  f32x4 a2[2][4];
#pragma unroll
  for (int mi = 0; mi < 2; ++mi)
#pragma unroll
    for (int nj = 0; nj < 4; ++nj) a2[mi][nj] = (f32x4){0.f, 0.f, 0.f, 0.f};
#pragma unroll
  for (int kk = 0; kk < 64; kk += 32) {
    const int kb = (kk + g * 8) * 2;
    bh8 af[2], bf[4];
#pragma unroll
    for (int mi = 0; mi < 2; ++mi) {
      const int ar = h * 32 + mi * 16 + c0;
      af[mi] = *reinterpret_cast<const bh8*>(&lds[abase + ar * 128 + (kb ^ ((ar & 7) << 4))]);
    }
#pragma unroll
    for (int nj = 0; nj < 4; ++nj) {
      const int br = nj * 16 + c0;
      bf[nj] = *reinterpret_cast<const bh8*>(&lds[bbase + br * 128 + (kb ^ ((br & 7) << 4))]);
    }
#pragma unroll
    for (int mi = 0; mi < 2; ++mi)
#pragma unroll
      for (int nj = 0; nj < 4; ++nj)
        a2[mi][nj] = __builtin_amdgcn_mfma_f32_16x16x32_bf16(af[mi], bf[nj], a2[mi][nj], 0, 0, 0);
  }
  float mx = 0.f;
#pragma unroll
  for (int mi = 0; mi < 2; ++mi)
#pragma unroll
    for (int nj = 0; nj < 4; ++nj)
#pragma unroll
      for (int reg = 0; reg < 4; ++reg) mx = fmaxf(mx, a2[mi][nj][reg]);
#pragma unroll
  for (int off = 1; off < 64; off <<= 1) mx = fmaxf(mx, __shfl_xor(mx, off, 64));
  if (lane == 0) wpm[w] = mx;
  __syncthreads();
  const float mp = fmaxf(wpm[p * 2], wpm[p * 2 + 1]);
  const float invp = 1.0f / mp;
#pragma unroll
  for (int mi = 0; mi < 2; ++mi)
#pragma unroll
    for (int nj = 0; nj < 4; ++nj)
#pragma unroll
      for (int reg = 0; reg < 4; ++reg) {
        const int row = h * 32 + mi * 16 + g * 4 + reg;
        const int col = nj * 16 + c0;
        const u16 val = f2bf(a2[mi][nj][reg] * invp);
        if (p == 0)
          *reinterpret_cast<u16*>(&lds[32768 + row * 128 + ((col * 2) ^ ((row & 7) << 4))]) = val;
        else
          *reinterpret_cast<u16*>(&lds[40960 + col * 128 + ((row * 2) ^ ((col & 7) << 4))]) = val;
      }
  __syncthreads();

  f32x4 acc[4];
#pragma unroll
  for (int i = 0; i < 4; ++i) acc[i] = (f32x4){0.f, 0.f, 0.f, 0.f};
  const int ra = w * 16 + c0;
#pragma unroll
  for (int kk = 0; kk < 64; kk += 32) {
    const int kb = (kk + g * 8) * 2;
    const bh8 af = *reinterpret_cast<const bh8*>(&lds[32768 + ra * 128 + (kb ^ ((ra & 7) << 4))]);
#pragma unroll
    for (int nj = 0; nj < 4; ++nj) {
      const int rb = nj * 16 + c0;
      const bh8 bf = *reinterpret_cast<const bh8*>(&lds[40960 + rb * 128 + (kb ^ ((rb & 7) << 4))]);
      acc[nj] = __builtin_amdgcn_mfma_f32_16x16x32_bf16(af, bf, acc[nj], 0, 0, 0);
    }
  }
  float mx2 = 0.f;
#pragma unroll
  for (int nj = 0; nj < 4; ++nj)
#pragma unroll
    for (int reg = 0; reg < 4; ++reg) mx2 = fmaxf(mx2, acc[nj][reg]);
#pragma unroll
  for (int off = 1; off < 64; off <<= 1) mx2 = fmaxf(mx2, __shfl_xor(mx2, off, 64));
  if (lane == 0) wpm[4 + w] = mx2;
  __syncthreads();
  const float m = fmaxf(fmaxf(wpm[4], wpm[5]), fmaxf(wpm[6], wpm[7]));
  const float inv = 1.0f / m;
  float* ftile = reinterpret_cast<float*>(lds);
#pragma unroll
  for (int nj = 0; nj < 4; ++nj)
#pragma unroll
    for (int reg = 0; reg < 4; ++reg)
      ftile[(w * 16 + g * 4 + reg) * 64 + nj * 16 + c0] = acc[nj][reg] * inv;
  __syncthreads();
  const int rr = tid >> 2, cb = (tid & 3) * 16;
  u16x8 o0, o1;
  if (parity == 0) {
#pragma unroll
    for (int e = 0; e < 8; ++e) o0[e] = f2bf(ftile[rr * 64 + cb + e]);
#pragma unroll
    for (int e = 0; e < 8; ++e) o1[e] = f2bf(ftile[rr * 64 + cb + 8 + e]);
  } else {
#pragma unroll
    for (int e = 0; e < 8; ++e) o0[e] = f2bf(ftile[(cb + e) * 64 + rr]);
#pragma unroll
    for (int e = 0; e < 8; ++e) o1[e] = f2bf(ftile[(cb + 8 + e) * 64 + rr]);
  }
  *reinterpret_cast<u16x8*>(node + rr * 64 + cb) = o0;
  *reinterpret_cast<u16x8*>(node + rr * 64 + cb + 8) = o1;
  if (tid == 0)
    *dsc = sc0 + sc1 + sc2 + sc3
         + logf(fmaxf(wpm[0], wpm[1])) + logf(fmaxf(wpm[2], wpm[3])) + logf(m);
}

__device__ __forceinline__ void comb4_stage(
    char* lds, const u16* s0, const u16* s1, const u16* s2, const u16* s3, int tid) {
  const u16* srcs[4] = {s0, s1, s2, s3};
  const int sr = tid >> 3, scb = (tid & 7) * 16;
#pragma unroll
  for (int nd = 0; nd < 4; ++nd)
#pragma unroll
    for (int rep = 0; rep < 2; ++rep) {
      const int r = rep * 32 + sr;
      const bh8 v = *reinterpret_cast<const bh8*>(srcs[nd] + r * 64 + (scb >> 1));
      *reinterpret_cast<bh8*>(&lds[nd * 8192 + r * 128 + (scb ^ ((r & 7) << 4))]) = v;
    }
  __syncthreads();
}

// ---------------- leafc2_k: 4 elementwise leaves in LDS + combine ----------------

__global__ __launch_bounds__(256) void leafc2_k(
    const float* __restrict__ T12, const float* __restrict__ rlse,
    const float* __restrict__ lall, const float* __restrict__ esum,
    const int* __restrict__ text, const int* __restrict__ w2c,
    u16* __restrict__ dst, float* __restrict__ scd) {
  __shared__ char lds[49152];
  __shared__ float wpm[8];
  __shared__ float scl[4];
  __shared__ float ev_s[64];
  const int tid = threadIdx.x, lane = tid & 63, w = tid >> 6;
  const int n = blockIdx.x >> 6, u = blockIdx.x & 63;
  const int r = tid >> 2, cb = (tid & 3) * 16;

  for (int j = 0; j < 4; ++j) {
    const int l = 4 * u + j;
    char* slot = &lds[j * 8192];
    __syncthreads();
    if (l == 255) {
      for (int idx = tid; idx < 4096; idx += 256) {
        const int rr = idx >> 6, cc = idx & 63;
        const u16 val = (rr == cc) ? (u16)0x3F80 : (u16)0;
        *reinterpret_cast<u16*>(&slot[cc * 128 + ((rr * 2) ^ ((cc & 7) << 4))]) = val;
      }
      if (tid == 0) scl[j] = 0.f;
      continue;
    }
    const int ttv = l + 1;
    const int wcur = text[n * TT + ttv];
    const int cp = w2c[text[n * TT + ttv - 1]];
    const int cc = w2c[wcur];
    if (tid < 64)
      ev_s[tid] = lall[(size_t)wcur * 64 + tid] - logf(esum[cc * 64 + tid]);
    __syncthreads();
    const int grow = cp * 64 + r;
    const float base = T12[(size_t)grow * 192 + cc] - rlse[grow];
    const float* t2row = T12 + (size_t)grow * 192 + 128 + cb;
    float L[16];
    float mx = -1e30f;
#pragma unroll
    for (int e = 0; e < 16; ++e) {
      L[e] = base + t2row[e] + ev_s[cb + e];
      mx = fmaxf(mx, L[e]);
    }
#pragma unroll
    for (int off = 1; off < 64; off <<= 1) mx = fmaxf(mx, __shfl_xor(mx, off, 64));
    if (lane == 0) wpm[w] = mx;
    __syncthreads();
    const float m = fmaxf(fmaxf(wpm[0], wpm[1]), fmaxf(wpm[2], wpm[3]));
    if ((j & 1) == 0) {
      u16x8 o0, o1;
#pragma unroll
      for (int e = 0; e < 8; ++e) o0[e] = f2bf(exp2f((L[e] - m) * LOG2E));
#pragma unroll
      for (int e = 0; e < 8; ++e) o1[e] = f2bf(exp2f((L[8 + e] - m) * LOG2E));
      const int sw = (r & 7) << 4;
      *reinterpret_cast<u16x8*>(&slot[r * 128 + ((cb * 2) ^ sw)]) = o0;
      *reinterpret_cast<u16x8*>(&slot[r * 128 + ((cb * 2 + 16) ^ sw)]) = o1;
    } else {
#pragma unroll
      for (int e = 0; e < 16; ++e) {
        const int col = cb + e;
        const u16 val = f2bf(exp2f((L[e] - m) * LOG2E));
        *reinterpret_cast<u16*>(&slot[col * 128 + ((r * 2) ^ ((col & 7) << 4))]) = val;
      }
    }
    if (tid == 0) scl[j] = m;
  }
  __syncthreads();
  comb4_core(lds, wpm, scl[0], scl[1], scl[2], scl[3],
             dst + ((size_t)(n * 64 + u)) * 4096, &scd[n * 64 + u], u & 1, tid);
}

__global__ __launch_bounds__(256) void comb4_k(const u16* __restrict__ src,
                                               const float* __restrict__ scs,
                                               u16* __restrict__ dst,
                                               float* __restrict__ scd, int U) {
  const int n = blockIdx.x / U, u = blockIdx.x % U;
  __shared__ char lds[49152];
  __shared__ float wpm[8];
  const u16* base = src + ((size_t)(n * 4 * U + 4 * u)) * 4096;
  const float* sb = scs + n * 4 * U + 4 * u;
  comb4_stage(lds, base, base + 4096, base + 2 * 4096, base + 3 * 4096, threadIdx.x);
  comb4_core(lds, wpm, sb[0], sb[1], sb[2], sb[3],
             dst + ((size_t)(n * U + u)) * 4096, &scd[n * U + u], u & 1, threadIdx.x);
}

// ---------------- tail2: 4 -> 1 + hlse + final (16 blocks) ----------------

__global__ __launch_bounds__(256) void tail2_k(
    const u16* __restrict__ nodes, const float* __restrict__ nsc,
    u16* __restrict__ rootb,
    const float* __restrict__ hlog, const float* __restrict__ lall,
    const float* __restrict__ esum, const int* __restrict__ text,
    const int* __restrict__ w2c, float* __restrict__ out) {
  __shared__ char lds[49152];
  __shared__ float wpm[8];
  __shared__ float redm[4];
  __shared__ float hl_s;
  __shared__ float rsc_s;
  const int n = blockIdx.x, tid = threadIdx.x;
  const int lane = tid & 63, w = tid >> 6;

  float mm = -1e30f;
  for (int i = tid; i < CS; i += 256) mm = fmaxf(mm, hlog[i]);
  for (int off = 32; off; off >>= 1) mm = fmaxf(mm, __shfl_xor(mm, off, 64));
  if (lane == 0) redm[w] = mm;
  __syncthreads();
  const float M = fmaxf(fmaxf(redm[0], redm[1]), fmaxf(redm[2], redm[3]));
  float sx = 0.f;
  for (int i = tid; i < CS; i += 256) sx += expf(hlog[i] - M);
  for (int off = 32; off; off >>= 1) sx += __shfl_xor(sx, off, 64);
  __syncthreads();
  if (lane == 0) redm[w] = sx;
  __syncthreads();
  if (tid == 0) hl_s = M + logf(redm[0] + redm[1] + redm[2] + redm[3]);
  __syncthreads();
  const float hlse = hl_s;

  const u16* src = nodes + (size_t)n * 4 * 4096;
  const float* sc = nsc + n * 4;
  u16* root = rootb + (size_t)n * 4096;
  comb4_stage(lds, src, src + 4096, src + 2 * 4096, src + 3 * 4096, tid);
  comb4_core(lds, wpm, sc[0], sc[1], sc[2], sc[3], root, &rsc_s, 0, tid);
  __syncthreads();

  if (tid < 64) {
    const int i = tid;
    const int w0 = text[n * TT];
    const int cc = w2c[w0];
    const float ev = lall[(size_t)w0 * 64 + i] - logf(esum[cc * 64 + i]);
    float a0 = hlog[cc * 64 + i] - hlse + ev;
    float m0 = a0;
    for (int off = 32; off; off >>= 1) m0 = fmaxf(m0, __shfl_xor(m0, off, 64));
    const float lin = expf(a0 - m0);
    const u16* row = root + i * 64;
    float rs = 0.f;
#pragma unroll
    for (int e8 = 0; e8 < 8; ++e8) {
      const u16x8 v = *reinterpret_cast<const u16x8*>(row + e8 * 8);
#pragma unroll
      for (int e = 0; e < 8; ++e) rs += bf2f(v[e]);
    }
    float v = lin * rs;
    for (int off = 32; off; off >>= 1) v += __shfl_xor(v, off, 64);
    if (i == 0) out[n] = m0 + rsc_s + logf(v);
  }
}

// ---------------- host orchestration ----------------

extern "C" void kernel_launch(void* const* d_in, const int* in_sizes, int n_in,
                              void* d_out, int out_size, void* d_ws, size_t ws_size,
                              hipStream_t stream) {
  (void)in_sizes; (void)n_in; (void)out_size; (void)ws_size;
  const int* text = (const int*)d_in[0];
  const int* w2c  = (const int*)d_in[1];
  const float* sec = (const float*)d_in[2];
  const float* ses = (const float*)d_in[3];
  const float* stc = (const float*)d_in[4];
  const float* sts = (const float*)d_in[5];
  const float* nec = (const float*)d_in[6];
  const float* nes = (const float*)d_in[7];
  const float* pec = (const float*)d_in[8];
  const float* pes = (const float*)d_in[9];
  const float* srw1 = (const float*)d_in[10];
  const float* srb1 = (const float*)d_in[11];
  const float* srw2 = (const float*)d_in[12];
  const float* srb2 = (const float*)d_in[13];
  const float* trw1 = (const float*)d_in[14];
  const float* trb1 = (const float*)d_in[15];
  const float* trw2 = (const float*)d_in[16];
  const float* trb2 = (const float*)d_in[17];
  const float* tew1 = (const float*)d_in[18];
  const float* teb1 = (const float*)d_in[19];
  const float* tew2 = (const float*)d_in[20];
  const float* teb2 = (const float*)d_in[21];
  const float* sow = (const float*)d_in[22];
  const float* sob = (const float*)d_in[23];
  const float* tpw = (const float*)d_in[24];
  const float* tpb = (const float*)d_in[25];
  float* out = (float*)d_out;

  char* p = (char*)d_ws;
  auto carve = [&](size_t bytes) -> char* {
    char* r = p; p += (bytes + 255) & ~(size_t)255; return r;
  };
  u16* Wall = (u16*)carve((size_t)WT2 * 2);
  u16* Wpb  = Wall + WTOT;
  u16* Hb0  = (u16*)carve((size_t)CS * HD * 2);
  u16* Hb1  = (u16*)carve((size_t)CS * HD * 2);
  u16* Hb2  = (u16*)carve((size_t)CS * HD * 2);
  u16* Xbf  = (u16*)carve((size_t)CS * HD * 2);
  u16* PHb  = (u16*)carve((size_t)CS * HD * 2);
  float* T12  = (float*)carve((size_t)CS * 192 * 4);
  float* hlog  = (float*)carve(CS * 4);
  float* rlse  = (float*)carve(CS * 4);
  int* offs    = (int*)carve((KCL + 1) * 4);
  int* wlist   = (int*)carve(VV * 4);
  int* bmap    = (int*)carve(MAXB * 4);
  float* esum  = (float*)carve(CS * 4);
  float* lall  = (float*)carve((size_t)VV * 64 * 4);
  u16*   bufA  = (u16*)carve((size_t)NB * 64 * 4096 * 2);   // L1 out
  u16*   bufB  = (u16*)carve((size_t)NB * 16 * 4096 * 2);   // L2 out
  u16*   bufC  = (u16*)carve((size_t)NB * 4 * 4096 * 2);    // L3 out
  u16*   rootb = (u16*)carve((size_t)NB * 4096 * 2);
  float* scA   = (float*)carve((size_t)NB * 64 * 4);
  float* scB   = (float*)carve((size_t)NB * 16 * 4);
  float* scC   = (float*)carve((size_t)NB * 4 * 4);

  prep_all<<<PREPB + 1, 256, 0, stream>>>(
      srw1, srw2, trw1, trw2, tew1, tew2, tpw, Wall,
      w2c, offs, wlist, bmap, esum, hlog, sob);

  mlp_k<1><<<dim3(4, 128, 3), 256, 0, stream>>>(
      sec, ses, stc, sts, pec, pes, Hb0, Hb1, Hb2, Wall,
      srb1, trb1, teb1, sow, hlog, nullptr, nullptr);
  mlp_k<2><<<dim3(4, 128, 3), 256, 0, stream>>>(
      sec, ses, stc, sts, pec, pes, Hb0, Hb1, Hb2, Wall,
      srb2, trb2, teb2, sow, hlog, Xbf, PHb);

  // t12 GEMM + emission in one launch
  te_k<<<CS / 64 + MAXB, 256, 0, stream>>>(
      Xbf, nec, nes, T12, rlse, Wpb, PHb, tpb, offs, wlist, bmap, esum, lall);

  // fused elementwise-leaf + level-1 combine: 256 leaves -> 64 nodes per seq
  leafc2_k<<<NB * 64, 256, 0, stream>>>(
      T12, rlse, lall, esum, text, w2c, bufA, scA);

  comb4_k<<<NB * 16, 256, 0, stream>>>(bufA, scA, bufB, scB, 16);
  comb4_k<<<NB * 4, 256, 0, stream>>>(bufB, scB, bufC, scC, 4);
  tail2_k<<<NB, 256, 0, stream>>>(bufC, scC, rootb, hlog, lall, esum, text, w2c, out);
}